// Round 1
// baseline (1437.975 us; speedup 1.0000x reference)
//
#include <hip/hip_runtime.h>
#include <math.h>

namespace {
constexpr int kL    = 262144;
constexpr int kC    = 256;
constexpr int kNH   = 8;
constexpr int kG    = 64;
constexpr int kFF   = 2048;
constexpr int kLPAD = 262144;
constexpr int kBS   = 4;
constexpr int kNW   = kLPAD / kG;   // 4096
constexpr int kS    = kNW / kBS;    // 1024
constexpr int kHD   = kC / kNH;     // 32

constexpr size_t MB        = 1024 * 1024;
constexpr size_t OFF_GIDX   = 0;        // int[LPAD]   1MB
constexpr size_t OFF_WINNER = 1 * MB;   // int[L]      1MB
constexpr size_t OFF_WLIST  = 2 * MB;   // int[L]      1MB
constexpr size_t OFF_CNT    = 3 * MB;   // int[1]
constexpr size_t OFF_X0     = 4 * MB;   // f32[4096*256]  4MB
constexpr size_t OFF_BASE   = 8 * MB;   // f32[4096*256]  4MB (reuses qkv region)
constexpr size_t OFF_QKV    = 8 * MB;   // f32[4096*768]  12MB
constexpr size_t OFF_W2T    = 12 * MB;  // f32[256*256]   256KB (reuses qkv region)
constexpr size_t OFF_ATTN   = 20 * MB;  // f32[4096*256]  4MB
constexpr size_t OFF_X2     = 20 * MB;  // reuses attn
constexpr size_t OFF_Y      = 24 * MB;  // f32[4096*256]  4MB (y1 then y2)
constexpr size_t OFF_X1     = 28 * MB;  // f32[4096*256]  4MB
constexpr size_t OFF_FF1    = 32 * MB;  // f32[4096*2048] 32MB  -> end 64MB
} // namespace

// ---------------------------------------------------------------- init
__global__ __launch_bounds__(256) void k_init(const int* __restrict__ x_idx,
                                              const int* __restrict__ flat2win,
                                              int* __restrict__ gidx,
                                              int* __restrict__ winner,
                                              int* __restrict__ cnt) {
  int j = blockIdx.x * 256 + threadIdx.x;          // grid covers LPAD == L
  gidx[j] = x_idx[flat2win[j]];
  winner[j] = -1;
  if (j == 0) cnt[0] = 0;
}

__global__ __launch_bounds__(256) void k_winner(const int* __restrict__ x_idx,
                                                int* __restrict__ winner) {
  int i = blockIdx.x * 256 + threadIdx.x;
  atomicMax(&winner[x_idx[i]], i);
}

__global__ __launch_bounds__(256) void k_compact(const int* __restrict__ x_idx,
                                                 const int* __restrict__ winner,
                                                 int* __restrict__ wlist,
                                                 int* __restrict__ cnt) {
  int i = blockIdx.x * 256 + threadIdx.x;
  if (winner[x_idx[i]] == i) {
    int p = atomicAdd(cnt, 1);
    wlist[p] = i;
  }
}

// ---------------------------------------------------------------- pool (gather + max over group)
__global__ __launch_bounds__(256) void k_pool(const float* __restrict__ feats,
                                              const int* __restrict__ gidx,
                                              float* __restrict__ x0) {
  int w = blockIdx.x, t = threadIdx.x;
  __shared__ int rows[kG];
  if (t < kG) rows[t] = gidx[w * kG + t];
  __syncthreads();
  float m = -INFINITY;
  #pragma unroll 4
  for (int g = 0; g < kG; ++g)
    m = fmaxf(m, feats[(size_t)rows[g] * kC + t]);
  x0[w * kC + t] = m;
}

// ---------------------------------------------------------------- generic tiled f32 GEMM: C = act(A*B^T + bias)
template <bool RELU>
__global__ __launch_bounds__(256) void k_gemm(const float* __restrict__ A, int lda,
                                              const float* __restrict__ B, int ldb,
                                              const float* __restrict__ bias,
                                              float* __restrict__ Cc, int ldc,
                                              int K) {
  __shared__ __align__(16) float As[16][68];
  __shared__ __align__(16) float Bs[16][68];
  const int n0 = blockIdx.x * 64;
  const int m0 = blockIdx.y * 64;
  const int t = threadIdx.x;
  const int tx = t & 15, ty = t >> 4;
  float acc[4][4] = {};
  for (int k0 = 0; k0 < K; k0 += 16) {
    #pragma unroll
    for (int it = 0; it < 4; ++it) {
      int idx = t + it * 256;             // 0..1023
      int kk = idx & 15, mm = idx >> 4;   // mm 0..63
      As[kk][mm] = A[(size_t)(m0 + mm) * lda + k0 + kk];
      Bs[kk][mm] = B[(size_t)(n0 + mm) * ldb + k0 + kk];
    }
    __syncthreads();
    #pragma unroll
    for (int kk = 0; kk < 16; ++kk) {
      float4 a4 = *(const float4*)&As[kk][ty * 4];
      float4 b4 = *(const float4*)&Bs[kk][tx * 4];
      float av[4] = {a4.x, a4.y, a4.z, a4.w};
      float bv[4] = {b4.x, b4.y, b4.z, b4.w};
      #pragma unroll
      for (int i = 0; i < 4; ++i)
        #pragma unroll
        for (int j = 0; j < 4; ++j)
          acc[i][j] = fmaf(av[i], bv[j], acc[i][j]);
    }
    __syncthreads();
  }
  #pragma unroll
  for (int i = 0; i < 4; ++i) {
    int row = m0 + ty * 4 + i;
    int col = n0 + tx * 4;
    float4 v;
    v.x = acc[i][0] + bias[col + 0];
    v.y = acc[i][1] + bias[col + 1];
    v.z = acc[i][2] + bias[col + 2];
    v.w = acc[i][3] + bias[col + 3];
    if (RELU) {
      v.x = fmaxf(v.x, 0.f); v.y = fmaxf(v.y, 0.f);
      v.z = fmaxf(v.z, 0.f); v.w = fmaxf(v.w, 0.f);
    }
    *(float4*)&Cc[(size_t)row * ldc + col] = v;
  }
}

// ---------------------------------------------------------------- attention: one wave per q-row
__global__ __launch_bounds__(256) void k_attn(const float* __restrict__ qkv,
                                              float* __restrict__ attn_out) {
  int blk = blockIdx.x;                    // 0..8191
  int q0 = (blk & (kS / 4 - 1)) * 4;       // 256 q-tiles per (b,h)
  int bh = blk >> 8;
  int h = bh & (kNH - 1), b = bh >> 3;
  int wv = threadIdx.x >> 6, lane = threadIdx.x & 63;
  int qrow = q0 + wv;
  __shared__ float sc[4][kS];
  __shared__ float qb[4][kHD];
  const float scale = 0.17677669529663687f;   // 1/sqrt(32)

  const float* qp = qkv + (size_t)(b * kS + qrow) * (3 * kC) + h * kHD;
  if (lane < kHD) qb[wv][lane] = qp[lane] * scale;
  __syncthreads();

  // scores
  float lmax = -INFINITY;
  const float* kbase = qkv + (size_t)b * kS * (3 * kC) + kC + h * kHD;
  for (int j = lane; j < kS; j += 64) {
    const float* kp = kbase + (size_t)j * (3 * kC);
    float dot = 0.f;
    #pragma unroll
    for (int d = 0; d < kHD; d += 4) {
      float4 kv = *(const float4*)(kp + d);
      dot += qb[wv][d] * kv.x + qb[wv][d + 1] * kv.y +
             qb[wv][d + 2] * kv.z + qb[wv][d + 3] * kv.w;
    }
    sc[wv][j] = dot;
    lmax = fmaxf(lmax, dot);
  }
  #pragma unroll
  for (int off = 32; off; off >>= 1) lmax = fmaxf(lmax, __shfl_xor(lmax, off));
  float lsum = 0.f;
  for (int j = lane; j < kS; j += 64) {
    float p = __expf(sc[wv][j] - lmax);
    sc[wv][j] = p;
    lsum += p;
  }
  #pragma unroll
  for (int off = 32; off; off >>= 1) lsum += __shfl_xor(lsum, off);
  float inv = 1.0f / lsum;

  // PV: lanes 0-31 handle j in [0,512), lanes 32-63 handle [512,1024), same d
  int half = lane >> 5, d = lane & 31;
  const float* vbase = qkv + (size_t)b * kS * (3 * kC) + 2 * kC + h * kHD + d;
  float acc = 0.f;
  int jb = half * 512;
  for (int j = jb; j < jb + 512; ++j)
    acc = fmaf(sc[wv][j], vbase[(size_t)j * (3 * kC)], acc);
  acc += __shfl_down(acc, 32);
  if (lane < 32)
    attn_out[(size_t)(b * kS + qrow) * kC + h * kHD + d] = acc * inv;
}

// ---------------------------------------------------------------- layer norm with residual: out = LN(y + r)
__global__ __launch_bounds__(256) void k_ln(const float* __restrict__ Y,
                                            const float* __restrict__ R,
                                            const float* __restrict__ g,
                                            const float* __restrict__ bb,
                                            float* __restrict__ Out) {
  int row = blockIdx.x, t = threadIdx.x;
  int wv = t >> 6, lane = t & 63;
  float v = Y[(size_t)row * kC + t] + R[(size_t)row * kC + t];
  __shared__ float red1[4], red2[4];
  float s = v;
  #pragma unroll
  for (int off = 32; off; off >>= 1) s += __shfl_xor(s, off);
  if (lane == 0) red1[wv] = s;
  __syncthreads();
  float mu = (red1[0] + red1[1] + red1[2] + red1[3]) * (1.0f / kC);
  float d = v - mu;
  float sq = d * d;
  #pragma unroll
  for (int off = 32; off; off >>= 1) sq += __shfl_xor(sq, off);
  if (lane == 0) red2[wv] = sq;
  __syncthreads();
  float var = (red2[0] + red2[1] + red2[2] + red2[3]) * (1.0f / kC);
  Out[(size_t)row * kC + t] = d * rsqrtf(var + 1e-5f) * g[t] + bb[t];
}

// ---------------------------------------------------------------- W2 transpose: W2T[k][c] = proj_w[c][256+k]
__global__ __launch_bounds__(256) void k_w2t(const float* __restrict__ proj_w,
                                             float* __restrict__ W2T) {
  int k = blockIdx.x, c = threadIdx.x;
  W2T[k * kC + c] = proj_w[(size_t)c * (2 * kC) + kC + k];
}

// ---------------------------------------------------------------- fuse GEMV batch + scatter
__global__ __launch_bounds__(256) void k_fuse(const float* __restrict__ feats,
                                              const int* __restrict__ gidx,
                                              const int* __restrict__ wlist,
                                              const int* __restrict__ cnt,
                                              const int* __restrict__ win2flat,
                                              const int* __restrict__ x_idx,
                                              const float* __restrict__ base,
                                              const float* __restrict__ W2T,
                                              float* __restrict__ out) {
  int count = cnt[0];
  int r0 = blockIdx.x * 32;
  if (r0 >= count) return;
  int nr = min(32, count - r0);
  int t = threadIdx.x;
  __shared__ __align__(16) float AT[256][36];   // [k][r], padded stride 36 (144B, 16B-aligned rows)
  __shared__ int dstrow[32];
  __shared__ int wwin[32];
  __shared__ int srcrow[32];
  if (t < 32) {
    if (t < nr) {
      int i = wlist[r0 + t];
      int j = win2flat[i];
      srcrow[t] = gidx[j];
      wwin[t] = j >> 6;
      dstrow[t] = x_idx[i];
    } else {
      srcrow[t] = 0; wwin[t] = 0; dstrow[t] = 0;
    }
  }
  __syncthreads();
  // stage A transposed: AT[k][r] = feats[srcrow[r]][k]
  #pragma unroll
  for (int r = 0; r < 32; ++r)
    AT[t][r] = feats[(size_t)srcrow[r] * kC + t];
  __syncthreads();

  float acc[32];
  #pragma unroll
  for (int r = 0; r < 32; ++r) acc[r] = 0.f;

  #pragma unroll 4
  for (int k = 0; k < kC; ++k) {
    float wv = W2T[k * kC + t];     // coalesced, L2-resident (256KB)
    #pragma unroll
    for (int r = 0; r < 32; r += 4) {
      float4 a = *(const float4*)&AT[k][r];    // broadcast LDS read
      acc[r + 0] = fmaf(wv, a.x, acc[r + 0]);
      acc[r + 1] = fmaf(wv, a.y, acc[r + 1]);
      acc[r + 2] = fmaf(wv, a.z, acc[r + 2]);
      acc[r + 3] = fmaf(wv, a.w, acc[r + 3]);
    }
  }
  #pragma unroll
  for (int r = 0; r < 32; ++r) {
    if (r < nr)
      out[(size_t)dstrow[r] * kC + t] = acc[r] + base[(size_t)wwin[r] * kC + t];
  }
}

// ---------------------------------------------------------------- launch
extern "C" void kernel_launch(void* const* d_in, const int* in_sizes, int n_in,
                              void* d_out, int out_size, void* d_ws, size_t ws_size,
                              hipStream_t stream) {
  const float* feats      = (const float*)d_in[0];
  const int*   x_idx      = (const int*)d_in[1];
  const int*   flat2win   = (const int*)d_in[2];
  const int*   win2flat   = (const int*)d_in[3];
  const float* in_proj_w  = (const float*)d_in[4];
  const float* in_proj_b  = (const float*)d_in[5];
  const float* out_proj_w = (const float*)d_in[6];
  const float* out_proj_b = (const float*)d_in[7];
  const float* lin1_w     = (const float*)d_in[8];
  const float* lin1_b     = (const float*)d_in[9];
  const float* lin2_w     = (const float*)d_in[10];
  const float* lin2_b     = (const float*)d_in[11];
  const float* ln1_g      = (const float*)d_in[12];
  const float* ln1_b      = (const float*)d_in[13];
  const float* ln2_g      = (const float*)d_in[14];
  const float* ln2_b      = (const float*)d_in[15];
  const float* proj_w     = (const float*)d_in[16];
  const float* proj_b     = (const float*)d_in[17];

  char* ws = (char*)d_ws;
  int*   gidx   = (int*)(ws + OFF_GIDX);
  int*   winner = (int*)(ws + OFF_WINNER);
  int*   wlist  = (int*)(ws + OFF_WLIST);
  int*   cnt    = (int*)(ws + OFF_CNT);
  float* x0     = (float*)(ws + OFF_X0);
  float* qkv    = (float*)(ws + OFF_QKV);
  float* attn   = (float*)(ws + OFF_ATTN);
  float* y      = (float*)(ws + OFF_Y);
  float* x1     = (float*)(ws + OFF_X1);
  float* ff1    = (float*)(ws + OFF_FF1);
  float* x2     = (float*)(ws + OFF_X2);
  float* basep  = (float*)(ws + OFF_BASE);
  float* W2T    = (float*)(ws + OFF_W2T);
  float* out    = (float*)d_out;

  // full output starts as a copy of feats_flat (harness poisons d_out once)
  hipMemcpyAsync(d_out, (const void*)feats, (size_t)kL * kC * sizeof(float),
                 hipMemcpyDeviceToDevice, stream);

  k_init<<<kLPAD / 256, 256, 0, stream>>>(x_idx, flat2win, gidx, winner, cnt);
  k_winner<<<kL / 256, 256, 0, stream>>>(x_idx, winner);
  k_compact<<<kL / 256, 256, 0, stream>>>(x_idx, winner, wlist, cnt);
  k_pool<<<kNW, 256, 0, stream>>>(feats, gidx, x0);

  // qkv = x0 @ in_proj_w^T + b   [4096, 768]
  k_gemm<false><<<dim3(3 * kC / 64, kNW / 64), 256, 0, stream>>>(
      x0, kC, in_proj_w, kC, in_proj_b, qkv, 3 * kC, kC);
  k_attn<<<kBS * kNH * kS / 4, 256, 0, stream>>>(qkv, attn);
  // y1 = attn @ out_proj^T + b
  k_gemm<false><<<dim3(kC / 64, kNW / 64), 256, 0, stream>>>(
      attn, kC, out_proj_w, kC, out_proj_b, y, kC, kC);
  k_ln<<<kNW, 256, 0, stream>>>(y, x0, ln1_g, ln1_b, x1);
  // ff1 = relu(x1 @ lin1^T + b)  [4096, 2048]
  k_gemm<true><<<dim3(kFF / 64, kNW / 64), 256, 0, stream>>>(
      x1, kC, lin1_w, kC, lin1_b, ff1, kFF, kC);
  // y2 = ff1 @ lin2^T + b
  k_gemm<false><<<dim3(kC / 64, kNW / 64), 256, 0, stream>>>(
      ff1, kFF, lin2_w, kFF, lin2_b, y, kC, kFF);
  k_ln<<<kNW, 256, 0, stream>>>(y, x1, ln2_g, ln2_b, x2);
  // base = x2 @ proj_w[:, :256]^T + proj_b   (ldb = 512)
  k_gemm<false><<<dim3(kC / 64, kNW / 64), 256, 0, stream>>>(
      x2, kC, proj_w, 2 * kC, proj_b, basep, kC, kC);
  k_w2t<<<kC, 256, 0, stream>>>(proj_w, W2T);
  k_fuse<<<kL / 32, 256, 0, stream>>>(feats, gidx, wlist, cnt, win2flat, x_idx,
                                      basep, W2T, out);
}

// Round 2
// 933.278 us; speedup vs baseline: 1.5408x; 1.5408x over previous
//
#include <hip/hip_runtime.h>
#include <math.h>

namespace {
constexpr int kL    = 262144;
constexpr int kC    = 256;
constexpr int kNH   = 8;
constexpr int kG    = 64;
constexpr int kFF   = 2048;
constexpr int kLPAD = 262144;
constexpr int kBS   = 4;
constexpr int kNW   = kLPAD / kG;   // 4096
constexpr int kS    = kNW / kBS;    // 1024
constexpr int kHD   = kC / kNH;     // 32

constexpr size_t MB        = 1024 * 1024;
constexpr size_t OFF_GIDX   = 0;        // int[LPAD]   1MB
constexpr size_t OFF_WINNER = 1 * MB;   // int[L]      1MB
constexpr size_t OFF_WLIST  = 2 * MB;   // int[L]      1MB
constexpr size_t OFF_CNT    = 3 * MB;   // int[1]
constexpr size_t OFF_X0     = 4 * MB;   // f32[4096*256]  4MB
constexpr size_t OFF_BASE   = 8 * MB;   // f32[4096*256]  4MB (reuses qkv region)
constexpr size_t OFF_QKV    = 8 * MB;   // f32[4096*768]  12MB
constexpr size_t OFF_W2T    = 12 * MB;  // f32[256*256]   256KB (reuses qkv region)
constexpr size_t OFF_ATTN   = 20 * MB;  // f32[4096*256]  4MB
constexpr size_t OFF_X2     = 20 * MB;  // reuses attn
constexpr size_t OFF_Y      = 24 * MB;  // f32[4096*256]  4MB (y1 then y2); Qh during attn
constexpr size_t OFF_X1     = 28 * MB;  // f32[4096*256]  4MB; Kh during attn
constexpr size_t OFF_FF1    = 32 * MB;  // f32[4096*2048] 32MB; Vh during attn -> end 64MB
} // namespace

// ---------------------------------------------------------------- init
__global__ __launch_bounds__(256) void k_init(const int* __restrict__ x_idx,
                                              const int* __restrict__ flat2win,
                                              int* __restrict__ gidx,
                                              int* __restrict__ winner,
                                              int* __restrict__ cnt) {
  int j = blockIdx.x * 256 + threadIdx.x;          // grid covers LPAD == L
  gidx[j] = x_idx[flat2win[j]];
  winner[j] = -1;
  if (j == 0) cnt[0] = 0;
}

__global__ __launch_bounds__(256) void k_winner(const int* __restrict__ x_idx,
                                                int* __restrict__ winner) {
  int i = blockIdx.x * 256 + threadIdx.x;
  atomicMax(&winner[x_idx[i]], i);
}

__global__ __launch_bounds__(256) void k_compact(const int* __restrict__ x_idx,
                                                 const int* __restrict__ winner,
                                                 int* __restrict__ wlist,
                                                 int* __restrict__ cnt) {
  int i = blockIdx.x * 256 + threadIdx.x;
  if (winner[x_idx[i]] == i) {
    int p = atomicAdd(cnt, 1);
    wlist[p] = i;
  }
}

// ---------------------------------------------------------------- pool (gather + max over group)
__global__ __launch_bounds__(256) void k_pool(const float* __restrict__ feats,
                                              const int* __restrict__ gidx,
                                              float* __restrict__ x0) {
  int w = blockIdx.x, t = threadIdx.x;
  __shared__ int rows[kG];
  if (t < kG) rows[t] = gidx[w * kG + t];
  __syncthreads();
  float m = -INFINITY;
  #pragma unroll 4
  for (int g = 0; g < kG; ++g)
    m = fmaxf(m, feats[(size_t)rows[g] * kC + t]);
  x0[w * kC + t] = m;
}

// ---------------------------------------------------------------- generic tiled f32 GEMM: C = act(A*B^T + bias)
template <bool RELU>
__global__ __launch_bounds__(256) void k_gemm(const float* __restrict__ A, int lda,
                                              const float* __restrict__ B, int ldb,
                                              const float* __restrict__ bias,
                                              float* __restrict__ Cc, int ldc,
                                              int K) {
  __shared__ __align__(16) float As[16][68];
  __shared__ __align__(16) float Bs[16][68];
  const int n0 = blockIdx.x * 64;
  const int m0 = blockIdx.y * 64;
  const int t = threadIdx.x;
  const int tx = t & 15, ty = t >> 4;
  float acc[4][4] = {};
  for (int k0 = 0; k0 < K; k0 += 16) {
    #pragma unroll
    for (int it = 0; it < 4; ++it) {
      int idx = t + it * 256;             // 0..1023
      int kk = idx & 15, mm = idx >> 4;   // mm 0..63
      As[kk][mm] = A[(size_t)(m0 + mm) * lda + k0 + kk];
      Bs[kk][mm] = B[(size_t)(n0 + mm) * ldb + k0 + kk];
    }
    __syncthreads();
    #pragma unroll
    for (int kk = 0; kk < 16; ++kk) {
      float4 a4 = *(const float4*)&As[kk][ty * 4];
      float4 b4 = *(const float4*)&Bs[kk][tx * 4];
      float av[4] = {a4.x, a4.y, a4.z, a4.w};
      float bv[4] = {b4.x, b4.y, b4.z, b4.w};
      #pragma unroll
      for (int i = 0; i < 4; ++i)
        #pragma unroll
        for (int j = 0; j < 4; ++j)
          acc[i][j] = fmaf(av[i], bv[j], acc[i][j]);
    }
    __syncthreads();
  }
  #pragma unroll
  for (int i = 0; i < 4; ++i) {
    int row = m0 + ty * 4 + i;
    int col = n0 + tx * 4;
    float4 v;
    v.x = acc[i][0] + bias[col + 0];
    v.y = acc[i][1] + bias[col + 1];
    v.z = acc[i][2] + bias[col + 2];
    v.w = acc[i][3] + bias[col + 3];
    if (RELU) {
      v.x = fmaxf(v.x, 0.f); v.y = fmaxf(v.y, 0.f);
      v.z = fmaxf(v.z, 0.f); v.w = fmaxf(v.w, 0.f);
    }
    *(float4*)&Cc[(size_t)row * ldc + col] = v;
  }
}

// ---------------------------------------------------------------- qkv -> per-head contiguous Q(scaled),K,V [BH][S][32]
__global__ __launch_bounds__(256) void k_qkvt(const float* __restrict__ qkv,
                                              float* __restrict__ Qh,
                                              float* __restrict__ Kh,
                                              float* __restrict__ Vh) {
  const float scale = 0.17677669529663687f;   // 1/sqrt(32)
  int r = blockIdx.x;            // 0..4095  (b*1024+s)
  int b = r >> 10, s = r & 1023;
  int t = threadIdx.x;
  int h = t >> 5, d = t & 31;
  size_t src = (size_t)r * (3 * kC);
  float qv = qkv[src + t] * scale;
  float kv = qkv[src + kC + t];
  float vv = qkv[src + 2 * kC + t];
  size_t dst = (((size_t)(b * kNH + h) * kS) + s) * kHD + d;
  Qh[dst] = qv;
  Kh[dst] = kv;
  Vh[dst] = vv;
}

// ---------------------------------------------------------------- flash attention: 64 q-rows x 64-key tiles, f32
__global__ __launch_bounds__(256) void k_attn(const float* __restrict__ Qh,
                                              const float* __restrict__ Kh,
                                              const float* __restrict__ Vh,
                                              float* __restrict__ attn_out) {
  const int q0 = blockIdx.x * 64;
  const int bh = blockIdx.y;           // b*8+h
  const int b = bh >> 3, h = bh & 7;
  const int t = threadIdx.x;
  const int tx = t & 15, ty = t >> 4;

  __shared__ __align__(16) float Qs[32][68];
  __shared__ __align__(16) float Ks[32][68];
  __shared__ __align__(16) float Vs[64][36];
  __shared__ __align__(16) float Ps[64][68];

  const float* qbase = Qh + ((size_t)bh * kS + q0) * kHD;
  const float* kbase = Kh + (size_t)bh * kS * kHD;
  const float* vbase = Vh + (size_t)bh * kS * kHD;

  // stage Q tile transposed: Qs[d][qr]
  #pragma unroll
  for (int i = 0; i < 8; ++i) {
    int idx = t + i * 256;
    int qr = idx >> 5, d = idx & 31;
    Qs[d][qr] = qbase[(size_t)qr * kHD + d];
  }

  float m[4], l[4], O[4][2];
  #pragma unroll
  for (int i = 0; i < 4; ++i) { m[i] = -INFINITY; l[i] = 0.f; O[i][0] = 0.f; O[i][1] = 0.f; }

  for (int k0 = 0; k0 < kS; k0 += 64) {
    // stage K (transposed) and V tiles
    #pragma unroll
    for (int i = 0; i < 8; ++i) {
      int idx = t + i * 256;
      int kr = idx >> 5, d = idx & 31;
      float kv = kbase[(size_t)(k0 + kr) * kHD + d];
      float vv = vbase[(size_t)(k0 + kr) * kHD + d];
      Ks[d][kr] = kv;
      Vs[kr][d] = vv;
    }
    __syncthreads();

    // scores: 4x4 per thread, rows ty*4.., cols tx*4..
    float acc[4][4] = {};
    #pragma unroll
    for (int d = 0; d < 32; ++d) {
      float4 a4 = *(const float4*)&Qs[d][ty * 4];
      float4 b4 = *(const float4*)&Ks[d][tx * 4];
      float av[4] = {a4.x, a4.y, a4.z, a4.w};
      float bv[4] = {b4.x, b4.y, b4.z, b4.w};
      #pragma unroll
      for (int i = 0; i < 4; ++i)
        #pragma unroll
        for (int j = 0; j < 4; ++j)
          acc[i][j] = fmaf(av[i], bv[j], acc[i][j]);
    }

    // online softmax across the 16-lane row group (same ty)
    #pragma unroll
    for (int i = 0; i < 4; ++i) {
      float tmax = fmaxf(fmaxf(acc[i][0], acc[i][1]), fmaxf(acc[i][2], acc[i][3]));
      #pragma unroll
      for (int off = 8; off; off >>= 1) tmax = fmaxf(tmax, __shfl_xor(tmax, off, 16));
      float newm = fmaxf(m[i], tmax);
      float alpha = __expf(m[i] - newm);
      float ps = 0.f;
      #pragma unroll
      for (int j = 0; j < 4; ++j) {
        acc[i][j] = __expf(acc[i][j] - newm);
        ps += acc[i][j];
      }
      #pragma unroll
      for (int off = 8; off; off >>= 1) ps += __shfl_xor(ps, off, 16);
      l[i] = l[i] * alpha + ps;
      m[i] = newm;
      O[i][0] *= alpha;
      O[i][1] *= alpha;
      *(float4*)&Ps[ty * 4 + i][tx * 4] =
          make_float4(acc[i][0], acc[i][1], acc[i][2], acc[i][3]);
    }
    __syncthreads();

    // PV: thread owns (4 q-rows) x (d = tx*2, tx*2+1)
    #pragma unroll 8
    for (int k = 0; k < 64; ++k) {
      float2 v2 = *(const float2*)&Vs[k][tx * 2];
      #pragma unroll
      for (int i = 0; i < 4; ++i) {
        float p = Ps[ty * 4 + i][k];
        O[i][0] = fmaf(p, v2.x, O[i][0]);
        O[i][1] = fmaf(p, v2.y, O[i][1]);
      }
    }
    __syncthreads();
  }

  #pragma unroll
  for (int i = 0; i < 4; ++i) {
    float invl = 1.0f / l[i];
    size_t row = (size_t)b * kS + q0 + ty * 4 + i;
    *(float2*)&attn_out[row * kC + h * kHD + tx * 2] =
        make_float2(O[i][0] * invl, O[i][1] * invl);
  }
}

// ---------------------------------------------------------------- layer norm with residual: out = LN(y + r)
__global__ __launch_bounds__(256) void k_ln(const float* __restrict__ Y,
                                            const float* __restrict__ R,
                                            const float* __restrict__ g,
                                            const float* __restrict__ bb,
                                            float* __restrict__ Out) {
  int row = blockIdx.x, t = threadIdx.x;
  int wv = t >> 6, lane = t & 63;
  float v = Y[(size_t)row * kC + t] + R[(size_t)row * kC + t];
  __shared__ float red1[4], red2[4];
  float s = v;
  #pragma unroll
  for (int off = 32; off; off >>= 1) s += __shfl_xor(s, off);
  if (lane == 0) red1[wv] = s;
  __syncthreads();
  float mu = (red1[0] + red1[1] + red1[2] + red1[3]) * (1.0f / kC);
  float d = v - mu;
  float sq = d * d;
  #pragma unroll
  for (int off = 32; off; off >>= 1) sq += __shfl_xor(sq, off);
  if (lane == 0) red2[wv] = sq;
  __syncthreads();
  float var = (red2[0] + red2[1] + red2[2] + red2[3]) * (1.0f / kC);
  Out[(size_t)row * kC + t] = d * rsqrtf(var + 1e-5f) * g[t] + bb[t];
}

// ---------------------------------------------------------------- W2 transpose: W2T[k][c] = proj_w[c][256+k]
__global__ __launch_bounds__(256) void k_w2t(const float* __restrict__ proj_w,
                                             float* __restrict__ W2T) {
  int k = blockIdx.x, c = threadIdx.x;
  W2T[k * kC + c] = proj_w[(size_t)c * (2 * kC) + kC + k];
}

// ---------------------------------------------------------------- fuse GEMV batch + scatter
__global__ __launch_bounds__(256) void k_fuse(const float* __restrict__ feats,
                                              const int* __restrict__ gidx,
                                              const int* __restrict__ wlist,
                                              const int* __restrict__ cnt,
                                              const int* __restrict__ win2flat,
                                              const int* __restrict__ x_idx,
                                              const float* __restrict__ base,
                                              const float* __restrict__ W2T,
                                              float* __restrict__ out) {
  int count = cnt[0];
  int r0 = blockIdx.x * 32;
  if (r0 >= count) return;
  int nr = min(32, count - r0);
  int t = threadIdx.x;
  __shared__ __align__(16) float AT[256][36];   // [k][r], padded stride 36
  __shared__ int dstrow[32];
  __shared__ int wwin[32];
  __shared__ int srcrow[32];
  if (t < 32) {
    if (t < nr) {
      int i = wlist[r0 + t];
      int j = win2flat[i];
      srcrow[t] = gidx[j];
      wwin[t] = j >> 6;
      dstrow[t] = x_idx[i];
    } else {
      srcrow[t] = 0; wwin[t] = 0; dstrow[t] = 0;
    }
  }
  __syncthreads();
  // stage A transposed: AT[k][r] = feats[srcrow[r]][k]
  #pragma unroll
  for (int r = 0; r < 32; ++r)
    AT[t][r] = feats[(size_t)srcrow[r] * kC + t];
  __syncthreads();

  float acc[32];
  #pragma unroll
  for (int r = 0; r < 32; ++r) acc[r] = 0.f;

  #pragma unroll 4
  for (int k = 0; k < kC; ++k) {
    float wv = W2T[k * kC + t];     // coalesced, L2-resident (256KB)
    #pragma unroll
    for (int r = 0; r < 32; r += 4) {
      float4 a = *(const float4*)&AT[k][r];    // broadcast LDS read
      acc[r + 0] = fmaf(wv, a.x, acc[r + 0]);
      acc[r + 1] = fmaf(wv, a.y, acc[r + 1]);
      acc[r + 2] = fmaf(wv, a.z, acc[r + 2]);
      acc[r + 3] = fmaf(wv, a.w, acc[r + 3]);
    }
  }
  #pragma unroll
  for (int r = 0; r < 32; ++r) {
    if (r < nr)
      out[(size_t)dstrow[r] * kC + t] = acc[r] + base[(size_t)wwin[r] * kC + t];
  }
}

// ---------------------------------------------------------------- launch
extern "C" void kernel_launch(void* const* d_in, const int* in_sizes, int n_in,
                              void* d_out, int out_size, void* d_ws, size_t ws_size,
                              hipStream_t stream) {
  const float* feats      = (const float*)d_in[0];
  const int*   x_idx      = (const int*)d_in[1];
  const int*   flat2win   = (const int*)d_in[2];
  const int*   win2flat   = (const int*)d_in[3];
  const float* in_proj_w  = (const float*)d_in[4];
  const float* in_proj_b  = (const float*)d_in[5];
  const float* out_proj_w = (const float*)d_in[6];
  const float* out_proj_b = (const float*)d_in[7];
  const float* lin1_w     = (const float*)d_in[8];
  const float* lin1_b     = (const float*)d_in[9];
  const float* lin2_w     = (const float*)d_in[10];
  const float* lin2_b     = (const float*)d_in[11];
  const float* ln1_g      = (const float*)d_in[12];
  const float* ln1_b      = (const float*)d_in[13];
  const float* ln2_g      = (const float*)d_in[14];
  const float* ln2_b      = (const float*)d_in[15];
  const float* proj_w     = (const float*)d_in[16];
  const float* proj_b     = (const float*)d_in[17];

  char* ws = (char*)d_ws;
  int*   gidx   = (int*)(ws + OFF_GIDX);
  int*   winner = (int*)(ws + OFF_WINNER);
  int*   wlist  = (int*)(ws + OFF_WLIST);
  int*   cnt    = (int*)(ws + OFF_CNT);
  float* x0     = (float*)(ws + OFF_X0);
  float* qkv    = (float*)(ws + OFF_QKV);
  float* attn   = (float*)(ws + OFF_ATTN);
  float* y      = (float*)(ws + OFF_Y);
  float* x1     = (float*)(ws + OFF_X1);
  float* ff1    = (float*)(ws + OFF_FF1);
  float* x2     = (float*)(ws + OFF_X2);
  float* basep  = (float*)(ws + OFF_BASE);
  float* W2T    = (float*)(ws + OFF_W2T);
  float* out    = (float*)d_out;

  // Q/K/V per-head buffers live in regions that are dead during attention
  float* Qh = y;                         // 4MB
  float* Kh = x1;                        // 4MB
  float* Vh = ff1;                       // first 4MB of the 32MB region

  // full output starts as a copy of feats_flat (harness poisons d_out once)
  hipMemcpyAsync(d_out, (const void*)feats, (size_t)kL * kC * sizeof(float),
                 hipMemcpyDeviceToDevice, stream);

  k_init<<<kLPAD / 256, 256, 0, stream>>>(x_idx, flat2win, gidx, winner, cnt);
  k_winner<<<kL / 256, 256, 0, stream>>>(x_idx, winner);
  k_compact<<<kL / 256, 256, 0, stream>>>(x_idx, winner, wlist, cnt);
  k_pool<<<kNW, 256, 0, stream>>>(feats, gidx, x0);

  // qkv = x0 @ in_proj_w^T + b   [4096, 768]
  k_gemm<false><<<dim3(3 * kC / 64, kNW / 64), 256, 0, stream>>>(
      x0, kC, in_proj_w, kC, in_proj_b, qkv, 3 * kC, kC);
  k_qkvt<<<kNW, 256, 0, stream>>>(qkv, Qh, Kh, Vh);
  k_attn<<<dim3(kS / 64, kBS * kNH), 256, 0, stream>>>(Qh, Kh, Vh, attn);
  // y1 = attn @ out_proj^T + b
  k_gemm<false><<<dim3(kC / 64, kNW / 64), 256, 0, stream>>>(
      attn, kC, out_proj_w, kC, out_proj_b, y, kC, kC);
  k_ln<<<kNW, 256, 0, stream>>>(y, x0, ln1_g, ln1_b, x1);
  // ff1 = relu(x1 @ lin1^T + b)  [4096, 2048]
  k_gemm<true><<<dim3(kFF / 64, kNW / 64), 256, 0, stream>>>(
      x1, kC, lin1_w, kC, lin1_b, ff1, kFF, kC);
  // y2 = ff1 @ lin2^T + b
  k_gemm<false><<<dim3(kC / 64, kNW / 64), 256, 0, stream>>>(
      ff1, kFF, lin2_w, kFF, lin2_b, y, kC, kFF);
  k_ln<<<kNW, 256, 0, stream>>>(y, x1, ln2_g, ln2_b, x2);
  // base = x2 @ proj_w[:, :256]^T + proj_b   (ldb = 512)
  k_gemm<false><<<dim3(kC / 64, kNW / 64), 256, 0, stream>>>(
      x2, kC, proj_w, 2 * kC, proj_b, basep, kC, kC);
  k_w2t<<<kC, 256, 0, stream>>>(proj_w, W2T);
  k_fuse<<<kL / 32, 256, 0, stream>>>(feats, gidx, wlist, cnt, win2flat, x_idx,
                                      basep, W2T, out);
}

// Round 3
// 633.665 us; speedup vs baseline: 2.2693x; 1.4728x over previous
//
#include <hip/hip_runtime.h>
#include <math.h>

namespace {
constexpr int kL    = 262144;
constexpr int kC    = 256;
constexpr int kNH   = 8;
constexpr int kG    = 64;
constexpr int kFF   = 2048;
constexpr int kLPAD = 262144;
constexpr int kBS   = 4;
constexpr int kNW   = kLPAD / kG;   // 4096
constexpr int kS    = kNW / kBS;    // 1024
constexpr int kHD   = kC / kNH;     // 32

constexpr size_t MB        = 1024 * 1024;
constexpr size_t OFF_GIDX   = 0;        // int[LPAD]   1MB
constexpr size_t OFF_WINNER = 1 * MB;   // int[L]      1MB
constexpr size_t OFF_WLIST  = 2 * MB;   // int[L]      1MB
constexpr size_t OFF_CNT    = 3 * MB;   // int[1]
constexpr size_t OFF_X0     = 4 * MB;   // f32[4096*256]  4MB
constexpr size_t OFF_BASE   = 8 * MB;   // f32[4096*256]  4MB (reuses qkv region)
constexpr size_t OFF_QKV    = 8 * MB;   // f32[4096*768]  12MB
constexpr size_t OFF_W2B    = 12 * MB;  // bf16[256*256]  128KB (reuses qkv region, qkv dead by then)
constexpr size_t OFF_ATTN   = 20 * MB;  // f32[4096*256]  4MB
constexpr size_t OFF_X2     = 20 * MB;  // reuses attn
constexpr size_t OFF_Y      = 24 * MB;  // f32[4096*256]  4MB (y1 then y2); Qh during attn
constexpr size_t OFF_X1     = 28 * MB;  // f32[4096*256]  4MB; Kh during attn
constexpr size_t OFF_FF1    = 32 * MB;  // f32[4096*2048] 32MB; Vh during attn -> end 64MB

typedef __attribute__((ext_vector_type(8))) short bf16x8;
typedef __attribute__((ext_vector_type(4))) float f32x4;

__device__ inline unsigned short f2bf(float f) {
  union { float f; unsigned int u; } x; x.f = f;
  unsigned int r = x.u + 0x7fff + ((x.u >> 16) & 1);   // RNE
  return (unsigned short)(r >> 16);
}
} // namespace

// ---------------------------------------------------------------- init
__global__ __launch_bounds__(256) void k_init(const int* __restrict__ x_idx,
                                              const int* __restrict__ flat2win,
                                              int* __restrict__ gidx,
                                              int* __restrict__ winner,
                                              int* __restrict__ cnt) {
  int j = blockIdx.x * 256 + threadIdx.x;          // grid covers LPAD == L
  gidx[j] = x_idx[flat2win[j]];
  winner[j] = -1;
  if (j == 0) cnt[0] = 0;
}

__global__ __launch_bounds__(256) void k_winner(const int* __restrict__ x_idx,
                                                int* __restrict__ winner) {
  int i = blockIdx.x * 256 + threadIdx.x;
  atomicMax(&winner[x_idx[i]], i);
}

__global__ __launch_bounds__(256) void k_compact(const int* __restrict__ x_idx,
                                                 const int* __restrict__ winner,
                                                 int* __restrict__ wlist,
                                                 int* __restrict__ cnt) {
  int i = blockIdx.x * 256 + threadIdx.x;
  if (winner[x_idx[i]] == i) {
    int p = atomicAdd(cnt, 1);
    wlist[p] = i;
  }
}

// ---------------------------------------------------------------- selective copy: rows not overwritten by fuse scatter
__global__ __launch_bounds__(256) void k_copy(const float* __restrict__ feats,
                                              const int* __restrict__ winner,
                                              float* __restrict__ out) {
  size_t idx = (size_t)blockIdx.x * 256 + threadIdx.x;   // one float4 each
  int row = (int)(idx >> 6);
  int c4 = (int)(idx & 63);
  if (winner[row] < 0) {                                  // wave-uniform (one row per wave)
    *(float4*)&out[(size_t)row * kC + c4 * 4] =
        *(const float4*)&feats[(size_t)row * kC + c4 * 4];
  }
}

// ---------------------------------------------------------------- pool (gather + max over group)
__global__ __launch_bounds__(256) void k_pool(const float* __restrict__ feats,
                                              const int* __restrict__ gidx,
                                              float* __restrict__ x0) {
  int w = blockIdx.x, t = threadIdx.x;
  __shared__ int rows[kG];
  if (t < kG) rows[t] = gidx[w * kG + t];
  __syncthreads();
  float m = -INFINITY;
  #pragma unroll 4
  for (int g = 0; g < kG; ++g)
    m = fmaxf(m, feats[(size_t)rows[g] * kC + t]);
  x0[w * kC + t] = m;
}

// ---------------------------------------------------------------- generic tiled f32 GEMM: C = act(A*B^T + bias)
template <bool RELU>
__global__ __launch_bounds__(256) void k_gemm(const float* __restrict__ A, int lda,
                                              const float* __restrict__ B, int ldb,
                                              const float* __restrict__ bias,
                                              float* __restrict__ Cc, int ldc,
                                              int K) {
  __shared__ __align__(16) float As[16][68];
  __shared__ __align__(16) float Bs[16][68];
  const int n0 = blockIdx.x * 64;
  const int m0 = blockIdx.y * 64;
  const int t = threadIdx.x;
  const int tx = t & 15, ty = t >> 4;
  float acc[4][4] = {};
  for (int k0 = 0; k0 < K; k0 += 16) {
    #pragma unroll
    for (int it = 0; it < 4; ++it) {
      int idx = t + it * 256;             // 0..1023
      int kk = idx & 15, mm = idx >> 4;   // mm 0..63
      As[kk][mm] = A[(size_t)(m0 + mm) * lda + k0 + kk];
      Bs[kk][mm] = B[(size_t)(n0 + mm) * ldb + k0 + kk];
    }
    __syncthreads();
    #pragma unroll
    for (int kk = 0; kk < 16; ++kk) {
      float4 a4 = *(const float4*)&As[kk][ty * 4];
      float4 b4 = *(const float4*)&Bs[kk][tx * 4];
      float av[4] = {a4.x, a4.y, a4.z, a4.w};
      float bv[4] = {b4.x, b4.y, b4.z, b4.w};
      #pragma unroll
      for (int i = 0; i < 4; ++i)
        #pragma unroll
        for (int j = 0; j < 4; ++j)
          acc[i][j] = fmaf(av[i], bv[j], acc[i][j]);
    }
    __syncthreads();
  }
  #pragma unroll
  for (int i = 0; i < 4; ++i) {
    int row = m0 + ty * 4 + i;
    int col = n0 + tx * 4;
    float4 v;
    v.x = acc[i][0] + bias[col + 0];
    v.y = acc[i][1] + bias[col + 1];
    v.z = acc[i][2] + bias[col + 2];
    v.w = acc[i][3] + bias[col + 3];
    if (RELU) {
      v.x = fmaxf(v.x, 0.f); v.y = fmaxf(v.y, 0.f);
      v.z = fmaxf(v.z, 0.f); v.w = fmaxf(v.w, 0.f);
    }
    *(float4*)&Cc[(size_t)row * ldc + col] = v;
  }
}

// ---------------------------------------------------------------- qkv -> per-head contiguous Q(scaled),K,V [BH][S][32]
__global__ __launch_bounds__(256) void k_qkvt(const float* __restrict__ qkv,
                                              float* __restrict__ Qh,
                                              float* __restrict__ Kh,
                                              float* __restrict__ Vh) {
  const float scale = 0.17677669529663687f;   // 1/sqrt(32)
  int r = blockIdx.x;            // 0..4095  (b*1024+s)
  int b = r >> 10, s = r & 1023;
  int t = threadIdx.x;
  int h = t >> 5, d = t & 31;
  size_t src = (size_t)r * (3 * kC);
  float qv = qkv[src + t] * scale;
  float kv = qkv[src + kC + t];
  float vv = qkv[src + 2 * kC + t];
  size_t dst = (((size_t)(b * kNH + h) * kS) + s) * kHD + d;
  Qh[dst] = qv;
  Kh[dst] = kv;
  Vh[dst] = vv;
}

// ---------------------------------------------------------------- flash attention: 64 q-rows x 64-key tiles, f32
__global__ __launch_bounds__(256) void k_attn(const float* __restrict__ Qh,
                                              const float* __restrict__ Kh,
                                              const float* __restrict__ Vh,
                                              float* __restrict__ attn_out) {
  const int q0 = blockIdx.x * 64;
  const int bh = blockIdx.y;           // b*8+h
  const int b = bh >> 3, h = bh & 7;
  const int t = threadIdx.x;
  const int tx = t & 15, ty = t >> 4;

  __shared__ __align__(16) float Qs[32][68];
  __shared__ __align__(16) float Ks[32][68];
  __shared__ __align__(16) float Vs[64][36];
  __shared__ __align__(16) float Ps[64][68];

  const float* qbase = Qh + ((size_t)bh * kS + q0) * kHD;
  const float* kbase = Kh + (size_t)bh * kS * kHD;
  const float* vbase = Vh + (size_t)bh * kS * kHD;

  // stage Q tile transposed: Qs[d][qr]
  #pragma unroll
  for (int i = 0; i < 8; ++i) {
    int idx = t + i * 256;
    int qr = idx >> 5, d = idx & 31;
    Qs[d][qr] = qbase[(size_t)qr * kHD + d];
  }

  float m[4], l[4], O[4][2];
  #pragma unroll
  for (int i = 0; i < 4; ++i) { m[i] = -INFINITY; l[i] = 0.f; O[i][0] = 0.f; O[i][1] = 0.f; }

  for (int k0 = 0; k0 < kS; k0 += 64) {
    // stage K (transposed) and V tiles
    #pragma unroll
    for (int i = 0; i < 8; ++i) {
      int idx = t + i * 256;
      int kr = idx >> 5, d = idx & 31;
      float kv = kbase[(size_t)(k0 + kr) * kHD + d];
      float vv = vbase[(size_t)(k0 + kr) * kHD + d];
      Ks[d][kr] = kv;
      Vs[kr][d] = vv;
    }
    __syncthreads();

    // scores: 4x4 per thread, rows ty*4.., cols tx*4..
    float acc[4][4] = {};
    #pragma unroll
    for (int d = 0; d < 32; ++d) {
      float4 a4 = *(const float4*)&Qs[d][ty * 4];
      float4 b4 = *(const float4*)&Ks[d][tx * 4];
      float av[4] = {a4.x, a4.y, a4.z, a4.w};
      float bv[4] = {b4.x, b4.y, b4.z, b4.w};
      #pragma unroll
      for (int i = 0; i < 4; ++i)
        #pragma unroll
        for (int j = 0; j < 4; ++j)
          acc[i][j] = fmaf(av[i], bv[j], acc[i][j]);
    }

    // online softmax across the 16-lane row group (same ty)
    #pragma unroll
    for (int i = 0; i < 4; ++i) {
      float tmax = fmaxf(fmaxf(acc[i][0], acc[i][1]), fmaxf(acc[i][2], acc[i][3]));
      #pragma unroll
      for (int off = 8; off; off >>= 1) tmax = fmaxf(tmax, __shfl_xor(tmax, off, 16));
      float newm = fmaxf(m[i], tmax);
      float alpha = __expf(m[i] - newm);
      float ps = 0.f;
      #pragma unroll
      for (int j = 0; j < 4; ++j) {
        acc[i][j] = __expf(acc[i][j] - newm);
        ps += acc[i][j];
      }
      #pragma unroll
      for (int off = 8; off; off >>= 1) ps += __shfl_xor(ps, off, 16);
      l[i] = l[i] * alpha + ps;
      m[i] = newm;
      O[i][0] *= alpha;
      O[i][1] *= alpha;
      *(float4*)&Ps[ty * 4 + i][tx * 4] =
          make_float4(acc[i][0], acc[i][1], acc[i][2], acc[i][3]);
    }
    __syncthreads();

    // PV: thread owns (4 q-rows) x (d = tx*2, tx*2+1)
    #pragma unroll 8
    for (int k = 0; k < 64; ++k) {
      float2 v2 = *(const float2*)&Vs[k][tx * 2];
      #pragma unroll
      for (int i = 0; i < 4; ++i) {
        float p = Ps[ty * 4 + i][k];
        O[i][0] = fmaf(p, v2.x, O[i][0]);
        O[i][1] = fmaf(p, v2.y, O[i][1]);
      }
    }
    __syncthreads();
  }

  #pragma unroll
  for (int i = 0; i < 4; ++i) {
    float invl = 1.0f / l[i];
    size_t row = (size_t)b * kS + q0 + ty * 4 + i;
    *(float2*)&attn_out[row * kC + h * kHD + tx * 2] =
        make_float2(O[i][0] * invl, O[i][1] * invl);
  }
}

// ---------------------------------------------------------------- layer norm with residual: out = LN(y + r)
__global__ __launch_bounds__(256) void k_ln(const float* __restrict__ Y,
                                            const float* __restrict__ R,
                                            const float* __restrict__ g,
                                            const float* __restrict__ bb,
                                            float* __restrict__ Out) {
  int row = blockIdx.x, t = threadIdx.x;
  int wv = t >> 6, lane = t & 63;
  float v = Y[(size_t)row * kC + t] + R[(size_t)row * kC + t];
  __shared__ float red1[4], red2[4];
  float s = v;
  #pragma unroll
  for (int off = 32; off; off >>= 1) s += __shfl_xor(s, off);
  if (lane == 0) red1[wv] = s;
  __syncthreads();
  float mu = (red1[0] + red1[1] + red1[2] + red1[3]) * (1.0f / kC);
  float d = v - mu;
  float sq = d * d;
  #pragma unroll
  for (int off = 32; off; off >>= 1) sq += __shfl_xor(sq, off);
  if (lane == 0) red2[wv] = sq;
  __syncthreads();
  float var = (red2[0] + red2[1] + red2[2] + red2[3]) * (1.0f / kC);
  Out[(size_t)row * kC + t] = d * rsqrtf(var + 1e-5f) * g[t] + bb[t];
}

// ---------------------------------------------------------------- W2 -> bf16: W2B[c][k] = bf16(proj_w[c][256+k])
__global__ __launch_bounds__(256) void k_w2bf(const float* __restrict__ proj_w,
                                              unsigned short* __restrict__ W2B) {
  int c = blockIdx.x, k = threadIdx.x;
  W2B[c * kC + k] = f2bf(proj_w[(size_t)c * (2 * kC) + kC + k]);
}

// ---------------------------------------------------------------- fuse: bf16 MFMA GEMM (gathered A) + scatter
// out[dstrow[i]][c] = sum_k feats[srcrow[i]][k]*W2[c][k] + base[wwin[i]][c]
__global__ __launch_bounds__(256) void k_fuse(const float* __restrict__ feats,
                                              const int* __restrict__ gidx,
                                              const int* __restrict__ wlist,
                                              const int* __restrict__ cnt,
                                              const int* __restrict__ win2flat,
                                              const int* __restrict__ x_idx,
                                              const float* __restrict__ base,
                                              const unsigned short* __restrict__ W2B,
                                              float* __restrict__ out) {
  const int count = cnt[0];
  const int r0 = blockIdx.x * 64;
  if (r0 >= count) return;
  const int nr = min(64, count - r0);
  const int t = threadIdx.x;
  const int lane = t & 63, w = t >> 6;

  __shared__ __align__(16) unsigned short As[64 * 256];   // 32KB, XOR-swizzled rows
  __shared__ int dstrow[64], wwin[64], srcrow[64];

  if (t < 64) {
    int rr = min(r0 + t, count - 1);      // clamp; padded rows never stored
    int i = wlist[rr];
    int j = win2flat[i];
    srcrow[t] = gidx[j];
    wwin[t] = j >> 6;
    dstrow[t] = x_idx[i];
  }
  __syncthreads();

  // stage gathered A rows as bf16 into swizzled LDS (wave per row, 16 iters)
  for (int i = 0; i < 16; ++i) {
    int row = i * 4 + w;
    float4 f4 = *(const float4*)&feats[(size_t)srcrow[row] * kC + lane * 4];
    ushort4 b4;
    b4.x = f2bf(f4.x); b4.y = f2bf(f4.y); b4.z = f2bf(f4.z); b4.w = f2bf(f4.w);
    unsigned int off = (((unsigned)row * 512u) + (unsigned)lane * 8u) ^ (((unsigned)row & 7u) << 4);
    *(ushort4*)((char*)As + off) = b4;
  }
  __syncthreads();

  // per-wave 64 rows x 64 cols via 4x4 MFMA tiles
  const int c0 = w * 64;
  const int kb = lane >> 4;     // 0..3 (k-group / row-group)
  const int lr = lane & 15;
  f32x4 acc[4][4] = {};
  for (int ks = 0; ks < 8; ++ks) {
    const int k0 = ks * 32;
    bf16x8 a[4], b[4];
    #pragma unroll
    for (int rt = 0; rt < 4; ++rt) {
      int row = rt * 16 + lr;
      unsigned int off = (((unsigned)row * 512u) + (unsigned)(k0 + kb * 8) * 2u) ^
                         (((unsigned)row & 7u) << 4);
      a[rt] = *(const bf16x8*)((const char*)As + off);
    }
    #pragma unroll
    for (int ct = 0; ct < 4; ++ct) {
      int c = c0 + ct * 16 + lr;
      b[ct] = *(const bf16x8*)&W2B[(size_t)c * kC + k0 + kb * 8];
    }
    #pragma unroll
    for (int rt = 0; rt < 4; ++rt)
      #pragma unroll
      for (int ct = 0; ct < 4; ++ct)
        acc[rt][ct] = __builtin_amdgcn_mfma_f32_16x16x32_bf16(a[rt], b[ct], acc[rt][ct], 0, 0, 0);
  }

  // epilogue: add base, scatter (C/D layout: row=(lane>>4)*4+r, col=lane&15)
  #pragma unroll
  for (int rt = 0; rt < 4; ++rt) {
    #pragma unroll
    for (int r = 0; r < 4; ++r) {
      int row = rt * 16 + kb * 4 + r;
      if (row < nr) {
        size_t orow = (size_t)dstrow[row] * kC;
        size_t brow = (size_t)wwin[row] * kC;
        #pragma unroll
        for (int ct = 0; ct < 4; ++ct) {
          int c = c0 + ct * 16 + lr;
          out[orow + c] = acc[rt][ct][r] + base[brow + c];
        }
      }
    }
  }
}

// ---------------------------------------------------------------- launch
extern "C" void kernel_launch(void* const* d_in, const int* in_sizes, int n_in,
                              void* d_out, int out_size, void* d_ws, size_t ws_size,
                              hipStream_t stream) {
  const float* feats      = (const float*)d_in[0];
  const int*   x_idx      = (const int*)d_in[1];
  const int*   flat2win   = (const int*)d_in[2];
  const int*   win2flat   = (const int*)d_in[3];
  const float* in_proj_w  = (const float*)d_in[4];
  const float* in_proj_b  = (const float*)d_in[5];
  const float* out_proj_w = (const float*)d_in[6];
  const float* out_proj_b = (const float*)d_in[7];
  const float* lin1_w     = (const float*)d_in[8];
  const float* lin1_b     = (const float*)d_in[9];
  const float* lin2_w     = (const float*)d_in[10];
  const float* lin2_b     = (const float*)d_in[11];
  const float* ln1_g      = (const float*)d_in[12];
  const float* ln1_b      = (const float*)d_in[13];
  const float* ln2_g      = (const float*)d_in[14];
  const float* ln2_b      = (const float*)d_in[15];
  const float* proj_w     = (const float*)d_in[16];
  const float* proj_b     = (const float*)d_in[17];

  char* ws = (char*)d_ws;
  int*   gidx   = (int*)(ws + OFF_GIDX);
  int*   winner = (int*)(ws + OFF_WINNER);
  int*   wlist  = (int*)(ws + OFF_WLIST);
  int*   cnt    = (int*)(ws + OFF_CNT);
  float* x0     = (float*)(ws + OFF_X0);
  float* qkv    = (float*)(ws + OFF_QKV);
  float* attn   = (float*)(ws + OFF_ATTN);
  float* y      = (float*)(ws + OFF_Y);
  float* x1     = (float*)(ws + OFF_X1);
  float* ff1    = (float*)(ws + OFF_FF1);
  float* x2     = (float*)(ws + OFF_X2);
  float* basep  = (float*)(ws + OFF_BASE);
  unsigned short* W2B = (unsigned short*)(ws + OFF_W2B);
  float* out    = (float*)d_out;

  // Q/K/V per-head buffers live in regions that are dead during attention
  float* Qh = y;                         // 4MB
  float* Kh = x1;                        // 4MB
  float* Vh = ff1;                       // first 4MB of the 32MB region

  k_init<<<kLPAD / 256, 256, 0, stream>>>(x_idx, flat2win, gidx, winner, cnt);
  k_winner<<<kL / 256, 256, 0, stream>>>(x_idx, winner);
  k_compact<<<kL / 256, 256, 0, stream>>>(x_idx, winner, wlist, cnt);
  // copy only rows NOT overwritten by the fuse scatter (winner < 0)
  k_copy<<<kL / 4, 256, 0, stream>>>(feats, winner, out);
  k_pool<<<kNW, 256, 0, stream>>>(feats, gidx, x0);

  // qkv = x0 @ in_proj_w^T + b   [4096, 768]
  k_gemm<false><<<dim3(3 * kC / 64, kNW / 64), 256, 0, stream>>>(
      x0, kC, in_proj_w, kC, in_proj_b, qkv, 3 * kC, kC);
  k_qkvt<<<kNW, 256, 0, stream>>>(qkv, Qh, Kh, Vh);
  k_attn<<<dim3(kS / 64, kBS * kNH), 256, 0, stream>>>(Qh, Kh, Vh, attn);
  // y1 = attn @ out_proj^T + b
  k_gemm<false><<<dim3(kC / 64, kNW / 64), 256, 0, stream>>>(
      attn, kC, out_proj_w, kC, out_proj_b, y, kC, kC);
  k_ln<<<kNW, 256, 0, stream>>>(y, x0, ln1_g, ln1_b, x1);
  // ff1 = relu(x1 @ lin1^T + b)  [4096, 2048]
  k_gemm<true><<<dim3(kFF / 64, kNW / 64), 256, 0, stream>>>(
      x1, kC, lin1_w, kC, lin1_b, ff1, kFF, kC);
  // y2 = ff1 @ lin2^T + b
  k_gemm<false><<<dim3(kC / 64, kNW / 64), 256, 0, stream>>>(
      ff1, kFF, lin2_w, kFF, lin2_b, y, kC, kFF);
  k_ln<<<kNW, 256, 0, stream>>>(y, x1, ln2_g, ln2_b, x2);
  // base = x2 @ proj_w[:, :256]^T + proj_b   (ldb = 512)
  k_gemm<false><<<dim3(kC / 64, kNW / 64), 256, 0, stream>>>(
      x2, kC, proj_w, 2 * kC, proj_b, basep, kC, kC);
  k_w2bf<<<kC, 256, 0, stream>>>(proj_w, W2B);
  k_fuse<<<kL / 64, 256, 0, stream>>>(feats, gidx, wlist, cnt, win2flat, x_idx,
                                      basep, W2B, out);
}

// Round 4
// 500.374 us; speedup vs baseline: 2.8738x; 1.2664x over previous
//
#include <hip/hip_runtime.h>
#include <math.h>

namespace {
constexpr int kL    = 262144;
constexpr int kC    = 256;
constexpr int kNH   = 8;
constexpr int kG    = 64;
constexpr int kFF   = 2048;
constexpr int kLPAD = 262144;
constexpr int kBS   = 4;
constexpr int kNW   = kLPAD / kG;   // 4096
constexpr int kS    = kNW / kBS;    // 1024
constexpr int kHD   = kC / kNH;     // 32

constexpr size_t MB        = 1024 * 1024;
constexpr size_t OFF_GIDX   = 0;        // int[LPAD]   1MB
constexpr size_t OFF_WINNER = 1 * MB;   // int[L]      1MB
constexpr size_t OFF_WLIST  = 2 * MB;   // int[L]      1MB
constexpr size_t OFF_CNT    = 3 * MB;   // int[1]
constexpr size_t OFF_X0     = 4 * MB;   // f32[4096*256]  4MB
constexpr size_t OFF_BASE   = 8 * MB;   // f32[4096*256]  4MB (reuses qkv region)
constexpr size_t OFF_QKV    = 8 * MB;   // f32[4096*768]  12MB
constexpr size_t OFF_ATTN   = 20 * MB;  // f32[4096*256]  4MB
constexpr size_t OFF_X2     = 20 * MB;  // reuses attn
constexpr size_t OFF_Y      = 24 * MB;  // f32[4096*256]  4MB (y1 then y2); Qh during attn
constexpr size_t OFF_X1     = 28 * MB;  // f32[4096*256]  4MB; Kh during attn
constexpr size_t OFF_FF1    = 32 * MB;  // f32[4096*2048] 32MB; Vh during attn -> end 64MB
// bf16 weights (cast once per launch)
constexpr size_t OFF_WINB   = 64 * MB;              // bf16[768*256]  384KB
constexpr size_t OFF_WOUTB  = OFF_WINB  + 512 * 1024;  // bf16[256*256] 128KB
constexpr size_t OFF_W1B    = OFF_WOUTB + 256 * 1024;  // bf16[2048*256] 1MB
constexpr size_t OFF_W2B    = OFF_W1B   + 1536 * 1024; // bf16[256*2048] 1MB
constexpr size_t OFF_WP1B   = OFF_W2B   + 1536 * 1024; // bf16[256*256] 128KB
constexpr size_t OFF_WP2B   = OFF_WP1B  + 256 * 1024;  // bf16[256*256] 128KB

typedef __attribute__((ext_vector_type(8))) short bf16x8;
typedef __attribute__((ext_vector_type(4))) float f32x4;

__device__ inline unsigned short f2bf(float f) {
  union { float f; unsigned int u; } x; x.f = f;
  unsigned int r = x.u + 0x7fff + ((x.u >> 16) & 1);   // RNE
  return (unsigned short)(r >> 16);
}
} // namespace

// ---------------------------------------------------------------- init
__global__ __launch_bounds__(256) void k_init(const int* __restrict__ x_idx,
                                              const int* __restrict__ flat2win,
                                              int* __restrict__ gidx,
                                              int* __restrict__ winner,
                                              int* __restrict__ cnt) {
  int j = blockIdx.x * 256 + threadIdx.x;          // grid covers LPAD == L
  gidx[j] = x_idx[flat2win[j]];
  winner[j] = -1;
  if (j == 0) cnt[0] = 0;
}

__global__ __launch_bounds__(256) void k_winner(const int* __restrict__ x_idx,
                                                int* __restrict__ winner) {
  int i = blockIdx.x * 256 + threadIdx.x;
  atomicMax(&winner[x_idx[i]], i);
}

__global__ __launch_bounds__(256) void k_compact(const int* __restrict__ x_idx,
                                                 const int* __restrict__ winner,
                                                 int* __restrict__ wlist,
                                                 int* __restrict__ cnt) {
  int i = blockIdx.x * 256 + threadIdx.x;
  if (winner[x_idx[i]] == i) {
    int p = atomicAdd(cnt, 1);
    wlist[p] = i;
  }
}

// ---------------------------------------------------------------- selective copy: rows not overwritten by fuse scatter
__global__ __launch_bounds__(256) void k_copy(const float* __restrict__ feats,
                                              const int* __restrict__ winner,
                                              float* __restrict__ out) {
  size_t idx = (size_t)blockIdx.x * 256 + threadIdx.x;   // one float4 each
  int row = (int)(idx >> 6);
  int c4 = (int)(idx & 63);
  if (winner[row] < 0) {                                  // wave-uniform (one row per wave)
    *(float4*)&out[(size_t)row * kC + c4 * 4] =
        *(const float4*)&feats[(size_t)row * kC + c4 * 4];
  }
}

// ---------------------------------------------------------------- pool (gather + max over group)
__global__ __launch_bounds__(256) void k_pool(const float* __restrict__ feats,
                                              const int* __restrict__ gidx,
                                              float* __restrict__ x0) {
  int w = blockIdx.x, t = threadIdx.x;
  __shared__ int rows[kG];
  if (t < kG) rows[t] = gidx[w * kG + t];
  __syncthreads();
  float m = -INFINITY;
  #pragma unroll 4
  for (int g = 0; g < kG; ++g)
    m = fmaxf(m, feats[(size_t)rows[g] * kC + t]);
  x0[w * kC + t] = m;
}

// ---------------------------------------------------------------- weight casts
__global__ __launch_bounds__(256) void k_cast(const float* __restrict__ src,
                                              unsigned short* __restrict__ dst,
                                              int n4) {
  int i = blockIdx.x * 256 + threadIdx.x;
  if (i < n4) {
    float4 v = ((const float4*)src)[i];
    ushort4 b;
    b.x = f2bf(v.x); b.y = f2bf(v.y); b.z = f2bf(v.z); b.w = f2bf(v.w);
    ((ushort4*)dst)[i] = b;
  }
}

__global__ __launch_bounds__(256) void k_wprep(const float* __restrict__ proj_w,
                                               unsigned short* __restrict__ WP1,
                                               unsigned short* __restrict__ WP2) {
  int c = blockIdx.x, t = threadIdx.x;
  WP1[c * kC + t] = f2bf(proj_w[(size_t)c * (2 * kC) + t]);
  WP2[c * kC + t] = f2bf(proj_w[(size_t)c * (2 * kC) + kC + t]);
}

// ---------------------------------------------------------------- bf16 MFMA GEMM: C = act(A @ Wb^T + bias)
// A f32 [M][lda], Wb bf16 [N][K] row-major. Block: 64 rows x 256 cols, 4 waves.
template <bool RELU>
__global__ __launch_bounds__(256) void k_gemm_bf(const float* __restrict__ A, int lda,
                                                 const unsigned short* __restrict__ Wb,
                                                 const float* __restrict__ bias,
                                                 float* __restrict__ Cc, int ldc,
                                                 int K) {
  const int m0 = blockIdx.y * 64;
  const int nb = blockIdx.x * 256;
  const int t = threadIdx.x;
  const int lane = t & 63, w = t >> 6;
  const int c0 = nb + w * 64;
  const int kb = lane >> 4;     // 0..3
  const int lr = lane & 15;

  __shared__ __align__(16) unsigned short As[64 * 256];   // 32KB, XOR-swizzled rows

  f32x4 acc[4][4] = {};
  for (int kc = 0; kc < K; kc += 256) {
    // stage 64x256 f32->bf16 chunk of A (wave per row, 16 iters)
    #pragma unroll
    for (int i = 0; i < 16; ++i) {
      int row = i * 4 + w;
      float4 f4 = *(const float4*)&A[(size_t)(m0 + row) * lda + kc + lane * 4];
      ushort4 b4;
      b4.x = f2bf(f4.x); b4.y = f2bf(f4.y); b4.z = f2bf(f4.z); b4.w = f2bf(f4.w);
      unsigned int off = (((unsigned)row * 512u) + (unsigned)lane * 8u) ^ (((unsigned)row & 7u) << 4);
      *(ushort4*)((char*)As + off) = b4;
    }
    __syncthreads();

    #pragma unroll
    for (int ks = 0; ks < 8; ++ks) {
      const int k0 = ks * 32;
      bf16x8 a[4], b[4];
      #pragma unroll
      for (int rt = 0; rt < 4; ++rt) {
        int row = rt * 16 + lr;
        unsigned int off = (((unsigned)row * 512u) + (unsigned)(k0 + kb * 8) * 2u) ^
                           (((unsigned)row & 7u) << 4);
        a[rt] = *(const bf16x8*)((const char*)As + off);
      }
      #pragma unroll
      for (int ct = 0; ct < 4; ++ct) {
        int c = c0 + ct * 16 + lr;
        b[ct] = *(const bf16x8*)&Wb[(size_t)c * K + kc + k0 + kb * 8];
      }
      #pragma unroll
      for (int rt = 0; rt < 4; ++rt)
        #pragma unroll
        for (int ct = 0; ct < 4; ++ct)
          acc[rt][ct] = __builtin_amdgcn_mfma_f32_16x16x32_bf16(a[rt], b[ct], acc[rt][ct], 0, 0, 0);
    }
    __syncthreads();
  }

  // epilogue (C/D layout: row=(lane>>4)*4+r, col=lane&15)
  #pragma unroll
  for (int rt = 0; rt < 4; ++rt) {
    #pragma unroll
    for (int r = 0; r < 4; ++r) {
      int row = m0 + rt * 16 + kb * 4 + r;
      #pragma unroll
      for (int ct = 0; ct < 4; ++ct) {
        int c = c0 + ct * 16 + lr;
        float v = acc[rt][ct][r] + bias[c];
        if (RELU) v = fmaxf(v, 0.f);
        Cc[(size_t)row * ldc + c] = v;
      }
    }
  }
}

// ---------------------------------------------------------------- qkv -> per-head contiguous Q(scaled),K,V [BH][S][32]
__global__ __launch_bounds__(256) void k_qkvt(const float* __restrict__ qkv,
                                              float* __restrict__ Qh,
                                              float* __restrict__ Kh,
                                              float* __restrict__ Vh) {
  const float scale = 0.17677669529663687f;   // 1/sqrt(32)
  int r = blockIdx.x;            // 0..4095  (b*1024+s)
  int b = r >> 10, s = r & 1023;
  int t = threadIdx.x;
  int h = t >> 5, d = t & 31;
  size_t src = (size_t)r * (3 * kC);
  float qv = qkv[src + t] * scale;
  float kv = qkv[src + kC + t];
  float vv = qkv[src + 2 * kC + t];
  size_t dst = (((size_t)(b * kNH + h) * kS) + s) * kHD + d;
  Qh[dst] = qv;
  Kh[dst] = kv;
  Vh[dst] = vv;
}

// ---------------------------------------------------------------- flash attention: 64 q-rows x 64-key tiles, f32
__global__ __launch_bounds__(256) void k_attn(const float* __restrict__ Qh,
                                              const float* __restrict__ Kh,
                                              const float* __restrict__ Vh,
                                              float* __restrict__ attn_out) {
  const int q0 = blockIdx.x * 64;
  const int bh = blockIdx.y;           // b*8+h
  const int b = bh >> 3, h = bh & 7;
  const int t = threadIdx.x;
  const int tx = t & 15, ty = t >> 4;

  __shared__ __align__(16) float Qs[32][68];
  __shared__ __align__(16) float Ks[32][68];
  __shared__ __align__(16) float Vs[64][36];
  __shared__ __align__(16) float Ps[64][68];

  const float* qbase = Qh + ((size_t)bh * kS + q0) * kHD;
  const float* kbase = Kh + (size_t)bh * kS * kHD;
  const float* vbase = Vh + (size_t)bh * kS * kHD;

  // stage Q tile transposed: Qs[d][qr]
  #pragma unroll
  for (int i = 0; i < 8; ++i) {
    int idx = t + i * 256;
    int qr = idx >> 5, d = idx & 31;
    Qs[d][qr] = qbase[(size_t)qr * kHD + d];
  }

  float m[4], l[4], O[4][2];
  #pragma unroll
  for (int i = 0; i < 4; ++i) { m[i] = -INFINITY; l[i] = 0.f; O[i][0] = 0.f; O[i][1] = 0.f; }

  for (int k0 = 0; k0 < kS; k0 += 64) {
    // stage K (transposed) and V tiles
    #pragma unroll
    for (int i = 0; i < 8; ++i) {
      int idx = t + i * 256;
      int kr = idx >> 5, d = idx & 31;
      float kv = kbase[(size_t)(k0 + kr) * kHD + d];
      float vv = vbase[(size_t)(k0 + kr) * kHD + d];
      Ks[d][kr] = kv;
      Vs[kr][d] = vv;
    }
    __syncthreads();

    // scores: 4x4 per thread, rows ty*4.., cols tx*4..
    float acc[4][4] = {};
    #pragma unroll
    for (int d = 0; d < 32; ++d) {
      float4 a4 = *(const float4*)&Qs[d][ty * 4];
      float4 b4 = *(const float4*)&Ks[d][tx * 4];
      float av[4] = {a4.x, a4.y, a4.z, a4.w};
      float bv[4] = {b4.x, b4.y, b4.z, b4.w};
      #pragma unroll
      for (int i = 0; i < 4; ++i)
        #pragma unroll
        for (int j = 0; j < 4; ++j)
          acc[i][j] = fmaf(av[i], bv[j], acc[i][j]);
    }

    // online softmax across the 16-lane row group (same ty)
    #pragma unroll
    for (int i = 0; i < 4; ++i) {
      float tmax = fmaxf(fmaxf(acc[i][0], acc[i][1]), fmaxf(acc[i][2], acc[i][3]));
      #pragma unroll
      for (int off = 8; off; off >>= 1) tmax = fmaxf(tmax, __shfl_xor(tmax, off, 16));
      float newm = fmaxf(m[i], tmax);
      float alpha = __expf(m[i] - newm);
      float ps = 0.f;
      #pragma unroll
      for (int j = 0; j < 4; ++j) {
        acc[i][j] = __expf(acc[i][j] - newm);
        ps += acc[i][j];
      }
      #pragma unroll
      for (int off = 8; off; off >>= 1) ps += __shfl_xor(ps, off, 16);
      l[i] = l[i] * alpha + ps;
      m[i] = newm;
      O[i][0] *= alpha;
      O[i][1] *= alpha;
      *(float4*)&Ps[ty * 4 + i][tx * 4] =
          make_float4(acc[i][0], acc[i][1], acc[i][2], acc[i][3]);
    }
    __syncthreads();

    // PV: thread owns (4 q-rows) x (d = tx*2, tx*2+1)
    #pragma unroll 8
    for (int k = 0; k < 64; ++k) {
      float2 v2 = *(const float2*)&Vs[k][tx * 2];
      #pragma unroll
      for (int i = 0; i < 4; ++i) {
        float p = Ps[ty * 4 + i][k];
        O[i][0] = fmaf(p, v2.x, O[i][0]);
        O[i][1] = fmaf(p, v2.y, O[i][1]);
      }
    }
    __syncthreads();
  }

  #pragma unroll
  for (int i = 0; i < 4; ++i) {
    float invl = 1.0f / l[i];
    size_t row = (size_t)b * kS + q0 + ty * 4 + i;
    *(float2*)&attn_out[row * kC + h * kHD + tx * 2] =
        make_float2(O[i][0] * invl, O[i][1] * invl);
  }
}

// ---------------------------------------------------------------- layer norm with residual: out = LN(y + r)
__global__ __launch_bounds__(256) void k_ln(const float* __restrict__ Y,
                                            const float* __restrict__ R,
                                            const float* __restrict__ g,
                                            const float* __restrict__ bb,
                                            float* __restrict__ Out) {
  int row = blockIdx.x, t = threadIdx.x;
  int wv = t >> 6, lane = t & 63;
  float v = Y[(size_t)row * kC + t] + R[(size_t)row * kC + t];
  __shared__ float red1[4], red2[4];
  float s = v;
  #pragma unroll
  for (int off = 32; off; off >>= 1) s += __shfl_xor(s, off);
  if (lane == 0) red1[wv] = s;
  __syncthreads();
  float mu = (red1[0] + red1[1] + red1[2] + red1[3]) * (1.0f / kC);
  float d = v - mu;
  float sq = d * d;
  #pragma unroll
  for (int off = 32; off; off >>= 1) sq += __shfl_xor(sq, off);
  if (lane == 0) red2[wv] = sq;
  __syncthreads();
  float var = (red2[0] + red2[1] + red2[2] + red2[3]) * (1.0f / kC);
  Out[(size_t)row * kC + t] = d * rsqrtf(var + 1e-5f) * g[t] + bb[t];
}

// ---------------------------------------------------------------- fuse: bf16 MFMA GEMM (gathered A) + scatter
__global__ __launch_bounds__(256) void k_fuse(const float* __restrict__ feats,
                                              const int* __restrict__ gidx,
                                              const int* __restrict__ wlist,
                                              const int* __restrict__ cnt,
                                              const int* __restrict__ win2flat,
                                              const int* __restrict__ x_idx,
                                              const float* __restrict__ base,
                                              const unsigned short* __restrict__ W2B,
                                              float* __restrict__ out) {
  const int count = cnt[0];
  const int r0 = blockIdx.x * 64;
  if (r0 >= count) return;
  const int nr = min(64, count - r0);
  const int t = threadIdx.x;
  const int lane = t & 63, w = t >> 6;

  __shared__ __align__(16) unsigned short As[64 * 256];   // 32KB, XOR-swizzled rows
  __shared__ int dstrow[64], wwin[64], srcrow[64];

  if (t < 64) {
    int rr = min(r0 + t, count - 1);      // clamp; padded rows never stored
    int i = wlist[rr];
    int j = win2flat[i];
    srcrow[t] = gidx[j];
    wwin[t] = j >> 6;
    dstrow[t] = x_idx[i];
  }
  __syncthreads();

  // stage gathered A rows as bf16 into swizzled LDS (wave per row, 16 iters)
  for (int i = 0; i < 16; ++i) {
    int row = i * 4 + w;
    float4 f4 = *(const float4*)&feats[(size_t)srcrow[row] * kC + lane * 4];
    ushort4 b4;
    b4.x = f2bf(f4.x); b4.y = f2bf(f4.y); b4.z = f2bf(f4.z); b4.w = f2bf(f4.w);
    unsigned int off = (((unsigned)row * 512u) + (unsigned)lane * 8u) ^ (((unsigned)row & 7u) << 4);
    *(ushort4*)((char*)As + off) = b4;
  }
  __syncthreads();

  // per-wave 64 rows x 64 cols via 4x4 MFMA tiles
  const int c0 = w * 64;
  const int kb = lane >> 4;     // 0..3 (k-group / row-group)
  const int lr = lane & 15;
  f32x4 acc[4][4] = {};
  for (int ks = 0; ks < 8; ++ks) {
    const int k0 = ks * 32;
    bf16x8 a[4], b[4];
    #pragma unroll
    for (int rt = 0; rt < 4; ++rt) {
      int row = rt * 16 + lr;
      unsigned int off = (((unsigned)row * 512u) + (unsigned)(k0 + kb * 8) * 2u) ^
                         (((unsigned)row & 7u) << 4);
      a[rt] = *(const bf16x8*)((const char*)As + off);
    }
    #pragma unroll
    for (int ct = 0; ct < 4; ++ct) {
      int c = c0 + ct * 16 + lr;
      b[ct] = *(const bf16x8*)&W2B[(size_t)c * kC + k0 + kb * 8];
    }
    #pragma unroll
    for (int rt = 0; rt < 4; ++rt)
      #pragma unroll
      for (int ct = 0; ct < 4; ++ct)
        acc[rt][ct] = __builtin_amdgcn_mfma_f32_16x16x32_bf16(a[rt], b[ct], acc[rt][ct], 0, 0, 0);
  }

  // epilogue: add base, scatter (C/D layout: row=(lane>>4)*4+r, col=lane&15)
  #pragma unroll
  for (int rt = 0; rt < 4; ++rt) {
    #pragma unroll
    for (int r = 0; r < 4; ++r) {
      int row = rt * 16 + kb * 4 + r;
      if (row < nr) {
        size_t orow = (size_t)dstrow[row] * kC;
        size_t brow = (size_t)wwin[row] * kC;
        #pragma unroll
        for (int ct = 0; ct < 4; ++ct) {
          int c = c0 + ct * 16 + lr;
          out[orow + c] = acc[rt][ct][r] + base[brow + c];
        }
      }
    }
  }
}

// ---------------------------------------------------------------- launch
extern "C" void kernel_launch(void* const* d_in, const int* in_sizes, int n_in,
                              void* d_out, int out_size, void* d_ws, size_t ws_size,
                              hipStream_t stream) {
  const float* feats      = (const float*)d_in[0];
  const int*   x_idx      = (const int*)d_in[1];
  const int*   flat2win   = (const int*)d_in[2];
  const int*   win2flat   = (const int*)d_in[3];
  const float* in_proj_w  = (const float*)d_in[4];
  const float* in_proj_b  = (const float*)d_in[5];
  const float* out_proj_w = (const float*)d_in[6];
  const float* out_proj_b = (const float*)d_in[7];
  const float* lin1_w     = (const float*)d_in[8];
  const float* lin1_b     = (const float*)d_in[9];
  const float* lin2_w     = (const float*)d_in[10];
  const float* lin2_b     = (const float*)d_in[11];
  const float* ln1_g      = (const float*)d_in[12];
  const float* ln1_b      = (const float*)d_in[13];
  const float* ln2_g      = (const float*)d_in[14];
  const float* ln2_b      = (const float*)d_in[15];
  const float* proj_w     = (const float*)d_in[16];
  const float* proj_b     = (const float*)d_in[17];

  char* ws = (char*)d_ws;
  int*   gidx   = (int*)(ws + OFF_GIDX);
  int*   winner = (int*)(ws + OFF_WINNER);
  int*   wlist  = (int*)(ws + OFF_WLIST);
  int*   cnt    = (int*)(ws + OFF_CNT);
  float* x0     = (float*)(ws + OFF_X0);
  float* qkv    = (float*)(ws + OFF_QKV);
  float* attn   = (float*)(ws + OFF_ATTN);
  float* y      = (float*)(ws + OFF_Y);
  float* x1     = (float*)(ws + OFF_X1);
  float* ff1    = (float*)(ws + OFF_FF1);
  float* x2     = (float*)(ws + OFF_X2);
  float* basep  = (float*)(ws + OFF_BASE);
  unsigned short* WINB  = (unsigned short*)(ws + OFF_WINB);
  unsigned short* WOUTB = (unsigned short*)(ws + OFF_WOUTB);
  unsigned short* W1B   = (unsigned short*)(ws + OFF_W1B);
  unsigned short* W2B   = (unsigned short*)(ws + OFF_W2B);
  unsigned short* WP1B  = (unsigned short*)(ws + OFF_WP1B);
  unsigned short* WP2B  = (unsigned short*)(ws + OFF_WP2B);
  float* out    = (float*)d_out;

  // Q/K/V per-head buffers live in regions that are dead during attention
  float* Qh = y;                         // 4MB
  float* Kh = x1;                        // 4MB
  float* Vh = ff1;                       // first 4MB of the 32MB region

  k_init<<<kLPAD / 256, 256, 0, stream>>>(x_idx, flat2win, gidx, winner, cnt);
  k_winner<<<kL / 256, 256, 0, stream>>>(x_idx, winner);
  k_compact<<<kL / 256, 256, 0, stream>>>(x_idx, winner, wlist, cnt);
  // copy only rows NOT overwritten by the fuse scatter (winner < 0)
  k_copy<<<kL / 4, 256, 0, stream>>>(feats, winner, out);
  k_pool<<<kNW, 256, 0, stream>>>(feats, gidx, x0);

  // weight casts (bf16)
  k_cast<<<(3 * kC * kC / 4 + 255) / 256, 256, 0, stream>>>(in_proj_w, WINB, 3 * kC * kC / 4);
  k_cast<<<(kC * kC / 4 + 255) / 256, 256, 0, stream>>>(out_proj_w, WOUTB, kC * kC / 4);
  k_cast<<<(kFF * kC / 4 + 255) / 256, 256, 0, stream>>>(lin1_w, W1B, kFF * kC / 4);
  k_cast<<<(kC * kFF / 4 + 255) / 256, 256, 0, stream>>>(lin2_w, W2B, kC * kFF / 4);
  k_wprep<<<kC, 256, 0, stream>>>(proj_w, WP1B, WP2B);

  // qkv = x0 @ in_proj_w^T + b   [4096, 768]
  k_gemm_bf<false><<<dim3(3, kNW / 64), 256, 0, stream>>>(
      x0, kC, WINB, in_proj_b, qkv, 3 * kC, kC);
  k_qkvt<<<kNW, 256, 0, stream>>>(qkv, Qh, Kh, Vh);
  k_attn<<<dim3(kS / 64, kBS * kNH), 256, 0, stream>>>(Qh, Kh, Vh, attn);
  // y1 = attn @ out_proj^T + b
  k_gemm_bf<false><<<dim3(1, kNW / 64), 256, 0, stream>>>(
      attn, kC, WOUTB, out_proj_b, y, kC, kC);
  k_ln<<<kNW, 256, 0, stream>>>(y, x0, ln1_g, ln1_b, x1);
  // ff1 = relu(x1 @ lin1^T + b)  [4096, 2048]
  k_gemm_bf<true><<<dim3(kFF / 256, kNW / 64), 256, 0, stream>>>(
      x1, kC, W1B, lin1_b, ff1, kFF, kC);
  // y2 = ff1 @ lin2^T + b   (K = 2048)
  k_gemm_bf<false><<<dim3(1, kNW / 64), 256, 0, stream>>>(
      ff1, kFF, W2B, lin2_b, y, kC, kFF);
  k_ln<<<kNW, 256, 0, stream>>>(y, x1, ln2_g, ln2_b, x2);
  // base = x2 @ proj_w[:, :256]^T + proj_b
  k_gemm_bf<false><<<dim3(1, kNW / 64), 256, 0, stream>>>(
      x2, kC, WP1B, proj_b, basep, kC, kC);
  k_fuse<<<kL / 64, 256, 0, stream>>>(feats, gidx, wlist, cnt, win2flat, x_idx,
                                      basep, WP2B, out);
}

// Round 5
// 442.527 us; speedup vs baseline: 3.2495x; 1.1307x over previous
//
#include <hip/hip_runtime.h>
#include <math.h>

namespace {
constexpr int kL    = 262144;
constexpr int kC    = 256;
constexpr int kNH   = 8;
constexpr int kG    = 64;
constexpr int kFF   = 2048;
constexpr int kLPAD = 262144;
constexpr int kBS   = 4;
constexpr int kNW   = kLPAD / kG;   // 4096
constexpr int kS    = kNW / kBS;    // 1024
constexpr int kHD   = kC / kNH;     // 32

constexpr size_t MB        = 1024 * 1024;
constexpr size_t OFF_GIDX   = 0;        // int[LPAD]   1MB
constexpr size_t OFF_WINNER = 1 * MB;   // int[L]      1MB
constexpr size_t OFF_WLIST  = 2 * MB;   // int[L]      1MB
constexpr size_t OFF_CNT    = 3 * MB;   // int[1]
constexpr size_t OFF_X0     = 4 * MB;   // f32[4096*256]  4MB
constexpr size_t OFF_BASE   = 8 * MB;   // f32[4096*256]  4MB
constexpr size_t OFF_QKV    = 8 * MB;   // f32[4096*768]  12MB (base reuses after qkv dead)
constexpr size_t OFF_ATTN   = 20 * MB;  // f32[4096*256]  4MB
constexpr size_t OFF_X2     = 20 * MB;  // reuses attn
constexpr size_t OFF_Y      = 24 * MB;  // f32[4096*256]; Qh/Kh (bf16) during attn
constexpr size_t OFF_X1     = 28 * MB;  // f32[4096*256]; Vh (bf16) during attn
constexpr size_t OFF_FF1    = 32 * MB;  // f32[4096*2048] 32MB -> end 64MB
// bf16 weights (cast once per launch)
constexpr size_t OFF_WINB   = 64 * MB;                 // bf16[768*256]  384KB
constexpr size_t OFF_WOUTB  = OFF_WINB  + 512 * 1024;  // bf16[256*256]  128KB
constexpr size_t OFF_W1B    = OFF_WOUTB + 256 * 1024;  // bf16[2048*256] 1MB
constexpr size_t OFF_W2B    = OFF_W1B   + 1536 * 1024; // bf16[256*2048] 1MB
constexpr size_t OFF_WP1B   = OFF_W2B   + 1536 * 1024; // bf16[256*256]  128KB
constexpr size_t OFF_WP2B   = OFF_WP1B  + 256 * 1024;  // bf16[256*256]  128KB

typedef __attribute__((ext_vector_type(8))) short bf16x8;
typedef __attribute__((ext_vector_type(4))) float f32x4;

__device__ inline unsigned short f2bf(float f) {
  union { float f; unsigned int u; } x; x.f = f;
  unsigned int r = x.u + 0x7fff + ((x.u >> 16) & 1);   // RNE
  return (unsigned short)(r >> 16);
}
} // namespace

// ---------------------------------------------------------------- winner/compact
__global__ __launch_bounds__(256) void k_winner(const int* __restrict__ x_idx,
                                                int* __restrict__ winner) {
  int i = blockIdx.x * 256 + threadIdx.x;
  atomicMax(&winner[x_idx[i]], i);
}

__global__ __launch_bounds__(256) void k_compact(const int* __restrict__ x_idx,
                                                 const int* __restrict__ winner,
                                                 int* __restrict__ wlist,
                                                 int* __restrict__ cnt) {
  int i = blockIdx.x * 256 + threadIdx.x;
  if (winner[x_idx[i]] == i) {
    int p = atomicAdd(cnt, 1);
    wlist[p] = i;
  }
}

// ---------------------------------------------------------------- selective copy: rows not overwritten by fuse scatter
__global__ __launch_bounds__(256) void k_copy(const float* __restrict__ feats,
                                              const int* __restrict__ winner,
                                              float* __restrict__ out) {
  size_t idx = (size_t)blockIdx.x * 256 + threadIdx.x;   // one float4 each
  int row = (int)(idx >> 6);
  int c4 = (int)(idx & 63);
  if (winner[row] < 0) {                                  // wave-uniform (one row per wave)
    *(float4*)&out[(size_t)row * kC + c4 * 4] =
        *(const float4*)&feats[(size_t)row * kC + c4 * 4];
  }
}

// ---------------------------------------------------------------- pool (computes gidx inline, gather + max)
__global__ __launch_bounds__(256) void k_pool(const float* __restrict__ feats,
                                              const int* __restrict__ x_idx,
                                              const int* __restrict__ flat2win,
                                              int* __restrict__ gidx,
                                              float* __restrict__ x0) {
  int w = blockIdx.x, t = threadIdx.x;
  __shared__ int rows[kG];
  if (t < kG) {
    int g = x_idx[flat2win[w * kG + t]];
    rows[t] = g;
    gidx[w * kG + t] = g;
  }
  __syncthreads();
  float m = -INFINITY;
  #pragma unroll 4
  for (int g = 0; g < kG; ++g)
    m = fmaxf(m, feats[(size_t)rows[g] * kC + t]);
  x0[w * kC + t] = m;
}

// ---------------------------------------------------------------- all weight casts in one kernel
__global__ __launch_bounds__(256) void k_wcast(const float* __restrict__ in_proj_w,
                                               const float* __restrict__ out_proj_w,
                                               const float* __restrict__ lin1_w,
                                               const float* __restrict__ lin2_w,
                                               const float* __restrict__ proj_w,
                                               unsigned short* __restrict__ WINB,
                                               unsigned short* __restrict__ WOUTB,
                                               unsigned short* __restrict__ W1B,
                                               unsigned short* __restrict__ W2B,
                                               unsigned short* __restrict__ WP1,
                                               unsigned short* __restrict__ WP2) {
  int blk = blockIdx.x, t = threadIdx.x;
  const float* src = nullptr; unsigned short* dst = nullptr; int i = 0;
  if (blk < 192)       { src = in_proj_w;  dst = WINB;  i = blk * 256 + t; }
  else if (blk < 256)  { src = out_proj_w; dst = WOUTB; i = (blk - 192) * 256 + t; }
  else if (blk < 768)  { src = lin1_w;     dst = W1B;   i = (blk - 256) * 256 + t; }
  else if (blk < 1280) { src = lin2_w;     dst = W2B;   i = (blk - 768) * 256 + t; }
  else {
    int c = blk - 1280;
    WP1[c * kC + t] = f2bf(proj_w[(size_t)c * (2 * kC) + t]);
    WP2[c * kC + t] = f2bf(proj_w[(size_t)c * (2 * kC) + kC + t]);
    return;
  }
  float4 v = ((const float4*)src)[i];
  ushort4 b;
  b.x = f2bf(v.x); b.y = f2bf(v.y); b.z = f2bf(v.z); b.w = f2bf(v.w);
  ((ushort4*)dst)[i] = b;
}

// ---------------------------------------------------------------- bf16 MFMA GEMM: C = act(A @ Wb^T + bias)
template <bool RELU>
__global__ __launch_bounds__(256) void k_gemm_bf(const float* __restrict__ A, int lda,
                                                 const unsigned short* __restrict__ Wb,
                                                 const float* __restrict__ bias,
                                                 float* __restrict__ Cc, int ldc,
                                                 int K) {
  const int m0 = blockIdx.y * 64;
  const int nb = blockIdx.x * 256;
  const int t = threadIdx.x;
  const int lane = t & 63, w = t >> 6;
  const int c0 = nb + w * 64;
  const int kb = lane >> 4;     // 0..3
  const int lr = lane & 15;

  __shared__ __align__(16) unsigned short As[64 * 256];   // 32KB, XOR-swizzled rows

  f32x4 acc[4][4] = {};
  for (int kc = 0; kc < K; kc += 256) {
    #pragma unroll
    for (int i = 0; i < 16; ++i) {
      int row = i * 4 + w;
      float4 f4 = *(const float4*)&A[(size_t)(m0 + row) * lda + kc + lane * 4];
      ushort4 b4;
      b4.x = f2bf(f4.x); b4.y = f2bf(f4.y); b4.z = f2bf(f4.z); b4.w = f2bf(f4.w);
      unsigned int off = (((unsigned)row * 512u) + (unsigned)lane * 8u) ^ (((unsigned)row & 7u) << 4);
      *(ushort4*)((char*)As + off) = b4;
    }
    __syncthreads();

    #pragma unroll
    for (int ks = 0; ks < 8; ++ks) {
      const int k0 = ks * 32;
      bf16x8 a[4], b[4];
      #pragma unroll
      for (int rt = 0; rt < 4; ++rt) {
        int row = rt * 16 + lr;
        unsigned int off = (((unsigned)row * 512u) + (unsigned)(k0 + kb * 8) * 2u) ^
                           (((unsigned)row & 7u) << 4);
        a[rt] = *(const bf16x8*)((const char*)As + off);
      }
      #pragma unroll
      for (int ct = 0; ct < 4; ++ct) {
        int c = c0 + ct * 16 + lr;
        b[ct] = *(const bf16x8*)&Wb[(size_t)c * K + kc + k0 + kb * 8];
      }
      #pragma unroll
      for (int rt = 0; rt < 4; ++rt)
        #pragma unroll
        for (int ct = 0; ct < 4; ++ct)
          acc[rt][ct] = __builtin_amdgcn_mfma_f32_16x16x32_bf16(a[rt], b[ct], acc[rt][ct], 0, 0, 0);
    }
    __syncthreads();
  }

  #pragma unroll
  for (int rt = 0; rt < 4; ++rt) {
    #pragma unroll
    for (int r = 0; r < 4; ++r) {
      int row = m0 + rt * 16 + kb * 4 + r;
      #pragma unroll
      for (int ct = 0; ct < 4; ++ct) {
        int c = c0 + ct * 16 + lr;
        float v = acc[rt][ct][r] + bias[c];
        if (RELU) v = fmaxf(v, 0.f);
        Cc[(size_t)row * ldc + c] = v;
      }
    }
  }
}

// ---------------------------------------------------------------- qkv -> per-head bf16 Q(scaled),K,V [BH][S][32]
__global__ __launch_bounds__(256) void k_qkvt(const float* __restrict__ qkv,
                                              unsigned short* __restrict__ Qh,
                                              unsigned short* __restrict__ Kh,
                                              unsigned short* __restrict__ Vh) {
  const float scale = 0.17677669529663687f;   // 1/sqrt(32)
  int r = blockIdx.x;            // 0..4095  (b*1024+s)
  int b = r >> 10, s = r & 1023;
  int t = threadIdx.x;
  int h = t >> 5, d = t & 31;
  size_t src = (size_t)r * (3 * kC);
  size_t dst = (((size_t)(b * kNH + h) * kS) + s) * kHD + d;
  Qh[dst] = f2bf(qkv[src + t] * scale);
  Kh[dst] = f2bf(qkv[src + kC + t]);
  Vh[dst] = f2bf(qkv[src + 2 * kC + t]);
}

// ---------------------------------------------------------------- flash attention, bf16 MFMA
// block: 64 q-rows x one (b,h); 4 waves, wave w owns q rows w*16..w*16+15
__global__ __launch_bounds__(256) void k_attn(const unsigned short* __restrict__ Qh,
                                              const unsigned short* __restrict__ Kh,
                                              const unsigned short* __restrict__ Vh,
                                              float* __restrict__ attn_out) {
  const int q0 = blockIdx.x * 64;
  const int bh = blockIdx.y;           // b*8+h
  const int b = bh >> 3, h = bh & 7;
  const int t = threadIdx.x;
  const int lane = t & 63, w = t >> 6;
  const int kb = lane >> 4, lr = lane & 15;

  __shared__ __align__(16) unsigned short Ks[64][40];    // keys x d (pad: 80B rows, <=2-way banks)
  __shared__ __align__(16) unsigned short VTs[32][72];   // d x keys (144B rows)
  __shared__ __align__(16) unsigned short Ps[4][16][72]; // per-wave P: q_local x keys

  // Q fragment in registers: row q0+w*16+lr, d = kb*8..+7
  bf16x8 aq = *(const bf16x8*)(Qh + (((size_t)bh * kS) + q0 + w * 16 + lr) * kHD + kb * 8);

  const unsigned short* kbase = Kh + (size_t)bh * kS * kHD;
  const unsigned short* vbase = Vh + (size_t)bh * kS * kHD;

  float m[4], l[4];
  f32x4 O[2] = {};
  #pragma unroll
  for (int r = 0; r < 4; ++r) { m[r] = -INFINITY; l[r] = 0.f; }

  for (int kt = 0; kt < kS / 64; ++kt) {
    // stage K tile [64][32] and V^T tile [32][64]
    {
      int key = t >> 2, d0 = (t & 3) * 8;
      size_t srow = ((size_t)(kt * 64 + key)) * kHD + d0;
      bf16x8 kv = *(const bf16x8*)(kbase + srow);
      *(bf16x8*)&Ks[key][d0] = kv;
      bf16x8 vv = *(const bf16x8*)(vbase + srow);
      #pragma unroll
      for (int i = 0; i < 8; ++i) VTs[d0 + i][key] = (unsigned short)vv[i];
    }
    __syncthreads();

    // scores: 16 q x 64 keys per wave = 4 MFMAs (K = head_dim = 32)
    f32x4 S[4] = {};
    #pragma unroll
    for (int ct = 0; ct < 4; ++ct) {
      bf16x8 bk = *(const bf16x8*)&Ks[ct * 16 + lr][kb * 8];
      S[ct] = __builtin_amdgcn_mfma_f32_16x16x32_bf16(aq, bk, S[ct], 0, 0, 0);
    }

    // online softmax; lane owns rows q_local = kb*4+r, cols {ct*16+lr}
    float alpha[4];
    #pragma unroll
    for (int r = 0; r < 4; ++r) {
      float tmax = fmaxf(fmaxf(S[0][r], S[1][r]), fmaxf(S[2][r], S[3][r]));
      #pragma unroll
      for (int off = 8; off; off >>= 1) tmax = fmaxf(tmax, __shfl_xor(tmax, off, 16));
      float newm = fmaxf(m[r], tmax);
      alpha[r] = __expf(m[r] - newm);
      float p[4], ps = 0.f;
      #pragma unroll
      for (int ct = 0; ct < 4; ++ct) { p[ct] = __expf(S[ct][r] - newm); ps += p[ct]; }
      #pragma unroll
      for (int off = 8; off; off >>= 1) ps += __shfl_xor(ps, off, 16);
      l[r] = l[r] * alpha[r] + ps;
      m[r] = newm;
      #pragma unroll
      for (int ct = 0; ct < 4; ++ct) Ps[w][kb * 4 + r][ct * 16 + lr] = f2bf(p[ct]);
    }
    #pragma unroll
    for (int r = 0; r < 4; ++r) { O[0][r] *= alpha[r]; O[1][r] *= alpha[r]; }

    // PV: 16 q x 32 d, K = 64 keys -> 2 ks-slices x 2 d-tiles (P is wave-private)
    #pragma unroll
    for (int ks = 0; ks < 2; ++ks) {
      bf16x8 ap = *(const bf16x8*)&Ps[w][lr][ks * 32 + kb * 8];
      #pragma unroll
      for (int ct = 0; ct < 2; ++ct) {
        bf16x8 bv = *(const bf16x8*)&VTs[ct * 16 + lr][ks * 32 + kb * 8];
        O[ct] = __builtin_amdgcn_mfma_f32_16x16x32_bf16(ap, bv, O[ct], 0, 0, 0);
      }
    }
    __syncthreads();
  }

  #pragma unroll
  for (int ct = 0; ct < 2; ++ct) {
    #pragma unroll
    for (int r = 0; r < 4; ++r) {
      size_t row = (size_t)b * kS + q0 + w * 16 + kb * 4 + r;
      attn_out[row * kC + h * kHD + ct * 16 + lr] = O[ct][r] / l[r];
    }
  }
}

// ---------------------------------------------------------------- layer norm with residual: out = LN(y + r)
__global__ __launch_bounds__(256) void k_ln(const float* __restrict__ Y,
                                            const float* __restrict__ R,
                                            const float* __restrict__ g,
                                            const float* __restrict__ bb,
                                            float* __restrict__ Out) {
  int row = blockIdx.x, t = threadIdx.x;
  int wv = t >> 6, lane = t & 63;
  float v = Y[(size_t)row * kC + t] + R[(size_t)row * kC + t];
  __shared__ float red1[4], red2[4];
  float s = v;
  #pragma unroll
  for (int off = 32; off; off >>= 1) s += __shfl_xor(s, off);
  if (lane == 0) red1[wv] = s;
  __syncthreads();
  float mu = (red1[0] + red1[1] + red1[2] + red1[3]) * (1.0f / kC);
  float d = v - mu;
  float sq = d * d;
  #pragma unroll
  for (int off = 32; off; off >>= 1) sq += __shfl_xor(sq, off);
  if (lane == 0) red2[wv] = sq;
  __syncthreads();
  float var = (red2[0] + red2[1] + red2[2] + red2[3]) * (1.0f / kC);
  Out[(size_t)row * kC + t] = d * rsqrtf(var + 1e-5f) * g[t] + bb[t];
}

// ---------------------------------------------------------------- fuse: bf16 MFMA GEMM (gathered A) + scatter
__global__ __launch_bounds__(256) void k_fuse(const float* __restrict__ feats,
                                              const int* __restrict__ gidx,
                                              const int* __restrict__ wlist,
                                              const int* __restrict__ cnt,
                                              const int* __restrict__ win2flat,
                                              const int* __restrict__ x_idx,
                                              const float* __restrict__ base,
                                              const unsigned short* __restrict__ W2B,
                                              float* __restrict__ out) {
  const int count = cnt[0];
  const int r0 = blockIdx.x * 64;
  if (r0 >= count) return;
  const int nr = min(64, count - r0);
  const int t = threadIdx.x;
  const int lane = t & 63, w = t >> 6;

  __shared__ __align__(16) unsigned short As[64 * 256];   // 32KB, XOR-swizzled rows
  __shared__ int dstrow[64], wwin[64], srcrow[64];

  if (t < 64) {
    int rr = min(r0 + t, count - 1);      // clamp; padded rows never stored
    int i = wlist[rr];
    int j = win2flat[i];
    srcrow[t] = gidx[j];
    wwin[t] = j >> 6;
    dstrow[t] = x_idx[i];
  }
  __syncthreads();

  for (int i = 0; i < 16; ++i) {
    int row = i * 4 + w;
    float4 f4 = *(const float4*)&feats[(size_t)srcrow[row] * kC + lane * 4];
    ushort4 b4;
    b4.x = f2bf(f4.x); b4.y = f2bf(f4.y); b4.z = f2bf(f4.z); b4.w = f2bf(f4.w);
    unsigned int off = (((unsigned)row * 512u) + (unsigned)lane * 8u) ^ (((unsigned)row & 7u) << 4);
    *(ushort4*)((char*)As + off) = b4;
  }
  __syncthreads();

  const int c0 = w * 64;
  const int kb = lane >> 4;
  const int lr = lane & 15;
  f32x4 acc[4][4] = {};
  for (int ks = 0; ks < 8; ++ks) {
    const int k0 = ks * 32;
    bf16x8 a[4], b[4];
    #pragma unroll
    for (int rt = 0; rt < 4; ++rt) {
      int row = rt * 16 + lr;
      unsigned int off = (((unsigned)row * 512u) + (unsigned)(k0 + kb * 8) * 2u) ^
                         (((unsigned)row & 7u) << 4);
      a[rt] = *(const bf16x8*)((const char*)As + off);
    }
    #pragma unroll
    for (int ct = 0; ct < 4; ++ct) {
      int c = c0 + ct * 16 + lr;
      b[ct] = *(const bf16x8*)&W2B[(size_t)c * kC + k0 + kb * 8];
    }
    #pragma unroll
    for (int rt = 0; rt < 4; ++rt)
      #pragma unroll
      for (int ct = 0; ct < 4; ++ct)
        acc[rt][ct] = __builtin_amdgcn_mfma_f32_16x16x32_bf16(a[rt], b[ct], acc[rt][ct], 0, 0, 0);
  }

  #pragma unroll
  for (int rt = 0; rt < 4; ++rt) {
    #pragma unroll
    for (int r = 0; r < 4; ++r) {
      int row = rt * 16 + kb * 4 + r;
      if (row < nr) {
        size_t orow = (size_t)dstrow[row] * kC;
        size_t brow = (size_t)wwin[row] * kC;
        #pragma unroll
        for (int ct = 0; ct < 4; ++ct) {
          int c = c0 + ct * 16 + lr;
          out[orow + c] = acc[rt][ct][r] + base[brow + c];
        }
      }
    }
  }
}

// ---------------------------------------------------------------- launch
extern "C" void kernel_launch(void* const* d_in, const int* in_sizes, int n_in,
                              void* d_out, int out_size, void* d_ws, size_t ws_size,
                              hipStream_t stream) {
  const float* feats      = (const float*)d_in[0];
  const int*   x_idx      = (const int*)d_in[1];
  const int*   flat2win   = (const int*)d_in[2];
  const int*   win2flat   = (const int*)d_in[3];
  const float* in_proj_w  = (const float*)d_in[4];
  const float* in_proj_b  = (const float*)d_in[5];
  const float* out_proj_w = (const float*)d_in[6];
  const float* out_proj_b = (const float*)d_in[7];
  const float* lin1_w     = (const float*)d_in[8];
  const float* lin1_b     = (const float*)d_in[9];
  const float* lin2_w     = (const float*)d_in[10];
  const float* lin2_b     = (const float*)d_in[11];
  const float* ln1_g      = (const float*)d_in[12];
  const float* ln1_b      = (const float*)d_in[13];
  const float* ln2_g      = (const float*)d_in[14];
  const float* ln2_b      = (const float*)d_in[15];
  const float* proj_w     = (const float*)d_in[16];
  const float* proj_b     = (const float*)d_in[17];

  char* ws = (char*)d_ws;
  int*   gidx   = (int*)(ws + OFF_GIDX);
  int*   winner = (int*)(ws + OFF_WINNER);
  int*   wlist  = (int*)(ws + OFF_WLIST);
  int*   cnt    = (int*)(ws + OFF_CNT);
  float* x0     = (float*)(ws + OFF_X0);
  float* qkv    = (float*)(ws + OFF_QKV);
  float* attn   = (float*)(ws + OFF_ATTN);
  float* y      = (float*)(ws + OFF_Y);
  float* x1     = (float*)(ws + OFF_X1);
  float* ff1    = (float*)(ws + OFF_FF1);
  float* x2     = (float*)(ws + OFF_X2);
  float* basep  = (float*)(ws + OFF_BASE);
  unsigned short* WINB  = (unsigned short*)(ws + OFF_WINB);
  unsigned short* WOUTB = (unsigned short*)(ws + OFF_WOUTB);
  unsigned short* W1B   = (unsigned short*)(ws + OFF_W1B);
  unsigned short* W2B   = (unsigned short*)(ws + OFF_W2B);
  unsigned short* WP1B  = (unsigned short*)(ws + OFF_WP1B);
  unsigned short* WP2B  = (unsigned short*)(ws + OFF_WP2B);
  float* out    = (float*)d_out;

  // bf16 Q/K/V per-head buffers live in regions dead during attention
  unsigned short* Qh = (unsigned short*)(ws + OFF_Y);             // 2MB
  unsigned short* Kh = (unsigned short*)(ws + OFF_Y + 2 * MB);    // 2MB
  unsigned short* Vh = (unsigned short*)(ws + OFF_X1);            // 2MB

  hipMemsetAsync(winner, 0xFF, (size_t)kL * sizeof(int), stream);   // -1
  hipMemsetAsync(cnt, 0, sizeof(int), stream);

  k_winner<<<kL / 256, 256, 0, stream>>>(x_idx, winner);
  k_compact<<<kL / 256, 256, 0, stream>>>(x_idx, winner, wlist, cnt);
  k_copy<<<kL / 4, 256, 0, stream>>>(feats, winner, out);
  k_pool<<<kNW, 256, 0, stream>>>(feats, x_idx, flat2win, gidx, x0);
  k_wcast<<<1536, 256, 0, stream>>>(in_proj_w, out_proj_w, lin1_w, lin2_w, proj_w,
                                    WINB, WOUTB, W1B, W2B, WP1B, WP2B);

  // qkv = x0 @ in_proj_w^T + b   [4096, 768]
  k_gemm_bf<false><<<dim3(3, kNW / 64), 256, 0, stream>>>(
      x0, kC, WINB, in_proj_b, qkv, 3 * kC, kC);
  k_qkvt<<<kNW, 256, 0, stream>>>(qkv, Qh, Kh, Vh);
  k_attn<<<dim3(kS / 64, kBS * kNH), 256, 0, stream>>>(Qh, Kh, Vh, attn);
  // y1 = attn @ out_proj^T + b
  k_gemm_bf<false><<<dim3(1, kNW / 64), 256, 0, stream>>>(
      attn, kC, WOUTB, out_proj_b, y, kC, kC);
  k_ln<<<kNW, 256, 0, stream>>>(y, x0, ln1_g, ln1_b, x1);
  // ff1 = relu(x1 @ lin1^T + b)  [4096, 2048]
  k_gemm_bf<true><<<dim3(kFF / 256, kNW / 64), 256, 0, stream>>>(
      x1, kC, W1B, lin1_b, ff1, kFF, kC);
  // y2 = ff1 @ lin2^T + b   (K = 2048)
  k_gemm_bf<false><<<dim3(1, kNW / 64), 256, 0, stream>>>(
      ff1, kFF, W2B, lin2_b, y, kC, kFF);
  k_ln<<<kNW, 256, 0, stream>>>(y, x1, ln2_g, ln2_b, x2);
  // base = x2 @ proj_w[:, :256]^T + proj_b
  k_gemm_bf<false><<<dim3(1, kNW / 64), 256, 0, stream>>>(
      x2, kC, WP1B, proj_b, basep, kC, kC);
  k_fuse<<<kL / 64, 256, 0, stream>>>(feats, gidx, wlist, cnt, win2flat, x_idx,
                                      basep, WP2B, out);
}

// Round 6
// 404.140 us; speedup vs baseline: 3.5581x; 1.0950x over previous
//
#include <hip/hip_runtime.h>
#include <math.h>

namespace {
constexpr int kL    = 262144;
constexpr int kC    = 256;
constexpr int kNH   = 8;
constexpr int kG    = 64;
constexpr int kFF   = 2048;
constexpr int kLPAD = 262144;
constexpr int kBS   = 4;
constexpr int kNW   = kLPAD / kG;   // 4096
constexpr int kS    = kNW / kBS;    // 1024
constexpr int kHD   = kC / kNH;     // 32

constexpr size_t MB        = 1024 * 1024;
constexpr size_t OFF_GIDX   = 0;         // int[LPAD]      1MB
constexpr size_t OFF_WINNER = 1 * MB;    // int[L]         1MB
constexpr size_t OFF_WLIST  = 2 * MB;    // int[L]         1MB
constexpr size_t OFF_CNT    = 3 * MB;    // int[1]
constexpr size_t OFF_X0     = 4 * MB;    // f32[4096*256]  4MB
constexpr size_t OFF_BASE   = 8 * MB;    // f32[4096*256]  4MB
constexpr size_t OFF_ATTN   = 12 * MB;   // bf16[4096*256] 2MB
constexpr size_t OFF_QH     = 16 * MB;   // bf16[4096*32*... 2MB
constexpr size_t OFF_KH     = 18 * MB;   // 2MB
constexpr size_t OFF_VH     = 20 * MB;   // 2MB
constexpr size_t OFF_X1     = 24 * MB;   // f32[4096*256]  4MB
constexpr size_t OFF_FF1    = 32 * MB;   // bf16[4096*2048] 16MB
constexpr size_t OFF_WINB   = 64 * MB;                 // bf16[768*256]  384KB
constexpr size_t OFF_WOUTB  = OFF_WINB  + 512 * 1024;  // bf16[256*256]  128KB
constexpr size_t OFF_W1B    = OFF_WOUTB + 256 * 1024;  // bf16[2048*256] 1MB
constexpr size_t OFF_W2B    = OFF_W1B   + 1536 * 1024; // bf16[256*2048] 1MB
constexpr size_t OFF_WP1B   = OFF_W2B   + 1536 * 1024; // bf16[256*256]  128KB
constexpr size_t OFF_WP2B   = OFF_WP1B  + 256 * 1024;  // bf16[256*256]  128KB

typedef __attribute__((ext_vector_type(8))) short bf16x8;
typedef __attribute__((ext_vector_type(4))) float f32x4;

__device__ inline unsigned short f2bf(float f) {
  union { float f; unsigned int u; } x; x.f = f;
  unsigned int r = x.u + 0x7fff + ((x.u >> 16) & 1);   // RNE
  return (unsigned short)(r >> 16);
}
} // namespace

// ---------------------------------------------------------------- winner/compact
__global__ __launch_bounds__(256) void k_winner(const int* __restrict__ x_idx,
                                                int* __restrict__ winner) {
  int i = blockIdx.x * 256 + threadIdx.x;
  atomicMax(&winner[x_idx[i]], i);
}

__global__ __launch_bounds__(256) void k_compact(const int* __restrict__ x_idx,
                                                 const int* __restrict__ winner,
                                                 int* __restrict__ wlist,
                                                 int* __restrict__ cnt) {
  int i = blockIdx.x * 256 + threadIdx.x;
  if (winner[x_idx[i]] == i) {
    int p = atomicAdd(cnt, 1);
    wlist[p] = i;
  }
}

// ---------------------------------------------------------------- selective copy: rows not overwritten by fuse scatter
__global__ __launch_bounds__(256) void k_copy(const float* __restrict__ feats,
                                              const int* __restrict__ winner,
                                              float* __restrict__ out) {
  size_t idx = (size_t)blockIdx.x * 256 + threadIdx.x;   // one float4 each
  int row = (int)(idx >> 6);
  int c4 = (int)(idx & 63);
  if (winner[row] < 0) {                                  // wave-uniform (one row per wave)
    *(float4*)&out[(size_t)row * kC + c4 * 4] =
        *(const float4*)&feats[(size_t)row * kC + c4 * 4];
  }
}

// ---------------------------------------------------------------- pool (computes gidx inline, gather + max)
__global__ __launch_bounds__(256) void k_pool(const float* __restrict__ feats,
                                              const int* __restrict__ x_idx,
                                              const int* __restrict__ flat2win,
                                              int* __restrict__ gidx,
                                              float* __restrict__ x0) {
  int w = blockIdx.x, t = threadIdx.x;
  __shared__ int rows[kG];
  if (t < kG) {
    int g = x_idx[flat2win[w * kG + t]];
    rows[t] = g;
    gidx[w * kG + t] = g;
  }
  __syncthreads();
  float m = -INFINITY;
  #pragma unroll 4
  for (int g = 0; g < kG; ++g)
    m = fmaxf(m, feats[(size_t)rows[g] * kC + t]);
  x0[w * kC + t] = m;
}

// ---------------------------------------------------------------- all weight casts in one kernel
__global__ __launch_bounds__(256) void k_wcast(const float* __restrict__ in_proj_w,
                                               const float* __restrict__ out_proj_w,
                                               const float* __restrict__ lin1_w,
                                               const float* __restrict__ lin2_w,
                                               const float* __restrict__ proj_w,
                                               unsigned short* __restrict__ WINB,
                                               unsigned short* __restrict__ WOUTB,
                                               unsigned short* __restrict__ W1B,
                                               unsigned short* __restrict__ W2B,
                                               unsigned short* __restrict__ WP1,
                                               unsigned short* __restrict__ WP2) {
  int blk = blockIdx.x, t = threadIdx.x;
  const float* src = nullptr; unsigned short* dst = nullptr; int i = 0;
  if (blk < 192)       { src = in_proj_w;  dst = WINB;  i = blk * 256 + t; }
  else if (blk < 256)  { src = out_proj_w; dst = WOUTB; i = (blk - 192) * 256 + t; }
  else if (blk < 768)  { src = lin1_w;     dst = W1B;   i = (blk - 256) * 256 + t; }
  else if (blk < 1280) { src = lin2_w;     dst = W2B;   i = (blk - 768) * 256 + t; }
  else {
    int c = blk - 1280;
    WP1[c * kC + t] = f2bf(proj_w[(size_t)c * (2 * kC) + t]);
    WP2[c * kC + t] = f2bf(proj_w[(size_t)c * (2 * kC) + kC + t]);
    return;
  }
  float4 v = ((const float4*)src)[i];
  ushort4 b;
  b.x = f2bf(v.x); b.y = f2bf(v.y); b.z = f2bf(v.z); b.w = f2bf(v.w);
  ((ushort4*)dst)[i] = b;
}

// ---------------------------------------------------------------- qkv GEMM with per-head bf16 scatter epilogue
// grid (3, 64): blockIdx.x = section (0=Q scaled, 1=K, 2=V)
__global__ __launch_bounds__(256) void k_gemm_qkv(const float* __restrict__ A,
                                                  const unsigned short* __restrict__ Wb,
                                                  const float* __restrict__ bias,
                                                  unsigned short* __restrict__ Qh,
                                                  unsigned short* __restrict__ Kh,
                                                  unsigned short* __restrict__ Vh) {
  const float scale = 0.17677669529663687f;   // 1/sqrt(32)
  const int m0 = blockIdx.y * 64;
  const int sec = blockIdx.x;
  const int t = threadIdx.x;
  const int lane = t & 63, w = t >> 6;
  const int c0 = w * 64;
  const int kb = lane >> 4, lr = lane & 15;

  __shared__ __align__(16) unsigned short As[64 * 256];

  f32x4 acc[4][4] = {};
  // stage A (K=256, single chunk)
  #pragma unroll
  for (int i = 0; i < 16; ++i) {
    int row = i * 4 + w;
    float4 f4 = *(const float4*)&A[(size_t)(m0 + row) * kC + lane * 4];
    ushort4 b4;
    b4.x = f2bf(f4.x); b4.y = f2bf(f4.y); b4.z = f2bf(f4.z); b4.w = f2bf(f4.w);
    unsigned int off = (((unsigned)row * 512u) + (unsigned)lane * 8u) ^ (((unsigned)row & 7u) << 4);
    *(ushort4*)((char*)As + off) = b4;
  }
  __syncthreads();

  #pragma unroll
  for (int ks = 0; ks < 8; ++ks) {
    const int k0 = ks * 32;
    bf16x8 a[4], b[4];
    #pragma unroll
    for (int rt = 0; rt < 4; ++rt) {
      int row = rt * 16 + lr;
      unsigned int off = (((unsigned)row * 512u) + (unsigned)(k0 + kb * 8) * 2u) ^
                         (((unsigned)row & 7u) << 4);
      a[rt] = *(const bf16x8*)((const char*)As + off);
    }
    #pragma unroll
    for (int ct = 0; ct < 4; ++ct) {
      int c = sec * kC + c0 + ct * 16 + lr;
      b[ct] = *(const bf16x8*)&Wb[(size_t)c * kC + k0 + kb * 8];
    }
    #pragma unroll
    for (int rt = 0; rt < 4; ++rt)
      #pragma unroll
      for (int ct = 0; ct < 4; ++ct)
        acc[rt][ct] = __builtin_amdgcn_mfma_f32_16x16x32_bf16(a[rt], b[ct], acc[rt][ct], 0, 0, 0);
  }

  unsigned short* dstbuf = (sec == 0) ? Qh : (sec == 1) ? Kh : Vh;
  #pragma unroll
  for (int rt = 0; rt < 4; ++rt) {
    #pragma unroll
    for (int r = 0; r < 4; ++r) {
      int row = m0 + rt * 16 + kb * 4 + r;
      int bb = row >> 10, s = row & 1023;
      #pragma unroll
      for (int ct = 0; ct < 4; ++ct) {
        int c = c0 + ct * 16 + lr;
        float v = acc[rt][ct][r] + bias[sec * kC + c];
        if (sec == 0) v *= scale;
        int h = c >> 5, d = c & 31;
        dstbuf[(((size_t)(bb * kNH + h) * kS) + s) * kHD + d] = f2bf(v);
      }
    }
  }
}

// ---------------------------------------------------------------- flash attention, bf16 MFMA, bf16 out
__global__ __launch_bounds__(256) void k_attn(const unsigned short* __restrict__ Qh,
                                              const unsigned short* __restrict__ Kh,
                                              const unsigned short* __restrict__ Vh,
                                              unsigned short* __restrict__ attn_out) {
  const int q0 = blockIdx.x * 64;
  const int bh = blockIdx.y;           // b*8+h
  const int b = bh >> 3, h = bh & 7;
  const int t = threadIdx.x;
  const int lane = t & 63, w = t >> 6;
  const int kb = lane >> 4, lr = lane & 15;

  __shared__ __align__(16) unsigned short Ks[64][40];
  __shared__ __align__(16) unsigned short VTs[32][72];
  __shared__ __align__(16) unsigned short Ps[4][16][72];

  bf16x8 aq = *(const bf16x8*)(Qh + (((size_t)bh * kS) + q0 + w * 16 + lr) * kHD + kb * 8);

  const unsigned short* kbase = Kh + (size_t)bh * kS * kHD;
  const unsigned short* vbase = Vh + (size_t)bh * kS * kHD;

  float m[4], l[4];
  f32x4 O[2] = {};
  #pragma unroll
  for (int r = 0; r < 4; ++r) { m[r] = -INFINITY; l[r] = 0.f; }

  for (int kt = 0; kt < kS / 64; ++kt) {
    {
      int key = t >> 2, d0 = (t & 3) * 8;
      size_t srow = ((size_t)(kt * 64 + key)) * kHD + d0;
      bf16x8 kv = *(const bf16x8*)(kbase + srow);
      *(bf16x8*)&Ks[key][d0] = kv;
      bf16x8 vv = *(const bf16x8*)(vbase + srow);
      #pragma unroll
      for (int i = 0; i < 8; ++i) VTs[d0 + i][key] = (unsigned short)vv[i];
    }
    __syncthreads();

    f32x4 S[4] = {};
    #pragma unroll
    for (int ct = 0; ct < 4; ++ct) {
      bf16x8 bk = *(const bf16x8*)&Ks[ct * 16 + lr][kb * 8];
      S[ct] = __builtin_amdgcn_mfma_f32_16x16x32_bf16(aq, bk, S[ct], 0, 0, 0);
    }

    float alpha[4];
    #pragma unroll
    for (int r = 0; r < 4; ++r) {
      float tmax = fmaxf(fmaxf(S[0][r], S[1][r]), fmaxf(S[2][r], S[3][r]));
      #pragma unroll
      for (int off = 8; off; off >>= 1) tmax = fmaxf(tmax, __shfl_xor(tmax, off, 16));
      float newm = fmaxf(m[r], tmax);
      alpha[r] = __expf(m[r] - newm);
      float p[4], ps = 0.f;
      #pragma unroll
      for (int ct = 0; ct < 4; ++ct) { p[ct] = __expf(S[ct][r] - newm); ps += p[ct]; }
      #pragma unroll
      for (int off = 8; off; off >>= 1) ps += __shfl_xor(ps, off, 16);
      l[r] = l[r] * alpha[r] + ps;
      m[r] = newm;
      #pragma unroll
      for (int ct = 0; ct < 4; ++ct) Ps[w][kb * 4 + r][ct * 16 + lr] = f2bf(p[ct]);
    }
    #pragma unroll
    for (int r = 0; r < 4; ++r) { O[0][r] *= alpha[r]; O[1][r] *= alpha[r]; }

    #pragma unroll
    for (int ks = 0; ks < 2; ++ks) {
      bf16x8 ap = *(const bf16x8*)&Ps[w][lr][ks * 32 + kb * 8];
      #pragma unroll
      for (int ct = 0; ct < 2; ++ct) {
        bf16x8 bv = *(const bf16x8*)&VTs[ct * 16 + lr][ks * 32 + kb * 8];
        O[ct] = __builtin_amdgcn_mfma_f32_16x16x32_bf16(ap, bv, O[ct], 0, 0, 0);
      }
    }
    __syncthreads();
  }

  #pragma unroll
  for (int ct = 0; ct < 2; ++ct) {
    #pragma unroll
    for (int r = 0; r < 4; ++r) {
      size_t row = (size_t)b * kS + q0 + w * 16 + kb * 4 + r;
      attn_out[row * kC + h * kHD + ct * 16 + lr] = f2bf(O[ct][r] / l[r]);
    }
  }
}

// ---------------------------------------------------------------- 16-row GEMM + residual + LN (+ optional chained base GEMM)
// A bf16 [4096][K], Wb bf16 [256][K]; out = LN(A@Wb^T + bias + R)  (f32)
// DO_BASE: out = LN(...) @ WbB^T + biasB instead (LN result never hits HBM)
template <bool DO_BASE>
__global__ __launch_bounds__(256) void k_gemm_ln(const unsigned short* __restrict__ A,
                                                 int K,
                                                 const unsigned short* __restrict__ Wb,
                                                 const float* __restrict__ bias,
                                                 const float* __restrict__ R,
                                                 const float* __restrict__ g,
                                                 const float* __restrict__ bb,
                                                 float* __restrict__ Out,
                                                 const unsigned short* __restrict__ WbB,
                                                 const float* __restrict__ biasB) {
  const int m0 = blockIdx.x * 16;
  const int t = threadIdx.x;
  const int lane = t & 63, w = t >> 6;
  const int c0 = w * 64;
  const int kb = lane >> 4, lr = lane & 15;

  __shared__ __align__(16) unsigned short As[16 * 256];   // 8KB swizzled
  __shared__ __align__(16) unsigned short Xs[16 * 256];   // 8KB (DO_BASE second-stage A)
  __shared__ float red[2][16][4];

  f32x4 acc[4] = {};
  for (int kc = 0; kc < K; kc += 256) {
    #pragma unroll
    for (int i = 0; i < 2; ++i) {
      int idx = i * 256 + t;            // 0..511 ushort8s
      int row = idx >> 5, seg = idx & 31;
      bf16x8 v = *(const bf16x8*)&A[(size_t)(m0 + row) * K + kc + seg * 8];
      unsigned int off = (((unsigned)row * 512u) + (unsigned)seg * 16u) ^ (((unsigned)row & 7u) << 4);
      *(bf16x8*)((char*)As + off) = v;
    }
    __syncthreads();

    #pragma unroll
    for (int ks = 0; ks < 8; ++ks) {
      const int k0 = ks * 32;
      unsigned int aoff = (((unsigned)lr * 512u) + (unsigned)(k0 + kb * 8) * 2u) ^
                          (((unsigned)lr & 7u) << 4);
      bf16x8 a = *(const bf16x8*)((const char*)As + aoff);
      #pragma unroll
      for (int ct = 0; ct < 4; ++ct) {
        bf16x8 b = *(const bf16x8*)&Wb[(size_t)(c0 + ct * 16 + lr) * K + kc + k0 + kb * 8];
        acc[ct] = __builtin_amdgcn_mfma_f32_16x16x32_bf16(a, b, acc[ct], 0, 0, 0);
      }
    }
    __syncthreads();
  }

  // v = acc + bias + R;  per-row mean/var across the 256-col block
  float v[4][4];   // [r][ct]
  float s[4], sq[4];
  #pragma unroll
  for (int r = 0; r < 4; ++r) { s[r] = 0.f; sq[r] = 0.f; }
  #pragma unroll
  for (int r = 0; r < 4; ++r) {
    int row = m0 + kb * 4 + r;
    #pragma unroll
    for (int ct = 0; ct < 4; ++ct) {
      int c = c0 + ct * 16 + lr;
      float x = acc[ct][r] + bias[c] + R[(size_t)row * kC + c];
      v[r][ct] = x;
      s[r] += x;
      sq[r] += x * x;
    }
  }
  #pragma unroll
  for (int r = 0; r < 4; ++r) {
    #pragma unroll
    for (int off = 8; off; off >>= 1) {
      s[r]  += __shfl_xor(s[r], off, 16);
      sq[r] += __shfl_xor(sq[r], off, 16);
    }
    if (lr == 0) { red[0][kb * 4 + r][w] = s[r]; red[1][kb * 4 + r][w] = sq[r]; }
  }
  __syncthreads();

  #pragma unroll
  for (int r = 0; r < 4; ++r) {
    int lrow = kb * 4 + r;
    float su = red[0][lrow][0] + red[0][lrow][1] + red[0][lrow][2] + red[0][lrow][3];
    float sg = red[1][lrow][0] + red[1][lrow][1] + red[1][lrow][2] + red[1][lrow][3];
    float mu = su * (1.0f / kC);
    float var = sg * (1.0f / kC) - mu * mu;
    float rs = rsqrtf(var + 1e-5f);
    #pragma unroll
    for (int ct = 0; ct < 4; ++ct) {
      int c = c0 + ct * 16 + lr;
      float yv = (v[r][ct] - mu) * rs * g[c] + bb[c];
      if (!DO_BASE) {
        Out[(size_t)(m0 + lrow) * kC + c] = yv;
      } else {
        unsigned int off = (((unsigned)lrow * 512u) + (unsigned)c * 2u) ^ (((unsigned)lrow & 7u) << 4);
        *(unsigned short*)((char*)Xs + off) = f2bf(yv);
      }
    }
  }

  if (DO_BASE) {
    __syncthreads();
    f32x4 acc2[4] = {};
    #pragma unroll
    for (int ks = 0; ks < 8; ++ks) {
      const int k0 = ks * 32;
      unsigned int aoff = (((unsigned)lr * 512u) + (unsigned)(k0 + kb * 8) * 2u) ^
                          (((unsigned)lr & 7u) << 4);
      bf16x8 a = *(const bf16x8*)((const char*)Xs + aoff);
      #pragma unroll
      for (int ct = 0; ct < 4; ++ct) {
        bf16x8 b = *(const bf16x8*)&WbB[(size_t)(c0 + ct * 16 + lr) * kC + k0 + kb * 8];
        acc2[ct] = __builtin_amdgcn_mfma_f32_16x16x32_bf16(a, b, acc2[ct], 0, 0, 0);
      }
    }
    #pragma unroll
    for (int r = 0; r < 4; ++r) {
      int row = m0 + kb * 4 + r;
      #pragma unroll
      for (int ct = 0; ct < 4; ++ct) {
        int c = c0 + ct * 16 + lr;
        Out[(size_t)row * kC + c] = acc2[ct][r] + biasB[c];
      }
    }
  }
}

// ---------------------------------------------------------------- bf16 MFMA GEMM, f32 A, bf16 out + RELU (lin1)
__global__ __launch_bounds__(256) void k_gemm_ff1(const float* __restrict__ A,
                                                  const unsigned short* __restrict__ Wb,
                                                  const float* __restrict__ bias,
                                                  unsigned short* __restrict__ Cc) {
  const int m0 = blockIdx.y * 64;
  const int nb = blockIdx.x * 256;
  const int t = threadIdx.x;
  const int lane = t & 63, w = t >> 6;
  const int c0 = nb + w * 64;
  const int kb = lane >> 4, lr = lane & 15;

  __shared__ __align__(16) unsigned short As[64 * 256];

  f32x4 acc[4][4] = {};
  #pragma unroll
  for (int i = 0; i < 16; ++i) {
    int row = i * 4 + w;
    float4 f4 = *(const float4*)&A[(size_t)(m0 + row) * kC + lane * 4];
    ushort4 b4;
    b4.x = f2bf(f4.x); b4.y = f2bf(f4.y); b4.z = f2bf(f4.z); b4.w = f2bf(f4.w);
    unsigned int off = (((unsigned)row * 512u) + (unsigned)lane * 8u) ^ (((unsigned)row & 7u) << 4);
    *(ushort4*)((char*)As + off) = b4;
  }
  __syncthreads();

  #pragma unroll
  for (int ks = 0; ks < 8; ++ks) {
    const int k0 = ks * 32;
    bf16x8 a[4], b[4];
    #pragma unroll
    for (int rt = 0; rt < 4; ++rt) {
      int row = rt * 16 + lr;
      unsigned int off = (((unsigned)row * 512u) + (unsigned)(k0 + kb * 8) * 2u) ^
                         (((unsigned)row & 7u) << 4);
      a[rt] = *(const bf16x8*)((const char*)As + off);
    }
    #pragma unroll
    for (int ct = 0; ct < 4; ++ct) {
      int c = c0 + ct * 16 + lr;
      b[ct] = *(const bf16x8*)&Wb[(size_t)c * kC + k0 + kb * 8];
    }
    #pragma unroll
    for (int rt = 0; rt < 4; ++rt)
      #pragma unroll
      for (int ct = 0; ct < 4; ++ct)
        acc[rt][ct] = __builtin_amdgcn_mfma_f32_16x16x32_bf16(a[rt], b[ct], acc[rt][ct], 0, 0, 0);
  }

  #pragma unroll
  for (int rt = 0; rt < 4; ++rt) {
    #pragma unroll
    for (int r = 0; r < 4; ++r) {
      int row = m0 + rt * 16 + kb * 4 + r;
      #pragma unroll
      for (int ct = 0; ct < 4; ++ct) {
        int c = c0 + ct * 16 + lr;
        float vv = fmaxf(acc[rt][ct][r] + bias[c], 0.f);
        Cc[(size_t)row * kFF + c] = f2bf(vv);
      }
    }
  }
}

// ---------------------------------------------------------------- fuse: bf16 MFMA GEMM (gathered A) + scatter
__global__ __launch_bounds__(256) void k_fuse(const float* __restrict__ feats,
                                              const int* __restrict__ gidx,
                                              const int* __restrict__ wlist,
                                              const int* __restrict__ cnt,
                                              const int* __restrict__ win2flat,
                                              const int* __restrict__ x_idx,
                                              const float* __restrict__ base,
                                              const unsigned short* __restrict__ W2B,
                                              float* __restrict__ out) {
  const int count = cnt[0];
  const int r0 = blockIdx.x * 64;
  if (r0 >= count) return;
  const int nr = min(64, count - r0);
  const int t = threadIdx.x;
  const int lane = t & 63, w = t >> 6;

  __shared__ __align__(16) unsigned short As[64 * 256];
  __shared__ int dstrow[64], wwin[64], srcrow[64];

  if (t < 64) {
    int rr = min(r0 + t, count - 1);
    int i = wlist[rr];
    int j = win2flat[i];
    srcrow[t] = gidx[j];
    wwin[t] = j >> 6;
    dstrow[t] = x_idx[i];
  }
  __syncthreads();

  for (int i = 0; i < 16; ++i) {
    int row = i * 4 + w;
    float4 f4 = *(const float4*)&feats[(size_t)srcrow[row] * kC + lane * 4];
    ushort4 b4;
    b4.x = f2bf(f4.x); b4.y = f2bf(f4.y); b4.z = f2bf(f4.z); b4.w = f2bf(f4.w);
    unsigned int off = (((unsigned)row * 512u) + (unsigned)lane * 8u) ^ (((unsigned)row & 7u) << 4);
    *(ushort4*)((char*)As + off) = b4;
  }
  __syncthreads();

  const int c0 = w * 64;
  const int kb = lane >> 4;
  const int lr = lane & 15;
  f32x4 acc[4][4] = {};
  for (int ks = 0; ks < 8; ++ks) {
    const int k0 = ks * 32;
    bf16x8 a[4], b[4];
    #pragma unroll
    for (int rt = 0; rt < 4; ++rt) {
      int row = rt * 16 + lr;
      unsigned int off = (((unsigned)row * 512u) + (unsigned)(k0 + kb * 8) * 2u) ^
                         (((unsigned)row & 7u) << 4);
      a[rt] = *(const bf16x8*)((const char*)As + off);
    }
    #pragma unroll
    for (int ct = 0; ct < 4; ++ct) {
      int c = c0 + ct * 16 + lr;
      b[ct] = *(const bf16x8*)&W2B[(size_t)c * kC + k0 + kb * 8];
    }
    #pragma unroll
    for (int rt = 0; rt < 4; ++rt)
      #pragma unroll
      for (int ct = 0; ct < 4; ++ct)
        acc[rt][ct] = __builtin_amdgcn_mfma_f32_16x16x32_bf16(a[rt], b[ct], acc[rt][ct], 0, 0, 0);
  }

  #pragma unroll
  for (int rt = 0; rt < 4; ++rt) {
    #pragma unroll
    for (int r = 0; r < 4; ++r) {
      int row = rt * 16 + kb * 4 + r;
      if (row < nr) {
        size_t orow = (size_t)dstrow[row] * kC;
        size_t brow = (size_t)wwin[row] * kC;
        #pragma unroll
        for (int ct = 0; ct < 4; ++ct) {
          int c = c0 + ct * 16 + lr;
          out[orow + c] = acc[rt][ct][r] + base[brow + c];
        }
      }
    }
  }
}

// ---------------------------------------------------------------- launch
extern "C" void kernel_launch(void* const* d_in, const int* in_sizes, int n_in,
                              void* d_out, int out_size, void* d_ws, size_t ws_size,
                              hipStream_t stream) {
  const float* feats      = (const float*)d_in[0];
  const int*   x_idx      = (const int*)d_in[1];
  const int*   flat2win   = (const int*)d_in[2];
  const int*   win2flat   = (const int*)d_in[3];
  const float* in_proj_w  = (const float*)d_in[4];
  const float* in_proj_b  = (const float*)d_in[5];
  const float* out_proj_w = (const float*)d_in[6];
  const float* out_proj_b = (const float*)d_in[7];
  const float* lin1_w     = (const float*)d_in[8];
  const float* lin1_b     = (const float*)d_in[9];
  const float* lin2_w     = (const float*)d_in[10];
  const float* lin2_b     = (const float*)d_in[11];
  const float* ln1_g      = (const float*)d_in[12];
  const float* ln1_b      = (const float*)d_in[13];
  const float* ln2_g      = (const float*)d_in[14];
  const float* ln2_b      = (const float*)d_in[15];
  const float* proj_w     = (const float*)d_in[16];
  const float* proj_b     = (const float*)d_in[17];

  char* ws = (char*)d_ws;
  int*   gidx   = (int*)(ws + OFF_GIDX);
  int*   winner = (int*)(ws + OFF_WINNER);
  int*   wlist  = (int*)(ws + OFF_WLIST);
  int*   cnt    = (int*)(ws + OFF_CNT);
  float* x0     = (float*)(ws + OFF_X0);
  float* basep  = (float*)(ws + OFF_BASE);
  float* x1     = (float*)(ws + OFF_X1);
  unsigned short* attnb = (unsigned short*)(ws + OFF_ATTN);
  unsigned short* Qh    = (unsigned short*)(ws + OFF_QH);
  unsigned short* Kh    = (unsigned short*)(ws + OFF_KH);
  unsigned short* Vh    = (unsigned short*)(ws + OFF_VH);
  unsigned short* ff1b  = (unsigned short*)(ws + OFF_FF1);
  unsigned short* WINB  = (unsigned short*)(ws + OFF_WINB);
  unsigned short* WOUTB = (unsigned short*)(ws + OFF_WOUTB);
  unsigned short* W1B   = (unsigned short*)(ws + OFF_W1B);
  unsigned short* W2B   = (unsigned short*)(ws + OFF_W2B);
  unsigned short* WP1B  = (unsigned short*)(ws + OFF_WP1B);
  unsigned short* WP2B  = (unsigned short*)(ws + OFF_WP2B);
  float* out    = (float*)d_out;

  hipMemsetAsync(winner, 0xFF, (size_t)kL * sizeof(int), stream);   // -1
  hipMemsetAsync(cnt, 0, sizeof(int), stream);

  k_winner<<<kL / 256, 256, 0, stream>>>(x_idx, winner);
  k_compact<<<kL / 256, 256, 0, stream>>>(x_idx, winner, wlist, cnt);
  k_copy<<<kL / 4, 256, 0, stream>>>(feats, winner, out);
  k_pool<<<kNW, 256, 0, stream>>>(feats, x_idx, flat2win, gidx, x0);
  k_wcast<<<1536, 256, 0, stream>>>(in_proj_w, out_proj_w, lin1_w, lin2_w, proj_w,
                                    WINB, WOUTB, W1B, W2B, WP1B, WP2B);

  // qkv + per-head transpose fused
  k_gemm_qkv<<<dim3(3, kNW / 64), 256, 0, stream>>>(x0, WINB, in_proj_b, Qh, Kh, Vh);
  k_attn<<<dim3(kS / 64, kBS * kNH), 256, 0, stream>>>(Qh, Kh, Vh, attnb);
  // out_proj + residual(x0) + LN1 -> x1
  k_gemm_ln<false><<<kNW / 16, 256, 0, stream>>>(
      attnb, kC, WOUTB, out_proj_b, x0, ln1_g, ln1_b, x1, nullptr, nullptr);
  // ff1 = relu(x1 @ lin1^T + b) -> bf16
  k_gemm_ff1<<<dim3(kFF / 256, kNW / 64), 256, 0, stream>>>(x1, W1B, lin1_b, ff1b);
  // lin2 + residual(x1) + LN2 -> (chained) base = x2 @ WP1^T + proj_b
  k_gemm_ln<true><<<kNW / 16, 256, 0, stream>>>(
      ff1b, kFF, W2B, lin2_b, x1, ln2_g, ln2_b, basep, WP1B, proj_b);
  k_fuse<<<kL / 64, 256, 0, stream>>>(feats, gidx, wlist, cnt, win2flat, x_idx,
                                      basep, WP2B, out);
}

// Round 7
// 385.781 us; speedup vs baseline: 3.7274x; 1.0476x over previous
//
#include <hip/hip_runtime.h>
#include <math.h>

namespace {
constexpr int kL    = 262144;
constexpr int kC    = 256;
constexpr int kNH   = 8;
constexpr int kG    = 64;
constexpr int kFF   = 2048;
constexpr int kLPAD = 262144;
constexpr int kBS   = 4;
constexpr int kNW   = kLPAD / kG;   // 4096
constexpr int kS    = kNW / kBS;    // 1024
constexpr int kHD   = kC / kNH;     // 32

constexpr size_t MB        = 1024 * 1024;
constexpr size_t OFF_GIDX   = 0;         // int[LPAD]      1MB
constexpr size_t OFF_WINNER = 1 * MB;    // int[L]         1MB
constexpr size_t OFF_WLIST  = 2 * MB;    // int[L]         1MB
constexpr size_t OFF_CNT    = 3 * MB;    // int[1]
constexpr size_t OFF_X0     = 4 * MB;    // f32[4096*256]  4MB
constexpr size_t OFF_BASE   = 8 * MB;    // f32[4096*256]  4MB
constexpr size_t OFF_ATTN   = 12 * MB;   // bf16[4096*256] 2MB
constexpr size_t OFF_QH     = 16 * MB;   // bf16 2MB
constexpr size_t OFF_KH     = 18 * MB;   // 2MB
constexpr size_t OFF_VH     = 20 * MB;   // 2MB
constexpr size_t OFF_X1     = 24 * MB;   // f32[4096*256]  4MB
constexpr size_t OFF_FF1    = 32 * MB;   // bf16[4096*2048] 16MB
constexpr size_t OFF_WINB   = 64 * MB;                 // bf16[768*256]  384KB
constexpr size_t OFF_WOUTB  = OFF_WINB  + 512 * 1024;  // bf16[256*256]  128KB
constexpr size_t OFF_W1B    = OFF_WOUTB + 256 * 1024;  // bf16[2048*256] 1MB
constexpr size_t OFF_W2B    = OFF_W1B   + 1536 * 1024; // bf16[256*2048] 1MB
constexpr size_t OFF_WP1B   = OFF_W2B   + 1536 * 1024; // bf16[256*256]  128KB
constexpr size_t OFF_WP2B   = OFF_WP1B  + 256 * 1024;  // bf16[256*256]  128KB

typedef __attribute__((ext_vector_type(8))) short bf16x8;
typedef __attribute__((ext_vector_type(4))) float f32x4;

__device__ inline unsigned short f2bf(float f) {
  union { float f; unsigned int u; } x; x.f = f;
  unsigned int r = x.u + 0x7fff + ((x.u >> 16) & 1);   // RNE
  return (unsigned short)(r >> 16);
}
} // namespace

// ---------------------------------------------------------------- winner (+cnt init)
__global__ __launch_bounds__(256) void k_winner(const int* __restrict__ x_idx,
                                                int* __restrict__ winner,
                                                int* __restrict__ cnt) {
  int i = blockIdx.x * 256 + threadIdx.x;
  if (i == 0) cnt[0] = 0;              // consumed only by k_fc (next kernel)
  atomicMax(&winner[x_idx[i]], i);
}

// ---------------------------------------------------------------- merged: compact (blk<1024) + weight casts
__global__ __launch_bounds__(256) void k_fc(const int* __restrict__ x_idx,
                                            const int* __restrict__ winner,
                                            int* __restrict__ wlist,
                                            int* __restrict__ cnt,
                                            const float* __restrict__ in_proj_w,
                                            const float* __restrict__ out_proj_w,
                                            const float* __restrict__ lin1_w,
                                            const float* __restrict__ lin2_w,
                                            const float* __restrict__ proj_w,
                                            unsigned short* __restrict__ WINB,
                                            unsigned short* __restrict__ WOUTB,
                                            unsigned short* __restrict__ W1B,
                                            unsigned short* __restrict__ W2B,
                                            unsigned short* __restrict__ WP1,
                                            unsigned short* __restrict__ WP2) {
  int blk = blockIdx.x, t = threadIdx.x;
  if (blk < 1024) {                      // compact
    int i = blk * 256 + t;
    if (winner[x_idx[i]] == i) {
      int p = atomicAdd(cnt, 1);
      wlist[p] = i;
    }
    return;
  }
  int b2 = blk - 1024;                   // weight casts
  const float* src = nullptr; unsigned short* dst = nullptr; int i = 0;
  if (b2 < 192)       { src = in_proj_w;  dst = WINB;  i = b2 * 256 + t; }
  else if (b2 < 256)  { src = out_proj_w; dst = WOUTB; i = (b2 - 192) * 256 + t; }
  else if (b2 < 768)  { src = lin1_w;     dst = W1B;   i = (b2 - 256) * 256 + t; }
  else if (b2 < 1280) { src = lin2_w;     dst = W2B;   i = (b2 - 768) * 256 + t; }
  else {
    int c = b2 - 1280;
    WP1[c * kC + t] = f2bf(proj_w[(size_t)c * (2 * kC) + t]);
    WP2[c * kC + t] = f2bf(proj_w[(size_t)c * (2 * kC) + kC + t]);
    return;
  }
  float4 v = ((const float4*)src)[i];
  ushort4 b;
  b.x = f2bf(v.x); b.y = f2bf(v.y); b.z = f2bf(v.z); b.w = f2bf(v.w);
  ((ushort4*)dst)[i] = b;
}

// ---------------------------------------------------------------- merged: pool (blk<4096) + selective copy
__global__ __launch_bounds__(256) void k_pc(const float* __restrict__ feats,
                                            const int* __restrict__ x_idx,
                                            const int* __restrict__ flat2win,
                                            const int* __restrict__ winner,
                                            int* __restrict__ gidx,
                                            float* __restrict__ x0,
                                            float* __restrict__ out) {
  int blk = blockIdx.x, t = threadIdx.x;
  if (blk < kNW) {                       // pool
    __shared__ int rows[kG];
    if (t < kG) {
      int g = x_idx[flat2win[blk * kG + t]];
      rows[t] = g;
      gidx[blk * kG + t] = g;
    }
    __syncthreads();
    float m = -INFINITY;
    #pragma unroll 4
    for (int g = 0; g < kG; ++g)
      m = fmaxf(m, feats[(size_t)rows[g] * kC + t]);
    x0[blk * kC + t] = m;
    return;
  }
  // copy rows not overwritten by the fuse scatter
  size_t idx = (size_t)(blk - kNW) * 256 + t;
  int row = (int)(idx >> 6);
  int c4 = (int)(idx & 63);
  if (winner[row] < 0) {
    *(float4*)&out[(size_t)row * kC + c4 * 4] =
        *(const float4*)&feats[(size_t)row * kC + c4 * 4];
  }
}

// ---------------------------------------------------------------- qkv GEMM with per-head bf16 scatter epilogue
__global__ __launch_bounds__(256) void k_gemm_qkv(const float* __restrict__ A,
                                                  const unsigned short* __restrict__ Wb,
                                                  const float* __restrict__ bias,
                                                  unsigned short* __restrict__ Qh,
                                                  unsigned short* __restrict__ Kh,
                                                  unsigned short* __restrict__ Vh) {
  const float scale = 0.17677669529663687f;   // 1/sqrt(32)
  const int m0 = blockIdx.y * 64;
  const int sec = blockIdx.x;
  const int t = threadIdx.x;
  const int lane = t & 63, w = t >> 6;
  const int c0 = w * 64;
  const int kb = lane >> 4, lr = lane & 15;

  __shared__ __align__(16) unsigned short As[64 * 256];

  f32x4 acc[4][4] = {};
  #pragma unroll
  for (int i = 0; i < 16; ++i) {
    int row = i * 4 + w;
    float4 f4 = *(const float4*)&A[(size_t)(m0 + row) * kC + lane * 4];
    ushort4 b4;
    b4.x = f2bf(f4.x); b4.y = f2bf(f4.y); b4.z = f2bf(f4.z); b4.w = f2bf(f4.w);
    unsigned int off = (((unsigned)row * 512u) + (unsigned)lane * 8u) ^ (((unsigned)row & 7u) << 4);
    *(ushort4*)((char*)As + off) = b4;
  }
  __syncthreads();

  #pragma unroll
  for (int ks = 0; ks < 8; ++ks) {
    const int k0 = ks * 32;
    bf16x8 a[4], b[4];
    #pragma unroll
    for (int rt = 0; rt < 4; ++rt) {
      int row = rt * 16 + lr;
      unsigned int off = (((unsigned)row * 512u) + (unsigned)(k0 + kb * 8) * 2u) ^
                         (((unsigned)row & 7u) << 4);
      a[rt] = *(const bf16x8*)((const char*)As + off);
    }
    #pragma unroll
    for (int ct = 0; ct < 4; ++ct) {
      int c = sec * kC + c0 + ct * 16 + lr;
      b[ct] = *(const bf16x8*)&Wb[(size_t)c * kC + k0 + kb * 8];
    }
    #pragma unroll
    for (int rt = 0; rt < 4; ++rt)
      #pragma unroll
      for (int ct = 0; ct < 4; ++ct)
        acc[rt][ct] = __builtin_amdgcn_mfma_f32_16x16x32_bf16(a[rt], b[ct], acc[rt][ct], 0, 0, 0);
  }

  unsigned short* dstbuf = (sec == 0) ? Qh : (sec == 1) ? Kh : Vh;
  #pragma unroll
  for (int rt = 0; rt < 4; ++rt) {
    #pragma unroll
    for (int r = 0; r < 4; ++r) {
      int row = m0 + rt * 16 + kb * 4 + r;
      int bb = row >> 10, s = row & 1023;
      #pragma unroll
      for (int ct = 0; ct < 4; ++ct) {
        int c = c0 + ct * 16 + lr;
        float v = acc[rt][ct][r] + bias[sec * kC + c];
        if (sec == 0) v *= scale;
        int h = c >> 5, d = c & 31;
        dstbuf[(((size_t)(bb * kNH + h) * kS) + s) * kHD + d] = f2bf(v);
      }
    }
  }
}

// ---------------------------------------------------------------- flash attention, bf16 MFMA, KVBLK=128
__global__ __launch_bounds__(256) void k_attn(const unsigned short* __restrict__ Qh,
                                              const unsigned short* __restrict__ Kh,
                                              const unsigned short* __restrict__ Vh,
                                              unsigned short* __restrict__ attn_out) {
  const int q0 = blockIdx.x * 64;
  const int bh = blockIdx.y;           // b*8+h
  const int b = bh >> 3, h = bh & 7;
  const int t = threadIdx.x;
  const int lane = t & 63, w = t >> 6;
  const int kb = lane >> 4, lr = lane & 15;

  __shared__ __align__(16) unsigned short Ks[128][40];     // 10KB
  __shared__ __align__(16) unsigned short VTs[32][136];    // 8.5KB
  __shared__ __align__(16) unsigned short Ps[4][16][136];  // 17KB

  bf16x8 aq = *(const bf16x8*)(Qh + (((size_t)bh * kS) + q0 + w * 16 + lr) * kHD + kb * 8);

  const unsigned short* kbase = Kh + (size_t)bh * kS * kHD;
  const unsigned short* vbase = Vh + (size_t)bh * kS * kHD;

  float m[4], l[4];
  f32x4 O[2] = {};
  #pragma unroll
  for (int r = 0; r < 4; ++r) { m[r] = -INFINITY; l[r] = 0.f; }

  for (int kt = 0; kt < kS / 128; ++kt) {
    {
      int key = t >> 1, d0 = (t & 1) * 16;
      size_t srow = ((size_t)(kt * 128 + key)) * kHD + d0;
      bf16x8 kv0 = *(const bf16x8*)(kbase + srow);
      bf16x8 kv1 = *(const bf16x8*)(kbase + srow + 8);
      *(bf16x8*)&Ks[key][d0] = kv0;
      *(bf16x8*)&Ks[key][d0 + 8] = kv1;
      bf16x8 vv0 = *(const bf16x8*)(vbase + srow);
      bf16x8 vv1 = *(const bf16x8*)(vbase + srow + 8);
      #pragma unroll
      for (int i = 0; i < 8; ++i) {
        VTs[d0 + i][key] = (unsigned short)vv0[i];
        VTs[d0 + 8 + i][key] = (unsigned short)vv1[i];
      }
    }
    __syncthreads();

    f32x4 S[8] = {};
    #pragma unroll
    for (int ct = 0; ct < 8; ++ct) {
      bf16x8 bk = *(const bf16x8*)&Ks[ct * 16 + lr][kb * 8];
      S[ct] = __builtin_amdgcn_mfma_f32_16x16x32_bf16(aq, bk, S[ct], 0, 0, 0);
    }

    float alpha[4];
    #pragma unroll
    for (int r = 0; r < 4; ++r) {
      float tmax = -INFINITY;
      #pragma unroll
      for (int ct = 0; ct < 8; ++ct) tmax = fmaxf(tmax, S[ct][r]);
      #pragma unroll
      for (int off = 8; off; off >>= 1) tmax = fmaxf(tmax, __shfl_xor(tmax, off, 16));
      float newm = fmaxf(m[r], tmax);
      alpha[r] = __expf(m[r] - newm);
      float ps = 0.f;
      #pragma unroll
      for (int ct = 0; ct < 8; ++ct) {
        float p = __expf(S[ct][r] - newm);
        ps += p;
        Ps[w][kb * 4 + r][ct * 16 + lr] = f2bf(p);
      }
      #pragma unroll
      for (int off = 8; off; off >>= 1) ps += __shfl_xor(ps, off, 16);
      l[r] = l[r] * alpha[r] + ps;
      m[r] = newm;
    }
    #pragma unroll
    for (int r = 0; r < 4; ++r) { O[0][r] *= alpha[r]; O[1][r] *= alpha[r]; }

    #pragma unroll
    for (int ks = 0; ks < 4; ++ks) {
      bf16x8 ap = *(const bf16x8*)&Ps[w][lr][ks * 32 + kb * 8];
      #pragma unroll
      for (int ct = 0; ct < 2; ++ct) {
        bf16x8 bv = *(const bf16x8*)&VTs[ct * 16 + lr][ks * 32 + kb * 8];
        O[ct] = __builtin_amdgcn_mfma_f32_16x16x32_bf16(ap, bv, O[ct], 0, 0, 0);
      }
    }
    __syncthreads();
  }

  #pragma unroll
  for (int ct = 0; ct < 2; ++ct) {
    #pragma unroll
    for (int r = 0; r < 4; ++r) {
      size_t row = (size_t)b * kS + q0 + w * 16 + kb * 4 + r;
      attn_out[row * kC + h * kHD + ct * 16 + lr] = f2bf(O[ct][r] / l[r]);
    }
  }
}

// ---------------------------------------------------------------- 16-row GEMM + residual + LN (+ optional chained base GEMM)
template <bool DO_BASE>
__global__ __launch_bounds__(256) void k_gemm_ln(const unsigned short* __restrict__ A,
                                                 int K,
                                                 const unsigned short* __restrict__ Wb,
                                                 const float* __restrict__ bias,
                                                 const float* __restrict__ R,
                                                 const float* __restrict__ g,
                                                 const float* __restrict__ bb,
                                                 float* __restrict__ Out,
                                                 const unsigned short* __restrict__ WbB,
                                                 const float* __restrict__ biasB) {
  const int m0 = blockIdx.x * 16;
  const int t = threadIdx.x;
  const int lane = t & 63, w = t >> 6;
  const int c0 = w * 64;
  const int kb = lane >> 4, lr = lane & 15;

  __shared__ __align__(16) unsigned short As[16 * 256];
  __shared__ __align__(16) unsigned short Xs[16 * 256];
  __shared__ float red[2][16][4];

  f32x4 acc[4] = {};
  for (int kc = 0; kc < K; kc += 256) {
    #pragma unroll
    for (int i = 0; i < 2; ++i) {
      int idx = i * 256 + t;
      int row = idx >> 5, seg = idx & 31;
      bf16x8 v = *(const bf16x8*)&A[(size_t)(m0 + row) * K + kc + seg * 8];
      unsigned int off = (((unsigned)row * 512u) + (unsigned)seg * 16u) ^ (((unsigned)row & 7u) << 4);
      *(bf16x8*)((char*)As + off) = v;
    }
    __syncthreads();

    #pragma unroll
    for (int ks = 0; ks < 8; ++ks) {
      const int k0 = ks * 32;
      unsigned int aoff = (((unsigned)lr * 512u) + (unsigned)(k0 + kb * 8) * 2u) ^
                          (((unsigned)lr & 7u) << 4);
      bf16x8 a = *(const bf16x8*)((const char*)As + aoff);
      #pragma unroll
      for (int ct = 0; ct < 4; ++ct) {
        bf16x8 b = *(const bf16x8*)&Wb[(size_t)(c0 + ct * 16 + lr) * K + kc + k0 + kb * 8];
        acc[ct] = __builtin_amdgcn_mfma_f32_16x16x32_bf16(a, b, acc[ct], 0, 0, 0);
      }
    }
    __syncthreads();
  }

  float v[4][4];
  float s[4], sq[4];
  #pragma unroll
  for (int r = 0; r < 4; ++r) { s[r] = 0.f; sq[r] = 0.f; }
  #pragma unroll
  for (int r = 0; r < 4; ++r) {
    int row = m0 + kb * 4 + r;
    #pragma unroll
    for (int ct = 0; ct < 4; ++ct) {
      int c = c0 + ct * 16 + lr;
      float x = acc[ct][r] + bias[c] + R[(size_t)row * kC + c];
      v[r][ct] = x;
      s[r] += x;
      sq[r] += x * x;
    }
  }
  #pragma unroll
  for (int r = 0; r < 4; ++r) {
    #pragma unroll
    for (int off = 8; off; off >>= 1) {
      s[r]  += __shfl_xor(s[r], off, 16);
      sq[r] += __shfl_xor(sq[r], off, 16);
    }
    if (lr == 0) { red[0][kb * 4 + r][w] = s[r]; red[1][kb * 4 + r][w] = sq[r]; }
  }
  __syncthreads();

  #pragma unroll
  for (int r = 0; r < 4; ++r) {
    int lrow = kb * 4 + r;
    float su = red[0][lrow][0] + red[0][lrow][1] + red[0][lrow][2] + red[0][lrow][3];
    float sg = red[1][lrow][0] + red[1][lrow][1] + red[1][lrow][2] + red[1][lrow][3];
    float mu = su * (1.0f / kC);
    float var = sg * (1.0f / kC) - mu * mu;
    float rs = rsqrtf(var + 1e-5f);
    #pragma unroll
    for (int ct = 0; ct < 4; ++ct) {
      int c = c0 + ct * 16 + lr;
      float yv = (v[r][ct] - mu) * rs * g[c] + bb[c];
      if (!DO_BASE) {
        Out[(size_t)(m0 + lrow) * kC + c] = yv;
      } else {
        unsigned int off = (((unsigned)lrow * 512u) + (unsigned)c * 2u) ^ (((unsigned)lrow & 7u) << 4);
        *(unsigned short*)((char*)Xs + off) = f2bf(yv);
      }
    }
  }

  if (DO_BASE) {
    __syncthreads();
    f32x4 acc2[4] = {};
    #pragma unroll
    for (int ks = 0; ks < 8; ++ks) {
      const int k0 = ks * 32;
      unsigned int aoff = (((unsigned)lr * 512u) + (unsigned)(k0 + kb * 8) * 2u) ^
                          (((unsigned)lr & 7u) << 4);
      bf16x8 a = *(const bf16x8*)((const char*)Xs + aoff);
      #pragma unroll
      for (int ct = 0; ct < 4; ++ct) {
        bf16x8 b = *(const bf16x8*)&WbB[(size_t)(c0 + ct * 16 + lr) * kC + k0 + kb * 8];
        acc2[ct] = __builtin_amdgcn_mfma_f32_16x16x32_bf16(a, b, acc2[ct], 0, 0, 0);
      }
    }
    #pragma unroll
    for (int r = 0; r < 4; ++r) {
      int row = m0 + kb * 4 + r;
      #pragma unroll
      for (int ct = 0; ct < 4; ++ct) {
        int c = c0 + ct * 16 + lr;
        Out[(size_t)row * kC + c] = acc2[ct][r] + biasB[c];
      }
    }
  }
}

// ---------------------------------------------------------------- bf16 MFMA GEMM, f32 A, bf16 out + RELU (lin1)
__global__ __launch_bounds__(256) void k_gemm_ff1(const float* __restrict__ A,
                                                  const unsigned short* __restrict__ Wb,
                                                  const float* __restrict__ bias,
                                                  unsigned short* __restrict__ Cc) {
  const int m0 = blockIdx.y * 64;
  const int nb = blockIdx.x * 256;
  const int t = threadIdx.x;
  const int lane = t & 63, w = t >> 6;
  const int c0 = nb + w * 64;
  const int kb = lane >> 4, lr = lane & 15;

  __shared__ __align__(16) unsigned short As[64 * 256];

  f32x4 acc[4][4] = {};
  #pragma unroll
  for (int i = 0; i < 16; ++i) {
    int row = i * 4 + w;
    float4 f4 = *(const float4*)&A[(size_t)(m0 + row) * kC + lane * 4];
    ushort4 b4;
    b4.x = f2bf(f4.x); b4.y = f2bf(f4.y); b4.z = f2bf(f4.z); b4.w = f2bf(f4.w);
    unsigned int off = (((unsigned)row * 512u) + (unsigned)lane * 8u) ^ (((unsigned)row & 7u) << 4);
    *(ushort4*)((char*)As + off) = b4;
  }
  __syncthreads();

  #pragma unroll
  for (int ks = 0; ks < 8; ++ks) {
    const int k0 = ks * 32;
    bf16x8 a[4], b[4];
    #pragma unroll
    for (int rt = 0; rt < 4; ++rt) {
      int row = rt * 16 + lr;
      unsigned int off = (((unsigned)row * 512u) + (unsigned)(k0 + kb * 8) * 2u) ^
                         (((unsigned)row & 7u) << 4);
      a[rt] = *(const bf16x8*)((const char*)As + off);
    }
    #pragma unroll
    for (int ct = 0; ct < 4; ++ct) {
      int c = c0 + ct * 16 + lr;
      b[ct] = *(const bf16x8*)&Wb[(size_t)c * kC + k0 + kb * 8];
    }
    #pragma unroll
    for (int rt = 0; rt < 4; ++rt)
      #pragma unroll
      for (int ct = 0; ct < 4; ++ct)
        acc[rt][ct] = __builtin_amdgcn_mfma_f32_16x16x32_bf16(a[rt], b[ct], acc[rt][ct], 0, 0, 0);
  }

  #pragma unroll
  for (int rt = 0; rt < 4; ++rt) {
    #pragma unroll
    for (int r = 0; r < 4; ++r) {
      int row = m0 + rt * 16 + kb * 4 + r;
      #pragma unroll
      for (int ct = 0; ct < 4; ++ct) {
        int c = c0 + ct * 16 + lr;
        float vv = fmaxf(acc[rt][ct][r] + bias[c], 0.f);
        Cc[(size_t)row * kFF + c] = f2bf(vv);
      }
    }
  }
}

// ---------------------------------------------------------------- fuse: bf16 MFMA GEMM (gathered A) + scatter
__global__ __launch_bounds__(256) void k_fuse(const float* __restrict__ feats,
                                              const int* __restrict__ gidx,
                                              const int* __restrict__ wlist,
                                              const int* __restrict__ cnt,
                                              const int* __restrict__ win2flat,
                                              const int* __restrict__ x_idx,
                                              const float* __restrict__ base,
                                              const unsigned short* __restrict__ W2B,
                                              float* __restrict__ out) {
  const int count = cnt[0];
  const int r0 = blockIdx.x * 64;
  if (r0 >= count) return;
  const int nr = min(64, count - r0);
  const int t = threadIdx.x;
  const int lane = t & 63, w = t >> 6;

  __shared__ __align__(16) unsigned short As[64 * 256];
  __shared__ int dstrow[64], wwin[64], srcrow[64];

  if (t < 64) {
    int rr = min(r0 + t, count - 1);
    int i = wlist[rr];
    int j = win2flat[i];
    srcrow[t] = gidx[j];
    wwin[t] = j >> 6;
    dstrow[t] = x_idx[i];
  }
  __syncthreads();

  for (int i = 0; i < 16; ++i) {
    int row = i * 4 + w;
    float4 f4 = *(const float4*)&feats[(size_t)srcrow[row] * kC + lane * 4];
    ushort4 b4;
    b4.x = f2bf(f4.x); b4.y = f2bf(f4.y); b4.z = f2bf(f4.z); b4.w = f2bf(f4.w);
    unsigned int off = (((unsigned)row * 512u) + (unsigned)lane * 8u) ^ (((unsigned)row & 7u) << 4);
    *(ushort4*)((char*)As + off) = b4;
  }
  __syncthreads();

  const int c0 = w * 64;
  const int kb = lane >> 4;
  const int lr = lane & 15;
  f32x4 acc[4][4] = {};
  for (int ks = 0; ks < 8; ++ks) {
    const int k0 = ks * 32;
    bf16x8 a[4], b[4];
    #pragma unroll
    for (int rt = 0; rt < 4; ++rt) {
      int row = rt * 16 + lr;
      unsigned int off = (((unsigned)row * 512u) + (unsigned)(k0 + kb * 8) * 2u) ^
                         (((unsigned)row & 7u) << 4);
      a[rt] = *(const bf16x8*)((const char*)As + off);
    }
    #pragma unroll
    for (int ct = 0; ct < 4; ++ct) {
      int c = c0 + ct * 16 + lr;
      b[ct] = *(const bf16x8*)&W2B[(size_t)c * kC + k0 + kb * 8];
    }
    #pragma unroll
    for (int rt = 0; rt < 4; ++rt)
      #pragma unroll
      for (int ct = 0; ct < 4; ++ct)
        acc[rt][ct] = __builtin_amdgcn_mfma_f32_16x16x32_bf16(a[rt], b[ct], acc[rt][ct], 0, 0, 0);
  }

  #pragma unroll
  for (int rt = 0; rt < 4; ++rt) {
    #pragma unroll
    for (int r = 0; r < 4; ++r) {
      int row = rt * 16 + kb * 4 + r;
      if (row < nr) {
        size_t orow = (size_t)dstrow[row] * kC;
        size_t brow = (size_t)wwin[row] * kC;
        #pragma unroll
        for (int ct = 0; ct < 4; ++ct) {
          int c = c0 + ct * 16 + lr;
          out[orow + c] = acc[rt][ct][r] + base[brow + c];
        }
      }
    }
  }
}

// ---------------------------------------------------------------- launch
extern "C" void kernel_launch(void* const* d_in, const int* in_sizes, int n_in,
                              void* d_out, int out_size, void* d_ws, size_t ws_size,
                              hipStream_t stream) {
  const float* feats      = (const float*)d_in[0];
  const int*   x_idx      = (const int*)d_in[1];
  const int*   flat2win   = (const int*)d_in[2];
  const int*   win2flat   = (const int*)d_in[3];
  const float* in_proj_w  = (const float*)d_in[4];
  const float* in_proj_b  = (const float*)d_in[5];
  const float* out_proj_w = (const float*)d_in[6];
  const float* out_proj_b = (const float*)d_in[7];
  const float* lin1_w     = (const float*)d_in[8];
  const float* lin1_b     = (const float*)d_in[9];
  const float* lin2_w     = (const float*)d_in[10];
  const float* lin2_b     = (const float*)d_in[11];
  const float* ln1_g      = (const float*)d_in[12];
  const float* ln1_b      = (const float*)d_in[13];
  const float* ln2_g      = (const float*)d_in[14];
  const float* ln2_b      = (const float*)d_in[15];
  const float* proj_w     = (const float*)d_in[16];
  const float* proj_b     = (const float*)d_in[17];

  char* ws = (char*)d_ws;
  int*   gidx   = (int*)(ws + OFF_GIDX);
  int*   winner = (int*)(ws + OFF_WINNER);
  int*   wlist  = (int*)(ws + OFF_WLIST);
  int*   cnt    = (int*)(ws + OFF_CNT);
  float* x0     = (float*)(ws + OFF_X0);
  float* basep  = (float*)(ws + OFF_BASE);
  float* x1     = (float*)(ws + OFF_X1);
  unsigned short* attnb = (unsigned short*)(ws + OFF_ATTN);
  unsigned short* Qh    = (unsigned short*)(ws + OFF_QH);
  unsigned short* Kh    = (unsigned short*)(ws + OFF_KH);
  unsigned short* Vh    = (unsigned short*)(ws + OFF_VH);
  unsigned short* ff1b  = (unsigned short*)(ws + OFF_FF1);
  unsigned short* WINB  = (unsigned short*)(ws + OFF_WINB);
  unsigned short* WOUTB = (unsigned short*)(ws + OFF_WOUTB);
  unsigned short* W1B   = (unsigned short*)(ws + OFF_W1B);
  unsigned short* W2B   = (unsigned short*)(ws + OFF_W2B);
  unsigned short* WP1B  = (unsigned short*)(ws + OFF_WP1B);
  unsigned short* WP2B  = (unsigned short*)(ws + OFF_WP2B);
  float* out    = (float*)d_out;

  hipMemsetAsync(winner, 0xFF, (size_t)kL * sizeof(int), stream);   // -1

  k_winner<<<kL / 256, 256, 0, stream>>>(x_idx, winner, cnt);
  k_fc<<<1024 + 1536, 256, 0, stream>>>(x_idx, winner, wlist, cnt,
                                        in_proj_w, out_proj_w, lin1_w, lin2_w, proj_w,
                                        WINB, WOUTB, W1B, W2B, WP1B, WP2B);
  k_pc<<<kNW + kL / 4, 256, 0, stream>>>(feats, x_idx, flat2win, winner, gidx, x0, out);

  k_gemm_qkv<<<dim3(3, kNW / 64), 256, 0, stream>>>(x0, WINB, in_proj_b, Qh, Kh, Vh);
  k_attn<<<dim3(kS / 64, kBS * kNH), 256, 0, stream>>>(Qh, Kh, Vh, attnb);
  k_gemm_ln<false><<<kNW / 16, 256, 0, stream>>>(
      attnb, kC, WOUTB, out_proj_b, x0, ln1_g, ln1_b, x1, nullptr, nullptr);
  k_gemm_ff1<<<dim3(kFF / 256, kNW / 64), 256, 0, stream>>>(x1, W1B, lin1_b, ff1b);
  k_gemm_ln<true><<<kNW / 16, 256, 0, stream>>>(
      ff1b, kFF, W2B, lin2_b, x1, ln2_g, ln2_b, basep, WP1B, proj_b);
  k_fuse<<<kL / 64, 256, 0, stream>>>(feats, gidx, wlist, cnt, win2flat, x_idx,
                                      basep, WP2B, out);
}

// Round 8
// 385.099 us; speedup vs baseline: 3.7340x; 1.0018x over previous
//
#include <hip/hip_runtime.h>
#include <math.h>

namespace {
constexpr int kL    = 262144;
constexpr int kC    = 256;
constexpr int kNH   = 8;
constexpr int kG    = 64;
constexpr int kFF   = 2048;
constexpr int kLPAD = 262144;
constexpr int kBS   = 4;
constexpr int kNW   = kLPAD / kG;   // 4096
constexpr int kS    = kNW / kBS;    // 1024
constexpr int kHD   = kC / kNH;     // 32

constexpr size_t MB        = 1024 * 1024;
constexpr size_t OFF_GIDX   = 0;         // int[LPAD]      1MB
constexpr size_t OFF_WINNER = 1 * MB;    // int[L]         1MB
constexpr size_t OFF_WLIST  = 2 * MB;    // int[L]         1MB
constexpr size_t OFF_CNT    = 3 * MB;    // int[1]
constexpr size_t OFF_X0     = 4 * MB;    // f32[4096*256]  4MB
constexpr size_t OFF_BASE   = 8 * MB;    // f32[4096*256]  4MB
constexpr size_t OFF_ATTN   = 12 * MB;   // bf16[4096*256] 2MB
constexpr size_t OFF_QH     = 16 * MB;   // bf16 2MB
constexpr size_t OFF_KH     = 18 * MB;   // 2MB
constexpr size_t OFF_VH     = 20 * MB;   // 2MB
constexpr size_t OFF_X1     = 24 * MB;   // f32[4096*256]  4MB
constexpr size_t OFF_FF1    = 32 * MB;   // bf16[4096*2048] 16MB
constexpr size_t OFF_WINB   = 64 * MB;                 // bf16[768*256]  384KB
constexpr size_t OFF_WOUTB  = OFF_WINB  + 512 * 1024;  // bf16[256*256]  128KB
constexpr size_t OFF_W1B    = OFF_WOUTB + 256 * 1024;  // bf16[2048*256] 1MB
constexpr size_t OFF_W2B    = OFF_W1B   + 1536 * 1024; // bf16[256*2048] 1MB
constexpr size_t OFF_WP1B   = OFF_W2B   + 1536 * 1024; // bf16[256*256]  128KB
constexpr size_t OFF_WP2B   = OFF_WP1B  + 256 * 1024;  // bf16[256*256]  128KB

typedef __attribute__((ext_vector_type(8))) short bf16x8;
typedef __attribute__((ext_vector_type(4))) float f32x4;

__device__ inline unsigned short f2bf(float f) {
  union { float f; unsigned int u; } x; x.f = f;
  unsigned int r = x.u + 0x7fff + ((x.u >> 16) & 1);   // RNE
  return (unsigned short)(r >> 16);
}
} // namespace

// ---------------------------------------------------------------- winner init (replaces 155us hipMemsetAsync fill!)
__global__ __launch_bounds__(256) void k_initw(int* __restrict__ winner,
                                               int* __restrict__ cnt) {
  int i = blockIdx.x * 256 + threadIdx.x;
  winner[i] = -1;
  if (i == 0) cnt[0] = 0;
}

// ---------------------------------------------------------------- winner
__global__ __launch_bounds__(256) void k_winner(const int* __restrict__ x_idx,
                                                int* __restrict__ winner) {
  int i = blockIdx.x * 256 + threadIdx.x;
  atomicMax(&winner[x_idx[i]], i);
}

// ---------------------------------------------------------------- merged: compact (blk<1024) + weight casts
__global__ __launch_bounds__(256) void k_fc(const int* __restrict__ x_idx,
                                            const int* __restrict__ winner,
                                            int* __restrict__ wlist,
                                            int* __restrict__ cnt,
                                            const float* __restrict__ in_proj_w,
                                            const float* __restrict__ out_proj_w,
                                            const float* __restrict__ lin1_w,
                                            const float* __restrict__ lin2_w,
                                            const float* __restrict__ proj_w,
                                            unsigned short* __restrict__ WINB,
                                            unsigned short* __restrict__ WOUTB,
                                            unsigned short* __restrict__ W1B,
                                            unsigned short* __restrict__ W2B,
                                            unsigned short* __restrict__ WP1,
                                            unsigned short* __restrict__ WP2) {
  int blk = blockIdx.x, t = threadIdx.x;
  if (blk < 1024) {                      // compact
    int i = blk * 256 + t;
    if (winner[x_idx[i]] == i) {
      int p = atomicAdd(cnt, 1);
      wlist[p] = i;
    }
    return;
  }
  int b2 = blk - 1024;                   // weight casts
  const float* src = nullptr; unsigned short* dst = nullptr; int i = 0;
  if (b2 < 192)       { src = in_proj_w;  dst = WINB;  i = b2 * 256 + t; }
  else if (b2 < 256)  { src = out_proj_w; dst = WOUTB; i = (b2 - 192) * 256 + t; }
  else if (b2 < 768)  { src = lin1_w;     dst = W1B;   i = (b2 - 256) * 256 + t; }
  else if (b2 < 1280) { src = lin2_w;     dst = W2B;   i = (b2 - 768) * 256 + t; }
  else {
    int c = b2 - 1280;
    WP1[c * kC + t] = f2bf(proj_w[(size_t)c * (2 * kC) + t]);
    WP2[c * kC + t] = f2bf(proj_w[(size_t)c * (2 * kC) + kC + t]);
    return;
  }
  float4 v = ((const float4*)src)[i];
  ushort4 b;
  b.x = f2bf(v.x); b.y = f2bf(v.y); b.z = f2bf(v.z); b.w = f2bf(v.w);
  ((ushort4*)dst)[i] = b;
}

// ---------------------------------------------------------------- merged: pool (blk<4096) + selective copy
__global__ __launch_bounds__(256) void k_pc(const float* __restrict__ feats,
                                            const int* __restrict__ x_idx,
                                            const int* __restrict__ flat2win,
                                            const int* __restrict__ winner,
                                            int* __restrict__ gidx,
                                            float* __restrict__ x0,
                                            float* __restrict__ out) {
  int blk = blockIdx.x, t = threadIdx.x;
  if (blk < kNW) {                       // pool
    __shared__ int rows[kG];
    if (t < kG) {
      int g = x_idx[flat2win[blk * kG + t]];
      rows[t] = g;
      gidx[blk * kG + t] = g;
    }
    __syncthreads();
    float m = -INFINITY;
    #pragma unroll 4
    for (int g = 0; g < kG; ++g)
      m = fmaxf(m, feats[(size_t)rows[g] * kC + t]);
    x0[blk * kC + t] = m;
    return;
  }
  // copy rows not overwritten by the fuse scatter
  size_t idx = (size_t)(blk - kNW) * 256 + t;
  int row = (int)(idx >> 6);
  int c4 = (int)(idx & 63);
  if (winner[row] < 0) {
    *(float4*)&out[(size_t)row * kC + c4 * 4] =
        *(const float4*)&feats[(size_t)row * kC + c4 * 4];
  }
}

// ---------------------------------------------------------------- qkv GEMM with per-head bf16 scatter epilogue
__global__ __launch_bounds__(256) void k_gemm_qkv(const float* __restrict__ A,
                                                  const unsigned short* __restrict__ Wb,
                                                  const float* __restrict__ bias,
                                                  unsigned short* __restrict__ Qh,
                                                  unsigned short* __restrict__ Kh,
                                                  unsigned short* __restrict__ Vh) {
  const float scale = 0.17677669529663687f;   // 1/sqrt(32)
  const int m0 = blockIdx.y * 64;
  const int sec = blockIdx.x;
  const int t = threadIdx.x;
  const int lane = t & 63, w = t >> 6;
  const int c0 = w * 64;
  const int kb = lane >> 4, lr = lane & 15;

  __shared__ __align__(16) unsigned short As[64 * 256];

  f32x4 acc[4][4] = {};
  #pragma unroll
  for (int i = 0; i < 16; ++i) {
    int row = i * 4 + w;
    float4 f4 = *(const float4*)&A[(size_t)(m0 + row) * kC + lane * 4];
    ushort4 b4;
    b4.x = f2bf(f4.x); b4.y = f2bf(f4.y); b4.z = f2bf(f4.z); b4.w = f2bf(f4.w);
    unsigned int off = (((unsigned)row * 512u) + (unsigned)lane * 8u) ^ (((unsigned)row & 7u) << 4);
    *(ushort4*)((char*)As + off) = b4;
  }
  __syncthreads();

  #pragma unroll
  for (int ks = 0; ks < 8; ++ks) {
    const int k0 = ks * 32;
    bf16x8 a[4], b[4];
    #pragma unroll
    for (int rt = 0; rt < 4; ++rt) {
      int row = rt * 16 + lr;
      unsigned int off = (((unsigned)row * 512u) + (unsigned)(k0 + kb * 8) * 2u) ^
                         (((unsigned)row & 7u) << 4);
      a[rt] = *(const bf16x8*)((const char*)As + off);
    }
    #pragma unroll
    for (int ct = 0; ct < 4; ++ct) {
      int c = sec * kC + c0 + ct * 16 + lr;
      b[ct] = *(const bf16x8*)&Wb[(size_t)c * kC + k0 + kb * 8];
    }
    #pragma unroll
    for (int rt = 0; rt < 4; ++rt)
      #pragma unroll
      for (int ct = 0; ct < 4; ++ct)
        acc[rt][ct] = __builtin_amdgcn_mfma_f32_16x16x32_bf16(a[rt], b[ct], acc[rt][ct], 0, 0, 0);
  }

  unsigned short* dstbuf = (sec == 0) ? Qh : (sec == 1) ? Kh : Vh;
  #pragma unroll
  for (int rt = 0; rt < 4; ++rt) {
    #pragma unroll
    for (int r = 0; r < 4; ++r) {
      int row = m0 + rt * 16 + kb * 4 + r;
      int bb = row >> 10, s = row & 1023;
      #pragma unroll
      for (int ct = 0; ct < 4; ++ct) {
        int c = c0 + ct * 16 + lr;
        float v = acc[rt][ct][r] + bias[sec * kC + c];
        if (sec == 0) v *= scale;
        int h = c >> 5, d = c & 31;
        dstbuf[(((size_t)(bb * kNH + h) * kS) + s) * kHD + d] = f2bf(v);
      }
    }
  }
}

// ---------------------------------------------------------------- flash attention, bf16 MFMA, KVBLK=128
__global__ __launch_bounds__(256) void k_attn(const unsigned short* __restrict__ Qh,
                                              const unsigned short* __restrict__ Kh,
                                              const unsigned short* __restrict__ Vh,
                                              unsigned short* __restrict__ attn_out) {
  const int q0 = blockIdx.x * 64;
  const int bh = blockIdx.y;           // b*8+h
  const int b = bh >> 3, h = bh & 7;
  const int t = threadIdx.x;
  const int lane = t & 63, w = t >> 6;
  const int kb = lane >> 4, lr = lane & 15;

  __shared__ __align__(16) unsigned short Ks[128][40];     // 10KB
  __shared__ __align__(16) unsigned short VTs[32][136];    // 8.5KB
  __shared__ __align__(16) unsigned short Ps[4][16][136];  // 17KB

  bf16x8 aq = *(const bf16x8*)(Qh + (((size_t)bh * kS) + q0 + w * 16 + lr) * kHD + kb * 8);

  const unsigned short* kbase = Kh + (size_t)bh * kS * kHD;
  const unsigned short* vbase = Vh + (size_t)bh * kS * kHD;

  float m[4], l[4];
  f32x4 O[2] = {};
  #pragma unroll
  for (int r = 0; r < 4; ++r) { m[r] = -INFINITY; l[r] = 0.f; }

  for (int kt = 0; kt < kS / 128; ++kt) {
    {
      int key = t >> 1, d0 = (t & 1) * 16;
      size_t srow = ((size_t)(kt * 128 + key)) * kHD + d0;
      bf16x8 kv0 = *(const bf16x8*)(kbase + srow);
      bf16x8 kv1 = *(const bf16x8*)(kbase + srow + 8);
      *(bf16x8*)&Ks[key][d0] = kv0;
      *(bf16x8*)&Ks[key][d0 + 8] = kv1;
      bf16x8 vv0 = *(const bf16x8*)(vbase + srow);
      bf16x8 vv1 = *(const bf16x8*)(vbase + srow + 8);
      #pragma unroll
      for (int i = 0; i < 8; ++i) {
        VTs[d0 + i][key] = (unsigned short)vv0[i];
        VTs[d0 + 8 + i][key] = (unsigned short)vv1[i];
      }
    }
    __syncthreads();

    f32x4 S[8] = {};
    #pragma unroll
    for (int ct = 0; ct < 8; ++ct) {
      bf16x8 bk = *(const bf16x8*)&Ks[ct * 16 + lr][kb * 8];
      S[ct] = __builtin_amdgcn_mfma_f32_16x16x32_bf16(aq, bk, S[ct], 0, 0, 0);
    }

    float alpha[4];
    #pragma unroll
    for (int r = 0; r < 4; ++r) {
      float tmax = -INFINITY;
      #pragma unroll
      for (int ct = 0; ct < 8; ++ct) tmax = fmaxf(tmax, S[ct][r]);
      #pragma unroll
      for (int off = 8; off; off >>= 1) tmax = fmaxf(tmax, __shfl_xor(tmax, off, 16));
      float newm = fmaxf(m[r], tmax);
      alpha[r] = __expf(m[r] - newm);
      float ps = 0.f;
      #pragma unroll
      for (int ct = 0; ct < 8; ++ct) {
        float p = __expf(S[ct][r] - newm);
        ps += p;
        Ps[w][kb * 4 + r][ct * 16 + lr] = f2bf(p);
      }
      #pragma unroll
      for (int off = 8; off; off >>= 1) ps += __shfl_xor(ps, off, 16);
      l[r] = l[r] * alpha[r] + ps;
      m[r] = newm;
    }
    #pragma unroll
    for (int r = 0; r < 4; ++r) { O[0][r] *= alpha[r]; O[1][r] *= alpha[r]; }

    #pragma unroll
    for (int ks = 0; ks < 4; ++ks) {
      bf16x8 ap = *(const bf16x8*)&Ps[w][lr][ks * 32 + kb * 8];
      #pragma unroll
      for (int ct = 0; ct < 2; ++ct) {
        bf16x8 bv = *(const bf16x8*)&VTs[ct * 16 + lr][ks * 32 + kb * 8];
        O[ct] = __builtin_amdgcn_mfma_f32_16x16x32_bf16(ap, bv, O[ct], 0, 0, 0);
      }
    }
    __syncthreads();
  }

  #pragma unroll
  for (int ct = 0; ct < 2; ++ct) {
    #pragma unroll
    for (int r = 0; r < 4; ++r) {
      size_t row = (size_t)b * kS + q0 + w * 16 + kb * 4 + r;
      attn_out[row * kC + h * kHD + ct * 16 + lr] = f2bf(O[ct][r] / l[r]);
    }
  }
}

// ---------------------------------------------------------------- 16-row GEMM + residual + LN (+ optional chained base GEMM)
template <bool DO_BASE>
__global__ __launch_bounds__(256) void k_gemm_ln(const unsigned short* __restrict__ A,
                                                 int K,
                                                 const unsigned short* __restrict__ Wb,
                                                 const float* __restrict__ bias,
                                                 const float* __restrict__ R,
                                                 const float* __restrict__ g,
                                                 const float* __restrict__ bb,
                                                 float* __restrict__ Out,
                                                 const unsigned short* __restrict__ WbB,
                                                 const float* __restrict__ biasB) {
  const int m0 = blockIdx.x * 16;
  const int t = threadIdx.x;
  const int lane = t & 63, w = t >> 6;
  const int c0 = w * 64;
  const int kb = lane >> 4, lr = lane & 15;

  __shared__ __align__(16) unsigned short As[16 * 256];
  __shared__ __align__(16) unsigned short Xs[16 * 256];
  __shared__ float red[2][16][4];

  f32x4 acc[4] = {};
  for (int kc = 0; kc < K; kc += 256) {
    #pragma unroll
    for (int i = 0; i < 2; ++i) {
      int idx = i * 256 + t;
      int row = idx >> 5, seg = idx & 31;
      bf16x8 v = *(const bf16x8*)&A[(size_t)(m0 + row) * K + kc + seg * 8];
      unsigned int off = (((unsigned)row * 512u) + (unsigned)seg * 16u) ^ (((unsigned)row & 7u) << 4);
      *(bf16x8*)((char*)As + off) = v;
    }
    __syncthreads();

    #pragma unroll
    for (int ks = 0; ks < 8; ++ks) {
      const int k0 = ks * 32;
      unsigned int aoff = (((unsigned)lr * 512u) + (unsigned)(k0 + kb * 8) * 2u) ^
                          (((unsigned)lr & 7u) << 4);
      bf16x8 a = *(const bf16x8*)((const char*)As + aoff);
      #pragma unroll
      for (int ct = 0; ct < 4; ++ct) {
        bf16x8 b = *(const bf16x8*)&Wb[(size_t)(c0 + ct * 16 + lr) * K + kc + k0 + kb * 8];
        acc[ct] = __builtin_amdgcn_mfma_f32_16x16x32_bf16(a, b, acc[ct], 0, 0, 0);
      }
    }
    __syncthreads();
  }

  float v[4][4];
  float s[4], sq[4];
  #pragma unroll
  for (int r = 0; r < 4; ++r) { s[r] = 0.f; sq[r] = 0.f; }
  #pragma unroll
  for (int r = 0; r < 4; ++r) {
    int row = m0 + kb * 4 + r;
    #pragma unroll
    for (int ct = 0; ct < 4; ++ct) {
      int c = c0 + ct * 16 + lr;
      float x = acc[ct][r] + bias[c] + R[(size_t)row * kC + c];
      v[r][ct] = x;
      s[r] += x;
      sq[r] += x * x;
    }
  }
  #pragma unroll
  for (int r = 0; r < 4; ++r) {
    #pragma unroll
    for (int off = 8; off; off >>= 1) {
      s[r]  += __shfl_xor(s[r], off, 16);
      sq[r] += __shfl_xor(sq[r], off, 16);
    }
    if (lr == 0) { red[0][kb * 4 + r][w] = s[r]; red[1][kb * 4 + r][w] = sq[r]; }
  }
  __syncthreads();

  #pragma unroll
  for (int r = 0; r < 4; ++r) {
    int lrow = kb * 4 + r;
    float su = red[0][lrow][0] + red[0][lrow][1] + red[0][lrow][2] + red[0][lrow][3];
    float sg = red[1][lrow][0] + red[1][lrow][1] + red[1][lrow][2] + red[1][lrow][3];
    float mu = su * (1.0f / kC);
    float var = sg * (1.0f / kC) - mu * mu;
    float rs = rsqrtf(var + 1e-5f);
    #pragma unroll
    for (int ct = 0; ct < 4; ++ct) {
      int c = c0 + ct * 16 + lr;
      float yv = (v[r][ct] - mu) * rs * g[c] + bb[c];
      if (!DO_BASE) {
        Out[(size_t)(m0 + lrow) * kC + c] = yv;
      } else {
        unsigned int off = (((unsigned)lrow * 512u) + (unsigned)c * 2u) ^ (((unsigned)lrow & 7u) << 4);
        *(unsigned short*)((char*)Xs + off) = f2bf(yv);
      }
    }
  }

  if (DO_BASE) {
    __syncthreads();
    f32x4 acc2[4] = {};
    #pragma unroll
    for (int ks = 0; ks < 8; ++ks) {
      const int k0 = ks * 32;
      unsigned int aoff = (((unsigned)lr * 512u) + (unsigned)(k0 + kb * 8) * 2u) ^
                          (((unsigned)lr & 7u) << 4);
      bf16x8 a = *(const bf16x8*)((const char*)Xs + aoff);
      #pragma unroll
      for (int ct = 0; ct < 4; ++ct) {
        bf16x8 b = *(const bf16x8*)&WbB[(size_t)(c0 + ct * 16 + lr) * kC + k0 + kb * 8];
        acc2[ct] = __builtin_amdgcn_mfma_f32_16x16x32_bf16(a, b, acc2[ct], 0, 0, 0);
      }
    }
    #pragma unroll
    for (int r = 0; r < 4; ++r) {
      int row = m0 + kb * 4 + r;
      #pragma unroll
      for (int ct = 0; ct < 4; ++ct) {
        int c = c0 + ct * 16 + lr;
        Out[(size_t)row * kC + c] = acc2[ct][r] + biasB[c];
      }
    }
  }
}

// ---------------------------------------------------------------- bf16 MFMA GEMM, f32 A, bf16 out + RELU (lin1)
__global__ __launch_bounds__(256) void k_gemm_ff1(const float* __restrict__ A,
                                                  const unsigned short* __restrict__ Wb,
                                                  const float* __restrict__ bias,
                                                  unsigned short* __restrict__ Cc) {
  const int m0 = blockIdx.y * 64;
  const int nb = blockIdx.x * 256;
  const int t = threadIdx.x;
  const int lane = t & 63, w = t >> 6;
  const int c0 = nb + w * 64;
  const int kb = lane >> 4, lr = lane & 15;

  __shared__ __align__(16) unsigned short As[64 * 256];

  f32x4 acc[4][4] = {};
  #pragma unroll
  for (int i = 0; i < 16; ++i) {
    int row = i * 4 + w;
    float4 f4 = *(const float4*)&A[(size_t)(m0 + row) * kC + lane * 4];
    ushort4 b4;
    b4.x = f2bf(f4.x); b4.y = f2bf(f4.y); b4.z = f2bf(f4.z); b4.w = f2bf(f4.w);
    unsigned int off = (((unsigned)row * 512u) + (unsigned)lane * 8u) ^ (((unsigned)row & 7u) << 4);
    *(ushort4*)((char*)As + off) = b4;
  }
  __syncthreads();

  #pragma unroll
  for (int ks = 0; ks < 8; ++ks) {
    const int k0 = ks * 32;
    bf16x8 a[4], b[4];
    #pragma unroll
    for (int rt = 0; rt < 4; ++rt) {
      int row = rt * 16 + lr;
      unsigned int off = (((unsigned)row * 512u) + (unsigned)(k0 + kb * 8) * 2u) ^
                         (((unsigned)row & 7u) << 4);
      a[rt] = *(const bf16x8*)((const char*)As + off);
    }
    #pragma unroll
    for (int ct = 0; ct < 4; ++ct) {
      int c = c0 + ct * 16 + lr;
      b[ct] = *(const bf16x8*)&Wb[(size_t)c * kC + k0 + kb * 8];
    }
    #pragma unroll
    for (int rt = 0; rt < 4; ++rt)
      #pragma unroll
      for (int ct = 0; ct < 4; ++ct)
        acc[rt][ct] = __builtin_amdgcn_mfma_f32_16x16x32_bf16(a[rt], b[ct], acc[rt][ct], 0, 0, 0);
  }

  #pragma unroll
  for (int rt = 0; rt < 4; ++rt) {
    #pragma unroll
    for (int r = 0; r < 4; ++r) {
      int row = m0 + rt * 16 + kb * 4 + r;
      #pragma unroll
      for (int ct = 0; ct < 4; ++ct) {
        int c = c0 + ct * 16 + lr;
        float vv = fmaxf(acc[rt][ct][r] + bias[c], 0.f);
        Cc[(size_t)row * kFF + c] = f2bf(vv);
      }
    }
  }
}

// ---------------------------------------------------------------- fuse: bf16 MFMA GEMM (gathered A) + scatter
__global__ __launch_bounds__(256) void k_fuse(const float* __restrict__ feats,
                                              const int* __restrict__ gidx,
                                              const int* __restrict__ wlist,
                                              const int* __restrict__ cnt,
                                              const int* __restrict__ win2flat,
                                              const int* __restrict__ x_idx,
                                              const float* __restrict__ base,
                                              const unsigned short* __restrict__ W2B,
                                              float* __restrict__ out) {
  const int count = cnt[0];
  const int r0 = blockIdx.x * 64;
  if (r0 >= count) return;
  const int nr = min(64, count - r0);
  const int t = threadIdx.x;
  const int lane = t & 63, w = t >> 6;

  __shared__ __align__(16) unsigned short As[64 * 256];
  __shared__ int dstrow[64], wwin[64], srcrow[64];

  if (t < 64) {
    int rr = min(r0 + t, count - 1);
    int i = wlist[rr];
    int j = win2flat[i];
    srcrow[t] = gidx[j];
    wwin[t] = j >> 6;
    dstrow[t] = x_idx[i];
  }
  __syncthreads();

  for (int i = 0; i < 16; ++i) {
    int row = i * 4 + w;
    float4 f4 = *(const float4*)&feats[(size_t)srcrow[row] * kC + lane * 4];
    ushort4 b4;
    b4.x = f2bf(f4.x); b4.y = f2bf(f4.y); b4.z = f2bf(f4.z); b4.w = f2bf(f4.w);
    unsigned int off = (((unsigned)row * 512u) + (unsigned)lane * 8u) ^ (((unsigned)row & 7u) << 4);
    *(ushort4*)((char*)As + off) = b4;
  }
  __syncthreads();

  const int c0 = w * 64;
  const int kb = lane >> 4;
  const int lr = lane & 15;
  f32x4 acc[4][4] = {};
  for (int ks = 0; ks < 8; ++ks) {
    const int k0 = ks * 32;
    bf16x8 a[4], b[4];
    #pragma unroll
    for (int rt = 0; rt < 4; ++rt) {
      int row = rt * 16 + lr;
      unsigned int off = (((unsigned)row * 512u) + (unsigned)(k0 + kb * 8) * 2u) ^
                         (((unsigned)row & 7u) << 4);
      a[rt] = *(const bf16x8*)((const char*)As + off);
    }
    #pragma unroll
    for (int ct = 0; ct < 4; ++ct) {
      int c = c0 + ct * 16 + lr;
      b[ct] = *(const bf16x8*)&W2B[(size_t)c * kC + k0 + kb * 8];
    }
    #pragma unroll
    for (int rt = 0; rt < 4; ++rt)
      #pragma unroll
      for (int ct = 0; ct < 4; ++ct)
        acc[rt][ct] = __builtin_amdgcn_mfma_f32_16x16x32_bf16(a[rt], b[ct], acc[rt][ct], 0, 0, 0);
  }

  #pragma unroll
  for (int rt = 0; rt < 4; ++rt) {
    #pragma unroll
    for (int r = 0; r < 4; ++r) {
      int row = rt * 16 + kb * 4 + r;
      if (row < nr) {
        size_t orow = (size_t)dstrow[row] * kC;
        size_t brow = (size_t)wwin[row] * kC;
        #pragma unroll
        for (int ct = 0; ct < 4; ++ct) {
          int c = c0 + ct * 16 + lr;
          out[orow + c] = acc[rt][ct][r] + base[brow + c];
        }
      }
    }
  }
}

// ---------------------------------------------------------------- launch
extern "C" void kernel_launch(void* const* d_in, const int* in_sizes, int n_in,
                              void* d_out, int out_size, void* d_ws, size_t ws_size,
                              hipStream_t stream) {
  const float* feats      = (const float*)d_in[0];
  const int*   x_idx      = (const int*)d_in[1];
  const int*   flat2win   = (const int*)d_in[2];
  const int*   win2flat   = (const int*)d_in[3];
  const float* in_proj_w  = (const float*)d_in[4];
  const float* in_proj_b  = (const float*)d_in[5];
  const float* out_proj_w = (const float*)d_in[6];
  const float* out_proj_b = (const float*)d_in[7];
  const float* lin1_w     = (const float*)d_in[8];
  const float* lin1_b     = (const float*)d_in[9];
  const float* lin2_w     = (const float*)d_in[10];
  const float* lin2_b     = (const float*)d_in[11];
  const float* ln1_g      = (const float*)d_in[12];
  const float* ln1_b      = (const float*)d_in[13];
  const float* ln2_g      = (const float*)d_in[14];
  const float* ln2_b      = (const float*)d_in[15];
  const float* proj_w     = (const float*)d_in[16];
  const float* proj_b     = (const float*)d_in[17];

  char* ws = (char*)d_ws;
  int*   gidx   = (int*)(ws + OFF_GIDX);
  int*   winner = (int*)(ws + OFF_WINNER);
  int*   wlist  = (int*)(ws + OFF_WLIST);
  int*   cnt    = (int*)(ws + OFF_CNT);
  float* x0     = (float*)(ws + OFF_X0);
  float* basep  = (float*)(ws + OFF_BASE);
  float* x1     = (float*)(ws + OFF_X1);
  unsigned short* attnb = (unsigned short*)(ws + OFF_ATTN);
  unsigned short* Qh    = (unsigned short*)(ws + OFF_QH);
  unsigned short* Kh    = (unsigned short*)(ws + OFF_KH);
  unsigned short* Vh    = (unsigned short*)(ws + OFF_VH);
  unsigned short* ff1b  = (unsigned short*)(ws + OFF_FF1);
  unsigned short* WINB  = (unsigned short*)(ws + OFF_WINB);
  unsigned short* WOUTB = (unsigned short*)(ws + OFF_WOUTB);
  unsigned short* W1B   = (unsigned short*)(ws + OFF_W1B);
  unsigned short* W2B   = (unsigned short*)(ws + OFF_W2B);
  unsigned short* WP1B  = (unsigned short*)(ws + OFF_WP1B);
  unsigned short* WP2B  = (unsigned short*)(ws + OFF_WP2B);
  float* out    = (float*)d_out;

  k_initw<<<kL / 256, 256, 0, stream>>>(winner, cnt);
  k_winner<<<kL / 256, 256, 0, stream>>>(x_idx, winner);
  k_fc<<<1024 + 1536, 256, 0, stream>>>(x_idx, winner, wlist, cnt,
                                        in_proj_w, out_proj_w, lin1_w, lin2_w, proj_w,
                                        WINB, WOUTB, W1B, W2B, WP1B, WP2B);
  k_pc<<<kNW + kL / 4, 256, 0, stream>>>(feats, x_idx, flat2win, winner, gidx, x0, out);

  k_gemm_qkv<<<dim3(3, kNW / 64), 256, 0, stream>>>(x0, WINB, in_proj_b, Qh, Kh, Vh);
  k_attn<<<dim3(kS / 64, kBS * kNH), 256, 0, stream>>>(Qh, Kh, Vh, attnb);
  k_gemm_ln<false><<<kNW / 16, 256, 0, stream>>>(
      attnb, kC, WOUTB, out_proj_b, x0, ln1_g, ln1_b, x1, nullptr, nullptr);
  k_gemm_ff1<<<dim3(kFF / 256, kNW / 64), 256, 0, stream>>>(x1, W1B, lin1_b, ff1b);
  k_gemm_ln<true><<<kNW / 16, 256, 0, stream>>>(
      ff1b, kFF, W2B, lin2_b, x1, ln2_g, ln2_b, basep, WP1B, proj_b);
  k_fuse<<<kL / 64, 256, 0, stream>>>(feats, gidx, wlist, cnt, win2flat, x_idx,
                                      basep, WP2B, out);
}

// Round 10
// 378.417 us; speedup vs baseline: 3.8000x; 1.0177x over previous
//
#include <hip/hip_runtime.h>
#include <math.h>

namespace {
constexpr int kL    = 262144;
constexpr int kC    = 256;
constexpr int kNH   = 8;
constexpr int kG    = 64;
constexpr int kFF   = 2048;
constexpr int kLPAD = 262144;
constexpr int kBS   = 4;
constexpr int kNW   = kLPAD / kG;   // 4096
constexpr int kS    = kNW / kBS;    // 1024
constexpr int kHD   = kC / kNH;     // 32

constexpr size_t MB        = 1024 * 1024;
constexpr size_t OFF_GIDX   = 0;         // int[LPAD]      1MB
constexpr size_t OFF_WINNER = 1 * MB;    // int[L]         1MB
constexpr size_t OFF_WLIST  = 2 * MB;    // int[L]         1MB
constexpr size_t OFF_CNT    = 3 * MB;    // int[1]
constexpr size_t OFF_X0     = 4 * MB;    // f32[4096*256]  4MB
constexpr size_t OFF_BASE   = 8 * MB;    // f32[4096*256]  4MB
constexpr size_t OFF_ATTN   = 12 * MB;   // bf16[4096*256] 2MB
constexpr size_t OFF_QH     = 16 * MB;   // bf16 2MB
constexpr size_t OFF_KH     = 18 * MB;   // 2MB
constexpr size_t OFF_VH     = 20 * MB;   // 2MB
constexpr size_t OFF_X1     = 24 * MB;   // f32[4096*256]  4MB
constexpr size_t OFF_FF1    = 32 * MB;   // bf16[4096*2048] 16MB
constexpr size_t OFF_WINB   = 64 * MB;                 // bf16[768*256]  384KB
constexpr size_t OFF_WOUTB  = OFF_WINB  + 512 * 1024;  // bf16[256*256]  128KB
constexpr size_t OFF_W1B    = OFF_WOUTB + 256 * 1024;  // bf16[2048*256] 1MB
constexpr size_t OFF_W2B    = OFF_W1B   + 1536 * 1024; // bf16[256*2048] 1MB
constexpr size_t OFF_WP1B   = OFF_W2B   + 1536 * 1024; // bf16[256*256]  128KB
constexpr size_t OFF_WP2B   = OFF_WP1B  + 256 * 1024;  // bf16[256*256]  128KB

typedef __attribute__((ext_vector_type(8))) short bf16x8;
typedef __attribute__((ext_vector_type(4))) float f32x4;

__device__ inline unsigned short f2bf(float f) {
  union { float f; unsigned int u; } x; x.f = f;
  unsigned int r = x.u + 0x7fff + ((x.u >> 16) & 1);   // RNE
  return (unsigned short)(r >> 16);
}
} // namespace

// ---------------------------------------------------------------- winner init (int4 per thread)
__global__ __launch_bounds__(256) void k_initw(int* __restrict__ winner,
                                               int* __restrict__ cnt) {
  int i = blockIdx.x * 256 + threadIdx.x;
  ((int4*)winner)[i] = make_int4(-1, -1, -1, -1);
  if (i == 0) cnt[0] = 0;
}

// ---------------------------------------------------------------- winner (4 per thread)
__global__ __launch_bounds__(256) void k_winner(const int* __restrict__ x_idx,
                                                int* __restrict__ winner) {
  int i0 = (blockIdx.x * 256 + threadIdx.x) * 4;
  int4 xi = *(const int4*)&x_idx[i0];
  atomicMax(&winner[xi.x], i0);
  atomicMax(&winner[xi.y], i0 + 1);
  atomicMax(&winner[xi.z], i0 + 2);
  atomicMax(&winner[xi.w], i0 + 3);
}

// ---------------------------------------------------------------- merged: compact (blk<256, 4/thread) + weight casts
__global__ __launch_bounds__(256) void k_fc(const int* __restrict__ x_idx,
                                            const int* __restrict__ winner,
                                            int* __restrict__ wlist,
                                            int* __restrict__ cnt,
                                            const float* __restrict__ in_proj_w,
                                            const float* __restrict__ out_proj_w,
                                            const float* __restrict__ lin1_w,
                                            const float* __restrict__ lin2_w,
                                            const float* __restrict__ proj_w,
                                            unsigned short* __restrict__ WINB,
                                            unsigned short* __restrict__ WOUTB,
                                            unsigned short* __restrict__ W1B,
                                            unsigned short* __restrict__ W2B,
                                            unsigned short* __restrict__ WP1,
                                            unsigned short* __restrict__ WP2) {
  int blk = blockIdx.x, t = threadIdx.x;
  if (blk < 256) {                      // compact, 4 elements/thread
    int i0 = (blk * 256 + t) * 4;
    int4 xi = *(const int4*)&x_idx[i0];
    #pragma unroll
    for (int j = 0; j < 4; ++j) {
      int i = i0 + j;
      int xv = (j == 0) ? xi.x : (j == 1) ? xi.y : (j == 2) ? xi.z : xi.w;
      if (winner[xv] == i) {
        int p = atomicAdd(cnt, 1);
        wlist[p] = i;
      }
    }
    return;
  }
  int b2 = blk - 256;                   // weight casts
  const float* src = nullptr; unsigned short* dst = nullptr; int i = 0;
  if (b2 < 192)       { src = in_proj_w;  dst = WINB;  i = b2 * 256 + t; }
  else if (b2 < 256)  { src = out_proj_w; dst = WOUTB; i = (b2 - 192) * 256 + t; }
  else if (b2 < 768)  { src = lin1_w;     dst = W1B;   i = (b2 - 256) * 256 + t; }
  else if (b2 < 1280) { src = lin2_w;     dst = W2B;   i = (b2 - 768) * 256 + t; }
  else {
    int c = b2 - 1280;
    WP1[c * kC + t] = f2bf(proj_w[(size_t)c * (2 * kC) + t]);
    WP2[c * kC + t] = f2bf(proj_w[(size_t)c * (2 * kC) + kC + t]);
    return;
  }
  float4 v = ((const float4*)src)[i];
  ushort4 b;
  b.x = f2bf(v.x); b.y = f2bf(v.y); b.z = f2bf(v.z); b.w = f2bf(v.w);
  ((ushort4*)dst)[i] = b;
}

// ---------------------------------------------------------------- merged: pool (blk<4096, wave-per-row) + copy (8 rows/blk)
__global__ __launch_bounds__(256) void k_pc(const float* __restrict__ feats,
                                            const int* __restrict__ x_idx,
                                            const int* __restrict__ flat2win,
                                            const int* __restrict__ winner,
                                            int* __restrict__ gidx,
                                            float* __restrict__ x0,
                                            float* __restrict__ out) {
  int blk = blockIdx.x, t = threadIdx.x;
  int w = t >> 6, lane = t & 63;
  if (blk < kNW) {                       // pool: wave w handles rows w*16..w*16+15
    __shared__ int rows[kG];
    __shared__ __align__(16) float mred[4][kC];
    if (t < kG) {
      int g = x_idx[flat2win[blk * kG + t]];
      rows[t] = g;
      gidx[blk * kG + t] = g;
    }
    __syncthreads();
    float4 mx = make_float4(-INFINITY, -INFINITY, -INFINITY, -INFINITY);
    #pragma unroll
    for (int i = 0; i < 16; ++i) {
      int r = rows[w * 16 + i];
      float4 v = *(const float4*)&feats[(size_t)r * kC + lane * 4];  // full 1KB row per wave instr
      mx.x = fmaxf(mx.x, v.x); mx.y = fmaxf(mx.y, v.y);
      mx.z = fmaxf(mx.z, v.z); mx.w = fmaxf(mx.w, v.w);
    }
    *(float4*)&mred[w][lane * 4] = mx;
    __syncthreads();
    x0[blk * kC + t] = fmaxf(fmaxf(mred[0][t], mred[1][t]),
                             fmaxf(mred[2][t], mred[3][t]));
    return;
  }
  // copy rows not overwritten by fuse scatter: 8 rows per block (2 per wave)
  int cb = blk - kNW;                    // 0..32767  (kL/8 blocks)
  #pragma unroll
  for (int i = 0; i < 2; ++i) {
    int row = cb * 8 + w * 2 + i;
    if (winner[row] < 0) {
      *(float4*)&out[(size_t)row * kC + lane * 4] =
          *(const float4*)&feats[(size_t)row * kC + lane * 4];
    }
  }
}

// ---------------------------------------------------------------- qkv GEMM with per-head bf16 scatter epilogue
__global__ __launch_bounds__(256) void k_gemm_qkv(const float* __restrict__ A,
                                                  const unsigned short* __restrict__ Wb,
                                                  const float* __restrict__ bias,
                                                  unsigned short* __restrict__ Qh,
                                                  unsigned short* __restrict__ Kh,
                                                  unsigned short* __restrict__ Vh) {
  const float scale = 0.17677669529663687f;   // 1/sqrt(32)
  const int m0 = blockIdx.y * 64;
  const int sec = blockIdx.x;
  const int t = threadIdx.x;
  const int lane = t & 63, w = t >> 6;
  const int c0 = w * 64;
  const int kb = lane >> 4, lr = lane & 15;

  __shared__ __align__(16) unsigned short As[64 * 256];

  f32x4 acc[4][4] = {};
  #pragma unroll
  for (int i = 0; i < 16; ++i) {
    int row = i * 4 + w;
    float4 f4 = *(const float4*)&A[(size_t)(m0 + row) * kC + lane * 4];
    ushort4 b4;
    b4.x = f2bf(f4.x); b4.y = f2bf(f4.y); b4.z = f2bf(f4.z); b4.w = f2bf(f4.w);
    unsigned int off = (((unsigned)row * 512u) + (unsigned)lane * 8u) ^ (((unsigned)row & 7u) << 4);
    *(ushort4*)((char*)As + off) = b4;
  }
  __syncthreads();

  #pragma unroll
  for (int ks = 0; ks < 8; ++ks) {
    const int k0 = ks * 32;
    bf16x8 a[4], b[4];
    #pragma unroll
    for (int rt = 0; rt < 4; ++rt) {
      int row = rt * 16 + lr;
      unsigned int off = (((unsigned)row * 512u) + (unsigned)(k0 + kb * 8) * 2u) ^
                         (((unsigned)row & 7u) << 4);
      a[rt] = *(const bf16x8*)((const char*)As + off);
    }
    #pragma unroll
    for (int ct = 0; ct < 4; ++ct) {
      int c = sec * kC + c0 + ct * 16 + lr;
      b[ct] = *(const bf16x8*)&Wb[(size_t)c * kC + k0 + kb * 8];
    }
    #pragma unroll
    for (int rt = 0; rt < 4; ++rt)
      #pragma unroll
      for (int ct = 0; ct < 4; ++ct)
        acc[rt][ct] = __builtin_amdgcn_mfma_f32_16x16x32_bf16(a[rt], b[ct], acc[rt][ct], 0, 0, 0);
  }

  unsigned short* dstbuf = (sec == 0) ? Qh : (sec == 1) ? Kh : Vh;
  #pragma unroll
  for (int rt = 0; rt < 4; ++rt) {
    #pragma unroll
    for (int r = 0; r < 4; ++r) {
      int row = m0 + rt * 16 + kb * 4 + r;
      int bb = row >> 10, s = row & 1023;
      #pragma unroll
      for (int ct = 0; ct < 4; ++ct) {
        int c = c0 + ct * 16 + lr;
        float v = acc[rt][ct][r] + bias[sec * kC + c];
        if (sec == 0) v *= scale;
        int h = c >> 5, d = c & 31;
        dstbuf[(((size_t)(bb * kNH + h) * kS) + s) * kHD + d] = f2bf(v);
      }
    }
  }
}

// ---------------------------------------------------------------- flash attention, bf16 MFMA, KVBLK=128
__global__ __launch_bounds__(256) void k_attn(const unsigned short* __restrict__ Qh,
                                              const unsigned short* __restrict__ Kh,
                                              const unsigned short* __restrict__ Vh,
                                              unsigned short* __restrict__ attn_out) {
  const int q0 = blockIdx.x * 64;
  const int bh = blockIdx.y;           // b*8+h
  const int b = bh >> 3, h = bh & 7;
  const int t = threadIdx.x;
  const int lane = t & 63, w = t >> 6;
  const int kb = lane >> 4, lr = lane & 15;

  __shared__ __align__(16) unsigned short Ks[128][40];     // 10KB
  __shared__ __align__(16) unsigned short VTs[32][136];    // 8.5KB
  __shared__ __align__(16) unsigned short Ps[4][16][136];  // 17KB

  bf16x8 aq = *(const bf16x8*)(Qh + (((size_t)bh * kS) + q0 + w * 16 + lr) * kHD + kb * 8);

  const unsigned short* kbase = Kh + (size_t)bh * kS * kHD;
  const unsigned short* vbase = Vh + (size_t)bh * kS * kHD;

  float m[4], l[4];
  f32x4 O[2] = {};
  #pragma unroll
  for (int r = 0; r < 4; ++r) { m[r] = -INFINITY; l[r] = 0.f; }

  for (int kt = 0; kt < kS / 128; ++kt) {
    {
      int key = t >> 1, d0 = (t & 1) * 16;
      size_t srow = ((size_t)(kt * 128 + key)) * kHD + d0;
      bf16x8 kv0 = *(const bf16x8*)(kbase + srow);
      bf16x8 kv1 = *(const bf16x8*)(kbase + srow + 8);
      *(bf16x8*)&Ks[key][d0] = kv0;
      *(bf16x8*)&Ks[key][d0 + 8] = kv1;
      bf16x8 vv0 = *(const bf16x8*)(vbase + srow);
      bf16x8 vv1 = *(const bf16x8*)(vbase + srow + 8);
      #pragma unroll
      for (int i = 0; i < 8; ++i) {
        VTs[d0 + i][key] = (unsigned short)vv0[i];
        VTs[d0 + 8 + i][key] = (unsigned short)vv1[i];
      }
    }
    __syncthreads();

    f32x4 S[8] = {};
    #pragma unroll
    for (int ct = 0; ct < 8; ++ct) {
      bf16x8 bk = *(const bf16x8*)&Ks[ct * 16 + lr][kb * 8];
      S[ct] = __builtin_amdgcn_mfma_f32_16x16x32_bf16(aq, bk, S[ct], 0, 0, 0);
    }

    float alpha[4];
    #pragma unroll
    for (int r = 0; r < 4; ++r) {
      float tmax = -INFINITY;
      #pragma unroll
      for (int ct = 0; ct < 8; ++ct) tmax = fmaxf(tmax, S[ct][r]);
      #pragma unroll
      for (int off = 8; off; off >>= 1) tmax = fmaxf(tmax, __shfl_xor(tmax, off, 16));
      float newm = fmaxf(m[r], tmax);
      alpha[r] = __expf(m[r] - newm);
      float ps = 0.f;
      #pragma unroll
      for (int ct = 0; ct < 8; ++ct) {
        float p = __expf(S[ct][r] - newm);
        ps += p;
        Ps[w][kb * 4 + r][ct * 16 + lr] = f2bf(p);
      }
      #pragma unroll
      for (int off = 8; off; off >>= 1) ps += __shfl_xor(ps, off, 16);
      l[r] = l[r] * alpha[r] + ps;
      m[r] = newm;
    }
    #pragma unroll
    for (int r = 0; r < 4; ++r) { O[0][r] *= alpha[r]; O[1][r] *= alpha[r]; }

    #pragma unroll
    for (int ks = 0; ks < 4; ++ks) {
      bf16x8 ap = *(const bf16x8*)&Ps[w][lr][ks * 32 + kb * 8];
      #pragma unroll
      for (int ct = 0; ct < 2; ++ct) {
        bf16x8 bv = *(const bf16x8*)&VTs[ct * 16 + lr][ks * 32 + kb * 8];
        O[ct] = __builtin_amdgcn_mfma_f32_16x16x32_bf16(ap, bv, O[ct], 0, 0, 0);
      }
    }
    __syncthreads();
  }

  #pragma unroll
  for (int ct = 0; ct < 2; ++ct) {
    #pragma unroll
    for (int r = 0; r < 4; ++r) {
      size_t row = (size_t)b * kS + q0 + w * 16 + kb * 4 + r;
      attn_out[row * kC + h * kHD + ct * 16 + lr] = f2bf(O[ct][r] / l[r]);
    }
  }
}

// ---------------------------------------------------------------- 16-row GEMM + residual + LN (+ optional chained base GEMM)
template <bool DO_BASE>
__global__ __launch_bounds__(256) void k_gemm_ln(const unsigned short* __restrict__ A,
                                                 int K,
                                                 const unsigned short* __restrict__ Wb,
                                                 const float* __restrict__ bias,
                                                 const float* __restrict__ R,
                                                 const float* __restrict__ g,
                                                 const float* __restrict__ bb,
                                                 float* __restrict__ Out,
                                                 const unsigned short* __restrict__ WbB,
                                                 const float* __restrict__ biasB) {
  const int m0 = blockIdx.x * 16;
  const int t = threadIdx.x;
  const int lane = t & 63, w = t >> 6;
  const int c0 = w * 64;
  const int kb = lane >> 4, lr = lane & 15;

  __shared__ __align__(16) unsigned short As[16 * 256];
  __shared__ __align__(16) unsigned short Xs[16 * 256];
  __shared__ float red[2][16][4];

  f32x4 acc[4] = {};
  for (int kc = 0; kc < K; kc += 256) {
    #pragma unroll
    for (int i = 0; i < 2; ++i) {
      int idx = i * 256 + t;
      int row = idx >> 5, seg = idx & 31;
      bf16x8 v = *(const bf16x8*)&A[(size_t)(m0 + row) * K + kc + seg * 8];
      unsigned int off = (((unsigned)row * 512u) + (unsigned)seg * 16u) ^ (((unsigned)row & 7u) << 4);
      *(bf16x8*)((char*)As + off) = v;
    }
    __syncthreads();

    #pragma unroll
    for (int ks = 0; ks < 8; ++ks) {
      const int k0 = ks * 32;
      unsigned int aoff = (((unsigned)lr * 512u) + (unsigned)(k0 + kb * 8) * 2u) ^
                          (((unsigned)lr & 7u) << 4);
      bf16x8 a = *(const bf16x8*)((const char*)As + aoff);
      #pragma unroll
      for (int ct = 0; ct < 4; ++ct) {
        bf16x8 b = *(const bf16x8*)&Wb[(size_t)(c0 + ct * 16 + lr) * K + kc + k0 + kb * 8];
        acc[ct] = __builtin_amdgcn_mfma_f32_16x16x32_bf16(a, b, acc[ct], 0, 0, 0);
      }
    }
    __syncthreads();
  }

  float v[4][4];
  float s[4], sq[4];
  #pragma unroll
  for (int r = 0; r < 4; ++r) { s[r] = 0.f; sq[r] = 0.f; }
  #pragma unroll
  for (int r = 0; r < 4; ++r) {
    int row = m0 + kb * 4 + r;
    #pragma unroll
    for (int ct = 0; ct < 4; ++ct) {
      int c = c0 + ct * 16 + lr;
      float x = acc[ct][r] + bias[c] + R[(size_t)row * kC + c];
      v[r][ct] = x;
      s[r] += x;
      sq[r] += x * x;
    }
  }
  #pragma unroll
  for (int r = 0; r < 4; ++r) {
    #pragma unroll
    for (int off = 8; off; off >>= 1) {
      s[r]  += __shfl_xor(s[r], off, 16);
      sq[r] += __shfl_xor(sq[r], off, 16);
    }
    if (lr == 0) { red[0][kb * 4 + r][w] = s[r]; red[1][kb * 4 + r][w] = sq[r]; }
  }
  __syncthreads();

  #pragma unroll
  for (int r = 0; r < 4; ++r) {
    int lrow = kb * 4 + r;
    float su = red[0][lrow][0] + red[0][lrow][1] + red[0][lrow][2] + red[0][lrow][3];
    float sg = red[1][lrow][0] + red[1][lrow][1] + red[1][lrow][2] + red[1][lrow][3];
    float mu = su * (1.0f / kC);
    float var = sg * (1.0f / kC) - mu * mu;
    float rs = rsqrtf(var + 1e-5f);
    #pragma unroll
    for (int ct = 0; ct < 4; ++ct) {
      int c = c0 + ct * 16 + lr;
      float yv = (v[r][ct] - mu) * rs * g[c] + bb[c];
      if (!DO_BASE) {
        Out[(size_t)(m0 + lrow) * kC + c] = yv;
      } else {
        unsigned int off = (((unsigned)lrow * 512u) + (unsigned)c * 2u) ^ (((unsigned)lrow & 7u) << 4);
        *(unsigned short*)((char*)Xs + off) = f2bf(yv);
      }
    }
  }

  if (DO_BASE) {
    __syncthreads();
    f32x4 acc2[4] = {};
    #pragma unroll
    for (int ks = 0; ks < 8; ++ks) {
      const int k0 = ks * 32;
      unsigned int aoff = (((unsigned)lr * 512u) + (unsigned)(k0 + kb * 8) * 2u) ^
                          (((unsigned)lr & 7u) << 4);
      bf16x8 a = *(const bf16x8*)((const char*)Xs + aoff);
      #pragma unroll
      for (int ct = 0; ct < 4; ++ct) {
        bf16x8 b = *(const bf16x8*)&WbB[(size_t)(c0 + ct * 16 + lr) * kC + k0 + kb * 8];
        acc2[ct] = __builtin_amdgcn_mfma_f32_16x16x32_bf16(a, b, acc2[ct], 0, 0, 0);
      }
    }
    #pragma unroll
    for (int r = 0; r < 4; ++r) {
      int row = m0 + kb * 4 + r;
      #pragma unroll
      for (int ct = 0; ct < 4; ++ct) {
        int c = c0 + ct * 16 + lr;
        Out[(size_t)row * kC + c] = acc2[ct][r] + biasB[c];
      }
    }
  }
}

// ---------------------------------------------------------------- bf16 MFMA GEMM, f32 A, bf16 out + RELU (lin1)
__global__ __launch_bounds__(256) void k_gemm_ff1(const float* __restrict__ A,
                                                  const unsigned short* __restrict__ Wb,
                                                  const float* __restrict__ bias,
                                                  unsigned short* __restrict__ Cc) {
  const int m0 = blockIdx.y * 64;
  const int nb = blockIdx.x * 256;
  const int t = threadIdx.x;
  const int lane = t & 63, w = t >> 6;
  const int c0 = nb + w * 64;
  const int kb = lane >> 4, lr = lane & 15;

  __shared__ __align__(16) unsigned short As[64 * 256];

  f32x4 acc[4][4] = {};
  #pragma unroll
  for (int i = 0; i < 16; ++i) {
    int row = i * 4 + w;
    float4 f4 = *(const float4*)&A[(size_t)(m0 + row) * kC + lane * 4];
    ushort4 b4;
    b4.x = f2bf(f4.x); b4.y = f2bf(f4.y); b4.z = f2bf(f4.z); b4.w = f2bf(f4.w);
    unsigned int off = (((unsigned)row * 512u) + (unsigned)lane * 8u) ^ (((unsigned)row & 7u) << 4);
    *(ushort4*)((char*)As + off) = b4;
  }
  __syncthreads();

  #pragma unroll
  for (int ks = 0; ks < 8; ++ks) {
    const int k0 = ks * 32;
    bf16x8 a[4], b[4];
    #pragma unroll
    for (int rt = 0; rt < 4; ++rt) {
      int row = rt * 16 + lr;
      unsigned int off = (((unsigned)row * 512u) + (unsigned)(k0 + kb * 8) * 2u) ^
                         (((unsigned)row & 7u) << 4);
      a[rt] = *(const bf16x8*)((const char*)As + off);
    }
    #pragma unroll
    for (int ct = 0; ct < 4; ++ct) {
      int c = c0 + ct * 16 + lr;
      b[ct] = *(const bf16x8*)&Wb[(size_t)c * kC + k0 + kb * 8];
    }
    #pragma unroll
    for (int rt = 0; rt < 4; ++rt)
      #pragma unroll
      for (int ct = 0; ct < 4; ++ct)
        acc[rt][ct] = __builtin_amdgcn_mfma_f32_16x16x32_bf16(a[rt], b[ct], acc[rt][ct], 0, 0, 0);
  }

  #pragma unroll
  for (int rt = 0; rt < 4; ++rt) {
    #pragma unroll
    for (int r = 0; r < 4; ++r) {
      int row = m0 + rt * 16 + kb * 4 + r;
      #pragma unroll
      for (int ct = 0; ct < 4; ++ct) {
        int c = c0 + ct * 16 + lr;
        float vv = fmaxf(acc[rt][ct][r] + bias[c], 0.f);
        Cc[(size_t)row * kFF + c] = f2bf(vv);
      }
    }
  }
}

// ---------------------------------------------------------------- fuse: bf16 MFMA GEMM (gathered A) + scatter
__global__ __launch_bounds__(256) void k_fuse(const float* __restrict__ feats,
                                              const int* __restrict__ gidx,
                                              const int* __restrict__ wlist,
                                              const int* __restrict__ cnt,
                                              const int* __restrict__ win2flat,
                                              const int* __restrict__ x_idx,
                                              const float* __restrict__ base,
                                              const unsigned short* __restrict__ W2B,
                                              float* __restrict__ out) {
  const int count = cnt[0];
  const int r0 = blockIdx.x * 64;
  if (r0 >= count) return;
  const int nr = min(64, count - r0);
  const int t = threadIdx.x;
  const int lane = t & 63, w = t >> 6;

  __shared__ __align__(16) unsigned short As[64 * 256];
  __shared__ int dstrow[64], wwin[64], srcrow[64];

  if (t < 64) {
    int rr = min(r0 + t, count - 1);
    int i = wlist[rr];
    int j = win2flat[i];
    srcrow[t] = gidx[j];
    wwin[t] = j >> 6;
    dstrow[t] = x_idx[i];
  }
  __syncthreads();

  for (int i = 0; i < 16; ++i) {
    int row = i * 4 + w;
    float4 f4 = *(const float4*)&feats[(size_t)srcrow[row] * kC + lane * 4];
    ushort4 b4;
    b4.x = f2bf(f4.x); b4.y = f2bf(f4.y); b4.z = f2bf(f4.z); b4.w = f2bf(f4.w);
    unsigned int off = (((unsigned)row * 512u) + (unsigned)lane * 8u) ^ (((unsigned)row & 7u) << 4);
    *(ushort4*)((char*)As + off) = b4;
  }
  __syncthreads();

  const int c0 = w * 64;
  const int kb = lane >> 4;
  const int lr = lane & 15;
  f32x4 acc[4][4] = {};
  for (int ks = 0; ks < 8; ++ks) {
    const int k0 = ks * 32;
    bf16x8 a[4], b[4];
    #pragma unroll
    for (int rt = 0; rt < 4; ++rt) {
      int row = rt * 16 + lr;
      unsigned int off = (((unsigned)row * 512u) + (unsigned)(k0 + kb * 8) * 2u) ^
                         (((unsigned)row & 7u) << 4);
      a[rt] = *(const bf16x8*)((const char*)As + off);
    }
    #pragma unroll
    for (int ct = 0; ct < 4; ++ct) {
      int c = c0 + ct * 16 + lr;
      b[ct] = *(const bf16x8*)&W2B[(size_t)c * kC + k0 + kb * 8];
    }
    #pragma unroll
    for (int rt = 0; rt < 4; ++rt)
      #pragma unroll
      for (int ct = 0; ct < 4; ++ct)
        acc[rt][ct] = __builtin_amdgcn_mfma_f32_16x16x32_bf16(a[rt], b[ct], acc[rt][ct], 0, 0, 0);
  }

  #pragma unroll
  for (int rt = 0; rt < 4; ++rt) {
    #pragma unroll
    for (int r = 0; r < 4; ++r) {
      int row = rt * 16 + kb * 4 + r;
      if (row < nr) {
        size_t orow = (size_t)dstrow[row] * kC;
        size_t brow = (size_t)wwin[row] * kC;
        #pragma unroll
        for (int ct = 0; ct < 4; ++ct) {
          int c = c0 + ct * 16 + lr;
          out[orow + c] = acc[rt][ct][r] + base[brow + c];
        }
      }
    }
  }
}

// ---------------------------------------------------------------- launch
extern "C" void kernel_launch(void* const* d_in, const int* in_sizes, int n_in,
                              void* d_out, int out_size, void* d_ws, size_t ws_size,
                              hipStream_t stream) {
  const float* feats      = (const float*)d_in[0];
  const int*   x_idx      = (const int*)d_in[1];
  const int*   flat2win   = (const int*)d_in[2];
  const int*   win2flat   = (const int*)d_in[3];
  const float* in_proj_w  = (const float*)d_in[4];
  const float* in_proj_b  = (const float*)d_in[5];
  const float* out_proj_w = (const float*)d_in[6];
  const float* out_proj_b = (const float*)d_in[7];
  const float* lin1_w     = (const float*)d_in[8];
  const float* lin1_b     = (const float*)d_in[9];
  const float* lin2_w     = (const float*)d_in[10];
  const float* lin2_b     = (const float*)d_in[11];
  const float* ln1_g      = (const float*)d_in[12];
  const float* ln1_b      = (const float*)d_in[13];
  const float* ln2_g      = (const float*)d_in[14];
  const float* ln2_b      = (const float*)d_in[15];
  const float* proj_w     = (const float*)d_in[16];
  const float* proj_b     = (const float*)d_in[17];

  char* ws = (char*)d_ws;
  int*   gidx   = (int*)(ws + OFF_GIDX);
  int*   winner = (int*)(ws + OFF_WINNER);
  int*   wlist  = (int*)(ws + OFF_WLIST);
  int*   cnt    = (int*)(ws + OFF_CNT);
  float* x0     = (float*)(ws + OFF_X0);
  float* basep  = (float*)(ws + OFF_BASE);
  float* x1     = (float*)(ws + OFF_X1);
  unsigned short* attnb = (unsigned short*)(ws + OFF_ATTN);
  unsigned short* Qh    = (unsigned short*)(ws + OFF_QH);
  unsigned short* Kh    = (unsigned short*)(ws + OFF_KH);
  unsigned short* Vh    = (unsigned short*)(ws + OFF_VH);
  unsigned short* ff1b  = (unsigned short*)(ws + OFF_FF1);
  unsigned short* WINB  = (unsigned short*)(ws + OFF_WINB);
  unsigned short* WOUTB = (unsigned short*)(ws + OFF_WOUTB);
  unsigned short* W1B   = (unsigned short*)(ws + OFF_W1B);
  unsigned short* W2B   = (unsigned short*)(ws + OFF_W2B);
  unsigned short* WP1B  = (unsigned short*)(ws + OFF_WP1B);
  unsigned short* WP2B  = (unsigned short*)(ws + OFF_WP2B);
  float* out    = (float*)d_out;

  k_initw<<<kL / 1024, 256, 0, stream>>>(winner, cnt);
  k_winner<<<kL / 1024, 256, 0, stream>>>(x_idx, winner);
  k_fc<<<256 + 1536, 256, 0, stream>>>(x_idx, winner, wlist, cnt,
                                       in_proj_w, out_proj_w, lin1_w, lin2_w, proj_w,
                                       WINB, WOUTB, W1B, W2B, WP1B, WP2B);
  // pool (4096 blocks) + copy (kL/8 = 32768 blocks x 8 rows)  [R8 bug: was kL/32]
  k_pc<<<kNW + kL / 8, 256, 0, stream>>>(feats, x_idx, flat2win, winner, gidx, x0, out);

  k_gemm_qkv<<<dim3(3, kNW / 64), 256, 0, stream>>>(x0, WINB, in_proj_b, Qh, Kh, Vh);
  k_attn<<<dim3(kS / 64, kBS * kNH), 256, 0, stream>>>(Qh, Kh, Vh, attnb);
  k_gemm_ln<false><<<kNW / 16, 256, 0, stream>>>(
      attnb, kC, WOUTB, out_proj_b, x0, ln1_g, ln1_b, x1, nullptr, nullptr);
  k_gemm_ff1<<<dim3(kFF / 256, kNW / 64), 256, 0, stream>>>(x1, W1B, lin1_b, ff1b);
  k_gemm_ln<true><<<kNW / 16, 256, 0, stream>>>(
      ff1b, kFF, W2B, lin2_b, x1, ln2_g, ln2_b, basep, WP1B, proj_b);
  k_fuse<<<kL / 64, 256, 0, stream>>>(feats, gidx, wlist, cnt, win2flat, x_idx,
                                      basep, WP2B, out);
}